// Round 2
// baseline (241.578 us; speedup 1.0000x reference)
//
#include <hip/hip_runtime.h>

#define T_ 4
#define B_ 32
#define C_ 384
#define N_ 256
#define HEADS_ 8
#define DH_ 48
#define EPS_ 1e-5f
#define NW_ (C_*C_)

typedef _Float16 f16;
typedef __attribute__((ext_vector_type(8))) _Float16 f16x8;
typedef __attribute__((ext_vector_type(16))) float f32x16;

#define PSCALE     4096.0f
#define PSCALE_INV (1.0f/4096.0f)

typedef const __attribute__((address_space(1))) unsigned int gas_u32;
typedef __attribute__((address_space(3))) unsigned int las_u32;

// async global -> LDS, 16B per lane; LDS dest is wave-uniform base (+lane*16 implicit)
__device__ __forceinline__ void gload16(const void* g, void* l) {
    __builtin_amdgcn_global_load_lds((gas_u32*)g, (las_u32*)l, 16, 0, 0);
}

// ---------------------------------------------------------------------------
// Kernel 1: input LIF with direct packed stores (no LDS), z==32: weight split
// + counts zeroing.
// Thread map (z<32): n = bx*64 + (tid&63); c0 = by*64 + (tid>>6)*16 -> each
// thread owns 16 consecutive channels of one n; packs 16 f16 spikes and
// stores 32B straight to s[t][b][n][c]. Fully coalesced loads (256B/wave).
// ---------------------------------------------------------------------------
__global__ __launch_bounds__(256)
void prep_kernel(const float* __restrict__ x, f16* __restrict__ s,
                 const float* __restrict__ qw, const float* __restrict__ kw,
                 const float* __restrict__ pw,
                 f16* __restrict__ q2, f16* __restrict__ k2, f16* __restrict__ p2,
                 unsigned int* __restrict__ counts)
{
    if (blockIdx.z == 32) {
        const int base = (blockIdx.y * 4 + blockIdx.x) * 256 + threadIdx.x; // 0..6143
        int idx = base;
#pragma unroll
        for (int it = 0; it < 24; ++it) {
            {
                float w = qw[idx]; f16 a = (f16)w; f16 bb = (f16)((w - (float)a) * PSCALE);
                q2[idx] = a; q2[NW_ + idx] = bb;
            }
            {
                float w = kw[idx]; f16 a = (f16)w; f16 bb = (f16)((w - (float)a) * PSCALE);
                k2[idx] = a; k2[NW_ + idx] = bb;
            }
            {
                float w = pw[idx]; f16 a = (f16)w; f16 bb = (f16)((w - (float)a) * PSCALE);
                p2[idx] = a; p2[NW_ + idx] = bb;
            }
            idx += 6144;
        }
        // zero counts: T*B*H*N u32 = 262144 -> 65536 uint4 over 6144 threads
        const uint4 z = make_uint4(0u, 0u, 0u, 0u);
        for (int i = base; i < (T_ * B_ * HEADS_ * N_) / 4; i += 6144)
            ((uint4*)counts)[i] = z;
        return;
    }

    const int tid = threadIdx.x;
    const int n  = blockIdx.x * 64 + (tid & 63);
    const int cg = tid >> 6;                     // 0..3
    const int c0 = blockIdx.y * 64 + cg * 16;
    const int b  = blockIdx.z;

    float v[16];
#pragma unroll
    for (int i = 0; i < 16; ++i) v[i] = 0.f;

#pragma unroll
    for (int t = 0; t < T_; ++t) {
        const float* xt = x + (((size_t)t * B_ + b) * C_) * N_;
        union { f16 h[16]; uint4 q[2]; } u;
#pragma unroll
        for (int i = 0; i < 16; ++i) {
            float xv = xt[(size_t)(c0 + i) * N_ + n];
            float vv = 0.5f * v[i] + xv;
            int sp = (vv >= 1.0f) ? 1 : 0;
            v[i] = sp ? 0.f : vv;
            u.h[i] = sp ? (f16)1.0f : (f16)0.0f;
        }
        f16* dst = s + (((size_t)t * B_ + b) * N_ + n) * (size_t)C_ + c0;
        *(uint4*)dst = u.q[0];
        *(uint4*)(dst + 8) = u.q[1];
    }
}

// ---------------------------------------------------------------------------
// Kernel 2: q/k GEMM + BN + in-kernel LIF.
// Staging via global_load_lds (16B), unpadded LDS [128][64] f16 per operand
// with XOR chunk swizzle (chunk ^= row&7) pre-applied on the per-lane global
// source address; ds_reads apply the same XOR (both-sides involution, rule 21).
// q path (path==0) emits per-head spike counts via ballot+atomicAdd (no q_spk
// buffer); k path writes k_spk.
// ---------------------------------------------------------------------------
__global__ __launch_bounds__(256)
void qk_gemm_lif_kernel(const f16* __restrict__ Wq, const f16* __restrict__ Wk,
                        const f16* __restrict__ S,
                        const float* __restrict__ qg, const float* __restrict__ qb,
                        const float* __restrict__ qm, const float* __restrict__ qv,
                        const float* __restrict__ kg, const float* __restrict__ kb,
                        const float* __restrict__ km, const float* __restrict__ kv,
                        unsigned int* __restrict__ counts, f16* __restrict__ k_spk)
{
    __shared__ __align__(16) char smem[32768];
    f16* ldsA = (f16*)smem;                              // [128][64]
    f16* ldsB = ldsA + 128 * 64;                         // [128][64] (2 planes x 64)
    float (*P)[64] = reinterpret_cast<float(*)[64]>(smem); // reuse, [128][64] f32

    const int tid  = threadIdx.x;
    const int lane = tid & 63;
    const int wave = tid >> 6;
    const int wm = wave & 1, wd = wave >> 1;
    const int l31 = lane & 31;
    const int lhi = lane >> 5;
    const int lr = lane >> 3, lc = lane & 7;

    const int mb = blockIdx.x;            // 0..255
    const int b  = mb >> 3;
    const int n0 = (mb & 7) * 32;
    const int dp0 = blockIdx.y * 64;      // 0..704
    const int path = (dp0 >= C_) ? 1 : 0; // 0=q 1=k
    const int d0 = dp0 - path * C_;

    const f16* W = path ? Wk : Wq;
    const float* g_  = path ? kg : qg;
    const float* be_ = path ? kb : qb;
    const float* m_  = path ? km : qm;
    const float* va_ = path ? kv : qv;

    const int dcol = d0 + wd * 32 + l31;
    const float inv = g_[dcol] / sqrtf(va_[dcol] + EPS_);
    const float add = be_[dcol] - m_[dcol] * inv;

    // staging: wave w covers rows [w*32, w*32+32) of A and B regions,
    // 4 instrs of 8 rows each; lane l -> row +(l>>3), chunk (l&7);
    // source chunk pre-swizzled: (l&7) ^ (row&7) == lc ^ lr.
    const f16* gA[4]; const f16* gB[4];
    f16* dA[4]; f16* dB[4];
#pragma unroll
    for (int j = 0; j < 4; ++j) {
        const int rr = wave * 32 + j * 8 + lr;          // 0..127
        const int t = rr >> 5, n = n0 + (rr & 31);
        gA[j] = S + (((size_t)t * B_ + b) * N_ + n) * (size_t)C_ + (lc ^ lr) * 8;
        const int p = rr >> 6, r = rr & 63;
        gB[j] = W + (size_t)p * NW_ + (size_t)(d0 + r) * C_ + (lc ^ lr) * 8;
        dA[j] = ldsA + (wave * 32 + j * 8) * 64;
        dB[j] = ldsB + (wave * 32 + j * 8) * 64;
    }

    f32x16 acc[2][2];
#pragma unroll
    for (int ms = 0; ms < 2; ++ms)
#pragma unroll
        for (int p = 0; p < 2; ++p)
#pragma unroll
            for (int r = 0; r < 16; ++r) acc[ms][p][r] = 0.f;

    const f16* pa0 = ldsA + (wm * 64 + l31) * 64;
    const f16* pa1 = pa0 + 32 * 64;
    const f16* pb0 = ldsB + (wd * 32 + l31) * 64;
    const f16* pb1 = pb0 + 64 * 64;
    const int sx = l31 & 7;   // rows of all 4 fragments share (row&7) == l31&7

    for (int kc = 0; kc < C_; kc += 64) {
        __syncthreads();
#pragma unroll
        for (int j = 0; j < 4; ++j) {
            gload16(gA[j] + kc, dA[j]);
            gload16(gB[j] + kc, dB[j]);
        }
        __syncthreads();
#pragma unroll
        for (int kk = 0; kk < 4; ++kk) {
            const int co = ((kk * 2 + lhi) ^ sx) * 8;
            f16x8 a0 = *(const f16x8*)(pa0 + co);
            f16x8 a1 = *(const f16x8*)(pa1 + co);
            f16x8 b0 = *(const f16x8*)(pb0 + co);
            f16x8 b1 = *(const f16x8*)(pb1 + co);
            acc[0][0] = __builtin_amdgcn_mfma_f32_32x32x16_f16(a0, b0, acc[0][0], 0, 0, 0);
            acc[1][0] = __builtin_amdgcn_mfma_f32_32x32x16_f16(a1, b0, acc[1][0], 0, 0, 0);
            acc[0][1] = __builtin_amdgcn_mfma_f32_32x32x16_f16(a0, b1, acc[0][1], 0, 0, 0);
            acc[1][1] = __builtin_amdgcn_mfma_f32_32x32x16_f16(a1, b1, acc[1][1], 0, 0, 0);
        }
    }

    // acc -> BN -> P (LDS reuse)
    __syncthreads();
#pragma unroll
    for (int ms = 0; ms < 2; ++ms)
#pragma unroll
    for (int r = 0; r < 16; ++r) {
        const int row = wm * 64 + ms * 32 + (r & 3) + 8 * (r >> 2) + 4 * lhi;
        const float val = acc[ms][0][r] + acc[ms][1][r] * PSCALE_INV;
        P[row][wd * 32 + l31] = val * inv + add;
    }
    __syncthreads();

    // in-block LIF over t
    {
        const int d = tid & 63;   // == lane
        const int g = tid >> 6;
        if (path == 0) {
            // q path: per-head spike counts, no spike buffer
            const int h0 = d0 / DH_;
            const int ls = (h0 + 1) * DH_ - d0;          // 16/32/48
            const unsigned long long lom = (1ull << ls) - 1ull;
#pragma unroll
            for (int i = 0; i < 8; ++i) {
                const int nl = g + 4 * i;
                float v = 0.f;
#pragma unroll
                for (int t = 0; t < T_; ++t) {
                    float p = P[t * 32 + nl][d];
                    float vv = 0.5f * v + p;
                    int sp = (vv >= 1.0f) ? 1 : 0;
                    v = sp ? 0.f : vv;
                    unsigned long long m = __ballot(sp);
                    if (lane == 0) {
                        const int base = ((t * B_ + b) * HEADS_) * N_ + n0 + nl;
                        atomicAdd(&counts[base + h0 * N_],
                                  (unsigned int)__popcll(m & lom));
                        atomicAdd(&counts[base + (h0 + 1) * N_],
                                  (unsigned int)__popcll(m & ~lom));
                    }
                }
            }
        } else {
#pragma unroll
            for (int i = 0; i < 8; ++i) {
                const int nl = g + 4 * i;
                float v = 0.f;
#pragma unroll
                for (int t = 0; t < T_; ++t) {
                    float p = P[t * 32 + nl][d];
                    float vv = 0.5f * v + p;
                    int sp = (vv >= 1.0f) ? 1 : 0;
                    v = sp ? 0.f : vv;
                    k_spk[(((size_t)t * B_ + b) * N_ + n0 + nl) * C_ + d0 + d] =
                        sp ? (f16)1.0f : (f16)0.0f;
                }
            }
        }
    }
}

// ---------------------------------------------------------------------------
// Kernel 3: decayed memory + attention LIF from precomputed per-head counts.
// ---------------------------------------------------------------------------
__global__ __launch_bounds__(256)
void head_attn_kernel(const unsigned int* __restrict__ counts,
                      const float* __restrict__ alpha_p,
                      unsigned char* __restrict__ attn)
{
    const int i = blockIdx.x * 256 + threadIdx.x;   // B*H*N = 65536
    const float alpha = alpha_p[0];
    const int stride = B_ * HEADS_ * N_;
    float M = 0.f, v = 0.f, Sprev = 0.f;
#pragma unroll
    for (int t = 0; t < T_; ++t) {
        float Sqt = (float)counts[t * stride + i];
        if (t == 0) M = Sqt;
        else        M = alpha * M + (1.f - alpha) * Sprev;
        float qsum = M + Sqt;
        float vv = 0.5f * v + qsum;
        unsigned char sp = (vv >= 0.5f) ? 1 : 0;
        v = sp ? 0.f : vv;
        attn[(size_t)t * stride + i] = sp;
        Sprev = Sqt;
    }
}

// ---------------------------------------------------------------------------
// Kernel 4: proj GEMM. B via global_load_lds (swizzled), A reg-staged with
// attn mask into the same swizzled layout. Epilogue bias+BN -> out.
// ---------------------------------------------------------------------------
__global__ __launch_bounds__(256)
void proj_gemm_kernel(const f16* __restrict__ Wp,
                      const f16* __restrict__ K,
                      const unsigned char* __restrict__ attn,
                      const float* __restrict__ bias,
                      const float* __restrict__ gamma, const float* __restrict__ beta,
                      const float* __restrict__ mean,  const float* __restrict__ var,
                      float* __restrict__ out)
{
    __shared__ __align__(16) char smem[32768];
    f16* ldsA = (f16*)smem;          // [128][64]
    f16* ldsB = ldsA + 128 * 64;     // [128][64]

    const int tid  = threadIdx.x;
    const int lane = tid & 63;
    const int wave = tid >> 6;
    const int wm = wave & 1, wd = wave >> 1;
    const int l31 = lane & 31;
    const int lhi = lane >> 5;
    const int lr = lane >> 3, lc = lane & 7;

    const int mb = blockIdx.x;            // 0..255
    const int tb = mb >> 1;
    const int n0 = (mb & 1) * 128;
    const int d0 = blockIdx.y * 64;

    const int dcol = d0 + wd * 32 + l31;
    const float iv = gamma[dcol] / sqrtf(var[dcol] + EPS_);
    const float ad = beta[dcol] - mean[dcol] * iv + bias[dcol] * iv;

    // A reg-stage map: 2 threads/row, 4 chunks each
    const int ar  = tid >> 1;             // 0..127
    const int ach = (tid & 1) * 4;        // chunk start
    const int an  = n0 + ar;
    const f16* arow = K + ((size_t)tb * N_ + an) * (size_t)C_;
    const unsigned char* At = attn + (size_t)tb * HEADS_ * N_;

    // B DMA map
    const f16* gB[4]; f16* dB[4];
#pragma unroll
    for (int j = 0; j < 4; ++j) {
        const int rr = wave * 32 + j * 8 + lr;
        const int p = rr >> 6, r = rr & 63;
        gB[j] = Wp + (size_t)p * NW_ + (size_t)(d0 + r) * C_ + (lc ^ lr) * 8;
        dB[j] = ldsB + (wave * 32 + j * 8) * 64;
    }

    f32x16 acc[2][2];
#pragma unroll
    for (int ms = 0; ms < 2; ++ms)
#pragma unroll
        for (int p = 0; p < 2; ++p)
#pragma unroll
            for (int r = 0; r < 16; ++r) acc[ms][p][r] = 0.f;

    const f16* pa0 = ldsA + (wm * 64 + l31) * 64;
    const f16* pa1 = pa0 + 32 * 64;
    const f16* pb0 = ldsB + (wd * 32 + l31) * 64;
    const f16* pb1 = pb0 + 64 * 64;
    const int sx = l31 & 7;

    for (int kc = 0; kc < C_; kc += 64) {
        __syncthreads();
#pragma unroll
        for (int j = 0; j < 4; ++j) gload16(gB[j] + kc, dB[j]);
#pragma unroll
        for (int j = 0; j < 4; ++j) {
            const int c8 = ach + j;
            const int c = kc + c8 * 8;
            const int h = c / DH_;
            const unsigned char am = At[(size_t)h * N_ + an];
            uint4 val = am ? *(const uint4*)(arow + c) : make_uint4(0u, 0u, 0u, 0u);
            *(uint4*)(ldsA + ar * 64 + ((c8 ^ (ar & 7)) * 8)) = val;
        }
        __syncthreads();
#pragma unroll
        for (int kk = 0; kk < 4; ++kk) {
            const int co = ((kk * 2 + lhi) ^ sx) * 8;
            f16x8 a0 = *(const f16x8*)(pa0 + co);
            f16x8 a1 = *(const f16x8*)(pa1 + co);
            f16x8 b0 = *(const f16x8*)(pb0 + co);
            f16x8 b1 = *(const f16x8*)(pb1 + co);
            acc[0][0] = __builtin_amdgcn_mfma_f32_32x32x16_f16(a0, b0, acc[0][0], 0, 0, 0);
            acc[1][0] = __builtin_amdgcn_mfma_f32_32x32x16_f16(a1, b0, acc[1][0], 0, 0, 0);
            acc[0][1] = __builtin_amdgcn_mfma_f32_32x32x16_f16(a0, b1, acc[0][1], 0, 0, 0);
            acc[1][1] = __builtin_amdgcn_mfma_f32_32x32x16_f16(a1, b1, acc[1][1], 0, 0, 0);
        }
    }

    // epilogue: out[tb][dcol][n]
    float* obase = out + ((size_t)tb * C_ + dcol) * N_;
#pragma unroll
    for (int ms = 0; ms < 2; ++ms)
#pragma unroll
    for (int r = 0; r < 16; ++r) {
        const int n = n0 + wm * 64 + ms * 32 + (r & 3) + 8 * (r >> 2) + 4 * lhi;
        const float val = acc[ms][0][r] + acc[ms][1][r] * PSCALE_INV;
        obase[n] = val * iv + ad;
    }
}

// ---------------------------------------------------------------------------
extern "C" void kernel_launch(void* const* d_in, const int* in_sizes, int n_in,
                              void* d_out, int out_size, void* d_ws, size_t ws_size,
                              hipStream_t stream)
{
    const float* x       = (const float*)d_in[0];
    const float* q_w     = (const float*)d_in[1];
    const float* q_gamma = (const float*)d_in[2];
    const float* q_beta  = (const float*)d_in[3];
    const float* q_mean  = (const float*)d_in[4];
    const float* q_var   = (const float*)d_in[5];
    const float* k_w     = (const float*)d_in[6];
    const float* k_gamma = (const float*)d_in[7];
    const float* k_beta  = (const float*)d_in[8];
    const float* k_mean  = (const float*)d_in[9];
    const float* k_var   = (const float*)d_in[10];
    const float* proj_w  = (const float*)d_in[11];
    const float* proj_b  = (const float*)d_in[12];
    const float* p_gamma = (const float*)d_in[13];
    const float* p_beta  = (const float*)d_in[14];
    const float* p_mean  = (const float*)d_in[15];
    const float* p_var   = (const float*)d_in[16];
    const float* m_alpha = (const float*)d_in[17];

    float* out = (float*)d_out;

    const size_t SPK_BYTES = (size_t)T_ * B_ * N_ * C_ * sizeof(f16);
    const size_t W2_BYTES  = (size_t)2 * NW_ * sizeof(f16);
    const size_t TBHN      = (size_t)T_ * B_ * HEADS_ * N_;

    unsigned char* ws = (unsigned char*)d_ws;
    size_t off = 0;
    auto carve = [&](size_t bytes) {
        off = (off + 255) & ~(size_t)255;
        void* p = ws + off;
        off += bytes;
        return p;
    };
    f16* s_f16  = (f16*)carve(SPK_BYTES);
    f16* k_spk  = (f16*)carve(SPK_BYTES);
    f16* Wq2    = (f16*)carve(W2_BYTES);
    f16* Wk2    = (f16*)carve(W2_BYTES);
    f16* Wp2    = (f16*)carve(W2_BYTES);
    unsigned char* attn   = (unsigned char*)carve(TBHN);
    unsigned int*  counts = (unsigned int*)carve(TBHN * 4);

    // 1. input LIF + packed direct stores (z<32); weight split + counts zero (z==32)
    dim3 pgrid1(4, 6, 33);
    prep_kernel<<<pgrid1, 256, 0, stream>>>(x, s_f16, q_w, k_w, proj_w,
                                            Wq2, Wk2, Wp2, counts);

    // 2. q+k GEMM + BN + in-kernel LIF (grid 256 x 12)
    dim3 qkgrid(256, 12);
    qk_gemm_lif_kernel<<<qkgrid, 256, 0, stream>>>(Wq2, Wk2, s_f16,
                                                   q_gamma, q_beta, q_mean, q_var,
                                                   k_gamma, k_beta, k_mean, k_var,
                                                   counts, k_spk);

    // 3. memory + attn LIF from counts
    head_attn_kernel<<<(B_ * HEADS_ * N_) / 256, 256, 0, stream>>>(counts, m_alpha, attn);

    // 4. proj GEMM -> out (grid 256 x 6)
    dim3 pjgrid(256, 6);
    proj_gemm_kernel<<<pjgrid, 256, 0, stream>>>(Wp2, k_spk, attn, proj_b,
                                                 p_gamma, p_beta, p_mean, p_var, out);
}

// Round 3
// 238.241 us; speedup vs baseline: 1.0140x; 1.0140x over previous
//
#include <hip/hip_runtime.h>

#define T_ 4
#define B_ 32
#define C_ 384
#define N_ 256
#define HEADS_ 8
#define DH_ 48
#define EPS_ 1e-5f
#define NW_ (C_*C_)

typedef _Float16 f16;
typedef __attribute__((ext_vector_type(8))) _Float16 f16x8;
typedef __attribute__((ext_vector_type(16))) float f32x16;

#define PSCALE     4096.0f
#define PSCALE_INV (1.0f/4096.0f)

// ---------------------------------------------------------------------------
// Kernel 1: input LIF, 16B/lane float4 loads, packed 16B stores (no LDS).
// z<32: thread owns 8 consecutive channels x 4 consecutive n.
// z==32: weight split into 2 f16 planes + counts zeroing (12 blocks).
// ---------------------------------------------------------------------------
__global__ __launch_bounds__(256)
void prep_kernel(const float* __restrict__ x, f16* __restrict__ s,
                 const float* __restrict__ qw, const float* __restrict__ kw,
                 const float* __restrict__ pw,
                 f16* __restrict__ q2, f16* __restrict__ k2, f16* __restrict__ p2,
                 unsigned int* __restrict__ counts)
{
    if (blockIdx.z == 32) {
        const int base = (blockIdx.y * 4 + blockIdx.x) * 256 + threadIdx.x; // 0..3071
        int idx = base;
#pragma unroll 4
        for (int it = 0; it < 48; ++it) {
            {
                float w = qw[idx]; f16 a = (f16)w; f16 bb = (f16)((w - (float)a) * PSCALE);
                q2[idx] = a; q2[NW_ + idx] = bb;
            }
            {
                float w = kw[idx]; f16 a = (f16)w; f16 bb = (f16)((w - (float)a) * PSCALE);
                k2[idx] = a; k2[NW_ + idx] = bb;
            }
            {
                float w = pw[idx]; f16 a = (f16)w; f16 bb = (f16)((w - (float)a) * PSCALE);
                p2[idx] = a; p2[NW_ + idx] = bb;
            }
            idx += 3072;
        }
        // zero counts: 262144 u32 = 65536 uint4 over 3072 threads
        const uint4 z = make_uint4(0u, 0u, 0u, 0u);
        for (int i = base; i < (T_ * B_ * HEADS_ * N_) / 4; i += 3072)
            ((uint4*)counts)[i] = z;
        return;
    }

    const int tid = threadIdx.x;
    const int ng = tid & 15;                     // n-group
    const int cg = tid >> 4;                     // 0..15
    const int n4 = blockIdx.x * 64 + ng * 4;     // 4 consecutive n
    const int c0 = blockIdx.y * 128 + cg * 8;    // 8 consecutive c
    const int b  = blockIdx.z;

    float v[8][4];
#pragma unroll
    for (int i = 0; i < 8; ++i)
#pragma unroll
        for (int j = 0; j < 4; ++j) v[i][j] = 0.f;

#pragma unroll
    for (int t = 0; t < T_; ++t) {
        const float* xt = x + (((size_t)t * B_ + b) * C_) * N_;
        float4 xv[8];
#pragma unroll
        for (int i = 0; i < 8; ++i)
            xv[i] = *(const float4*)&xt[(size_t)(c0 + i) * N_ + n4];
#pragma unroll
        for (int j = 0; j < 4; ++j) {
            union { f16 h[8]; uint4 q; } u;
#pragma unroll
            for (int i = 0; i < 8; ++i) {
                float xa = (j == 0) ? xv[i].x : (j == 1) ? xv[i].y
                         : (j == 2) ? xv[i].z : xv[i].w;
                float vv = 0.5f * v[i][j] + xa;
                int sp = (vv >= 1.0f) ? 1 : 0;
                v[i][j] = sp ? 0.f : vv;
                u.h[i] = sp ? (f16)1.0f : (f16)0.0f;
            }
            f16* dst = s + (((size_t)t * B_ + b) * N_ + n4 + j) * (size_t)C_ + c0;
            *(uint4*)dst = u.q;
        }
    }
}

// ---------------------------------------------------------------------------
// Kernel 2: q/k GEMM + BN + in-kernel LIF. Reg-staged padded LDS ([*][72],
// 0 bank conflicts measured). q path: per-head spike counts via
// ballot+atomicAdd (no q_spk buffer); k path: k_spk f16 spikes.
// ---------------------------------------------------------------------------
__global__ __launch_bounds__(256)
void qk_gemm_lif_kernel(const f16* __restrict__ Wq, const f16* __restrict__ Wk,
                        const f16* __restrict__ S,
                        const float* __restrict__ qg, const float* __restrict__ qb,
                        const float* __restrict__ qm, const float* __restrict__ qv,
                        const float* __restrict__ kg, const float* __restrict__ kb,
                        const float* __restrict__ km, const float* __restrict__ kv,
                        unsigned int* __restrict__ counts, f16* __restrict__ k_spk)
{
    __shared__ __align__(16) char smem[36864];
    f16 (*As)[72]      = reinterpret_cast<f16(*)[72]>(smem);            // [128][72]
    f16 (*Bs)[64][72]  = reinterpret_cast<f16(*)[64][72]>(smem + 18432);// [2][64][72]
    float (*P)[64]     = reinterpret_cast<float(*)[64]>(smem);          // [128][64] (reuse)

    const int tid  = threadIdx.x;
    const int lane = tid & 63;
    const int wave = tid >> 6;
    const int wm = wave & 1, wd = wave >> 1;
    const int l31 = lane & 31;
    const int lhi = lane >> 5;

    const int mb = blockIdx.x;            // 0..255
    const int b  = mb >> 3;
    const int n0 = (mb & 7) * 32;
    const int dp0 = blockIdx.y * 64;      // 0..704
    const int path = (dp0 >= C_) ? 1 : 0; // 0=q 1=k
    const int d0 = dp0 - path * C_;

    const f16* W = path ? Wk : Wq;
    const float* g_  = path ? kg : qg;
    const float* be_ = path ? kb : qb;
    const float* m_  = path ? km : qm;
    const float* va_ = path ? kv : qv;

    const int dcol = d0 + wd * 32 + l31;
    const float inv = g_[dcol] / sqrtf(va_[dcol] + EPS_);
    const float add = be_[dcol] - m_[dcol] * inv;

    // staging map
    const int ar = tid >> 1;              // 0..127
    const int ah = (tid & 1) * 32;        // col half
    const int at = ar >> 5;               // t of this A row
    const int an = n0 + (ar & 31);        // n of this A row
    const f16* arow = S + (((size_t)at * B_ + b) * N_ + an) * (size_t)C_;

    const int bp = tid >> 7;              // plane
    const int brr = (tid >> 1) & 63;      // d row
    const int bh = (tid & 1) * 32;
    const f16* brow = W + (size_t)bp * NW_ + (size_t)(d0 + brr) * C_;

    f32x16 acc[2][2];                     // [msub][plane]
#pragma unroll
    for (int ms = 0; ms < 2; ++ms)
#pragma unroll
        for (int p = 0; p < 2; ++p)
#pragma unroll
            for (int r = 0; r < 16; ++r) acc[ms][p][r] = 0.f;

    for (int kc = 0; kc < C_; kc += 64) {
        __syncthreads();
        {
            const f16* ga = arow + kc + ah;
            *(uint4*)&As[ar][ah]      = *(const uint4*)(ga);
            *(uint4*)&As[ar][ah + 8]  = *(const uint4*)(ga + 8);
            *(uint4*)&As[ar][ah + 16] = *(const uint4*)(ga + 16);
            *(uint4*)&As[ar][ah + 24] = *(const uint4*)(ga + 24);
            const f16* gb = brow + kc + bh;
            *(uint4*)&Bs[bp][brr][bh]      = *(const uint4*)(gb);
            *(uint4*)&Bs[bp][brr][bh + 8]  = *(const uint4*)(gb + 8);
            *(uint4*)&Bs[bp][brr][bh + 16] = *(const uint4*)(gb + 16);
            *(uint4*)&Bs[bp][brr][bh + 24] = *(const uint4*)(gb + 24);
        }
        __syncthreads();
#pragma unroll
        for (int kk = 0; kk < 4; ++kk) {
            const int ko = kk * 16 + lhi * 8;
            f16x8 a0 = *(const f16x8*)&As[wm * 64 + l31][ko];
            f16x8 a1 = *(const f16x8*)&As[wm * 64 + 32 + l31][ko];
            f16x8 b0 = *(const f16x8*)&Bs[0][wd * 32 + l31][ko];
            f16x8 b1 = *(const f16x8*)&Bs[1][wd * 32 + l31][ko];
            acc[0][0] = __builtin_amdgcn_mfma_f32_32x32x16_f16(a0, b0, acc[0][0], 0, 0, 0);
            acc[1][0] = __builtin_amdgcn_mfma_f32_32x32x16_f16(a1, b0, acc[1][0], 0, 0, 0);
            acc[0][1] = __builtin_amdgcn_mfma_f32_32x32x16_f16(a0, b1, acc[0][1], 0, 0, 0);
            acc[1][1] = __builtin_amdgcn_mfma_f32_32x32x16_f16(a1, b1, acc[1][1], 0, 0, 0);
        }
    }

    // acc -> BN -> P (LDS, reuses As/Bs space)
    __syncthreads();
#pragma unroll
    for (int ms = 0; ms < 2; ++ms)
#pragma unroll
    for (int r = 0; r < 16; ++r) {
        int row = wm * 64 + ms * 32 + (r & 3) + 8 * (r >> 2) + 4 * lhi;
        float val = acc[ms][0][r] + acc[ms][1][r] * PSCALE_INV;
        P[row][wd * 32 + l31] = val * inv + add;
    }
    __syncthreads();

    // in-block LIF over t
    {
        const int d = tid & 63;   // == lane
        const int g = tid >> 6;
        if (path == 0) {
            // q path: per-head spike counts, no spike buffer
            const int h0 = d0 / DH_;
            const int ls = (h0 + 1) * DH_ - d0;          // 16/32/48
            const unsigned long long lom = (1ull << ls) - 1ull;
#pragma unroll
            for (int i = 0; i < 8; ++i) {
                const int nl = g + 4 * i;
                float v = 0.f;
#pragma unroll
                for (int t = 0; t < T_; ++t) {
                    float p = P[t * 32 + nl][d];
                    float vv = 0.5f * v + p;
                    int sp = (vv >= 1.0f) ? 1 : 0;
                    v = sp ? 0.f : vv;
                    unsigned long long m = __ballot(sp);
                    if (lane == 0) {
                        const int base = ((t * B_ + b) * HEADS_) * N_ + n0 + nl;
                        atomicAdd(&counts[base + h0 * N_],
                                  (unsigned int)__popcll(m & lom));
                        atomicAdd(&counts[base + (h0 + 1) * N_],
                                  (unsigned int)__popcll(m & ~lom));
                    }
                }
            }
        } else {
#pragma unroll
            for (int i = 0; i < 8; ++i) {
                const int nl = g + 4 * i;
                float v = 0.f;
#pragma unroll
                for (int t = 0; t < T_; ++t) {
                    float p = P[t * 32 + nl][d];
                    float vv = 0.5f * v + p;
                    int sp = (vv >= 1.0f) ? 1 : 0;
                    v = sp ? 0.f : vv;
                    k_spk[(((size_t)t * B_ + b) * N_ + n0 + nl) * C_ + d0 + d] =
                        sp ? (f16)1.0f : (f16)0.0f;
                }
            }
        }
    }
}

// ---------------------------------------------------------------------------
// Kernel 3: proj GEMM with fused attn-LIF prologue. Each block recomputes its
// attn mask (8 heads x 128 n) from counts into LDS, then reg-staged padded
// GEMM with A = (attn & k_spk). Epilogue bias+BN -> out.
// ---------------------------------------------------------------------------
__global__ __launch_bounds__(256)
void proj_gemm_kernel(const f16* __restrict__ Wp,
                      const f16* __restrict__ K,
                      const unsigned int* __restrict__ counts,
                      const float* __restrict__ alpha_p,
                      const float* __restrict__ bias,
                      const float* __restrict__ gamma, const float* __restrict__ beta,
                      const float* __restrict__ mean,  const float* __restrict__ var,
                      float* __restrict__ out)
{
    __shared__ __align__(16) char smem[37888];
    f16 (*As)[72]     = reinterpret_cast<f16(*)[72]>(smem);
    f16 (*Bs)[64][72] = reinterpret_cast<f16(*)[64][72]>(smem + 18432);
    unsigned char* attn_l = (unsigned char*)(smem + 36864);   // [8][128]

    const int tid  = threadIdx.x;
    const int lane = tid & 63;
    const int wave = tid >> 6;
    const int wm = wave & 1, wd = wave >> 1;
    const int l31 = lane & 31;
    const int lhi = lane >> 5;

    const int mb = blockIdx.x;            // 0..255
    const int tb = mb >> 1;
    const int n0 = (mb & 1) * 128;
    const int d0 = blockIdx.y * 64;

    // ---- prologue: attn mask from counts (LIF chain over t' <= t) ----
    {
        const int t = tb >> 5;            // tb = t*B + b
        const int b = tb & 31;
        const float alpha = alpha_p[0];
        for (int ch = tid; ch < HEADS_ * 128; ch += 256) {
            const int h  = ch >> 7;
            const int nl = ch & 127;
            const unsigned int* cp =
                counts + ((size_t)b * HEADS_ + h) * N_ + n0 + nl;
            float M = 0.f, v = 0.f, Sprev = 0.f;
            unsigned char sp = 0;
            for (int tp = 0; tp <= t; ++tp) {
                float Sqt = (float)cp[(size_t)tp * (B_ * HEADS_ * N_)];
                if (tp == 0) M = Sqt;
                else         M = alpha * M + (1.f - alpha) * Sprev;
                float qsum = M + Sqt;
                float vv = 0.5f * v + qsum;
                sp = (vv >= 0.5f) ? 1 : 0;
                v = sp ? 0.f : vv;
                Sprev = Sqt;
            }
            attn_l[ch] = sp;
        }
    }

    const int dcol = d0 + wd * 32 + l31;
    const float iv = gamma[dcol] / sqrtf(var[dcol] + EPS_);
    const float ad = beta[dcol] - mean[dcol] * iv + bias[dcol] * iv;

    // A reg-stage map: 2 threads/row, 4 chunks each
    const int ar = tid >> 1;              // 0..127
    const int ah = (tid & 1) * 32;
    const int an = n0 + ar;
    const f16* arow = K + ((size_t)tb * N_ + an) * (size_t)C_;

    const int bp = tid >> 7;
    const int brr = (tid >> 1) & 63;
    const int bh = (tid & 1) * 32;
    const f16* brow = Wp + (size_t)bp * NW_ + (size_t)(d0 + brr) * C_;

    f32x16 acc[2][2];
#pragma unroll
    for (int ms = 0; ms < 2; ++ms)
#pragma unroll
        for (int p = 0; p < 2; ++p)
#pragma unroll
            for (int r = 0; r < 16; ++r) acc[ms][p][r] = 0.f;

    for (int kc = 0; kc < C_; kc += 64) {
        __syncthreads();
        {
#pragma unroll
            for (int j = 0; j < 4; ++j) {
                int c = kc + ah + 8 * j;
                int h = c / DH_;
                unsigned char am = attn_l[h * 128 + ar];
                uint4 val = am ? *(const uint4*)(arow + c) : make_uint4(0u, 0u, 0u, 0u);
                *(uint4*)&As[ar][ah + 8 * j] = val;
            }
            const f16* gb = brow + kc + bh;
            *(uint4*)&Bs[bp][brr][bh]      = *(const uint4*)(gb);
            *(uint4*)&Bs[bp][brr][bh + 8]  = *(const uint4*)(gb + 8);
            *(uint4*)&Bs[bp][brr][bh + 16] = *(const uint4*)(gb + 16);
            *(uint4*)&Bs[bp][brr][bh + 24] = *(const uint4*)(gb + 24);
        }
        __syncthreads();
#pragma unroll
        for (int kk = 0; kk < 4; ++kk) {
            const int ko = kk * 16 + lhi * 8;
            f16x8 a0 = *(const f16x8*)&As[wm * 64 + l31][ko];
            f16x8 a1 = *(const f16x8*)&As[wm * 64 + 32 + l31][ko];
            f16x8 b0 = *(const f16x8*)&Bs[0][wd * 32 + l31][ko];
            f16x8 b1 = *(const f16x8*)&Bs[1][wd * 32 + l31][ko];
            acc[0][0] = __builtin_amdgcn_mfma_f32_32x32x16_f16(a0, b0, acc[0][0], 0, 0, 0);
            acc[1][0] = __builtin_amdgcn_mfma_f32_32x32x16_f16(a1, b0, acc[1][0], 0, 0, 0);
            acc[0][1] = __builtin_amdgcn_mfma_f32_32x32x16_f16(a0, b1, acc[0][1], 0, 0, 0);
            acc[1][1] = __builtin_amdgcn_mfma_f32_32x32x16_f16(a1, b1, acc[1][1], 0, 0, 0);
        }
    }

    // epilogue: out[tb][dcol][n]
    float* obase = out + ((size_t)tb * C_ + dcol) * N_;
#pragma unroll
    for (int ms = 0; ms < 2; ++ms)
#pragma unroll
    for (int r = 0; r < 16; ++r) {
        int n = n0 + wm * 64 + ms * 32 + (r & 3) + 8 * (r >> 2) + 4 * lhi;
        float val = acc[ms][0][r] + acc[ms][1][r] * PSCALE_INV;
        obase[n] = val * iv + ad;
    }
}

// ---------------------------------------------------------------------------
extern "C" void kernel_launch(void* const* d_in, const int* in_sizes, int n_in,
                              void* d_out, int out_size, void* d_ws, size_t ws_size,
                              hipStream_t stream)
{
    const float* x       = (const float*)d_in[0];
    const float* q_w     = (const float*)d_in[1];
    const float* q_gamma = (const float*)d_in[2];
    const float* q_beta  = (const float*)d_in[3];
    const float* q_mean  = (const float*)d_in[4];
    const float* q_var   = (const float*)d_in[5];
    const float* k_w     = (const float*)d_in[6];
    const float* k_gamma = (const float*)d_in[7];
    const float* k_beta  = (const float*)d_in[8];
    const float* k_mean  = (const float*)d_in[9];
    const float* k_var   = (const float*)d_in[10];
    const float* proj_w  = (const float*)d_in[11];
    const float* proj_b  = (const float*)d_in[12];
    const float* p_gamma = (const float*)d_in[13];
    const float* p_beta  = (const float*)d_in[14];
    const float* p_mean  = (const float*)d_in[15];
    const float* p_var   = (const float*)d_in[16];
    const float* m_alpha = (const float*)d_in[17];

    float* out = (float*)d_out;

    const size_t SPK_BYTES = (size_t)T_ * B_ * N_ * C_ * sizeof(f16);
    const size_t W2_BYTES  = (size_t)2 * NW_ * sizeof(f16);
    const size_t TBHN      = (size_t)T_ * B_ * HEADS_ * N_;

    unsigned char* ws = (unsigned char*)d_ws;
    size_t off = 0;
    auto carve = [&](size_t bytes) {
        off = (off + 255) & ~(size_t)255;
        void* p = ws + off;
        off += bytes;
        return p;
    };
    f16* s_f16  = (f16*)carve(SPK_BYTES);
    f16* k_spk  = (f16*)carve(SPK_BYTES);
    f16* Wq2    = (f16*)carve(W2_BYTES);
    f16* Wk2    = (f16*)carve(W2_BYTES);
    f16* Wp2    = (f16*)carve(W2_BYTES);
    unsigned int* counts = (unsigned int*)carve(TBHN * 4);

    // 1. input LIF + packed direct stores (z<32); weight split + counts zero (z==32)
    dim3 pgrid1(4, 3, 33);
    prep_kernel<<<pgrid1, 256, 0, stream>>>(x, s_f16, q_w, k_w, proj_w,
                                            Wq2, Wk2, Wp2, counts);

    // 2. q+k GEMM + BN + in-kernel LIF (grid 256 x 12)
    dim3 qkgrid(256, 12);
    qk_gemm_lif_kernel<<<qkgrid, 256, 0, stream>>>(Wq2, Wk2, s_f16,
                                                   q_gamma, q_beta, q_mean, q_var,
                                                   k_gamma, k_beta, k_mean, k_var,
                                                   counts, k_spk);

    // 3. proj GEMM with fused attn prologue -> out (grid 256 x 6)
    dim3 pjgrid(256, 6);
    proj_gemm_kernel<<<pjgrid, 256, 0, stream>>>(Wp2, k_spk, counts, m_alpha, proj_b,
                                                 p_gamma, p_beta, p_mean, p_var, out);
}

// Round 4
// 230.782 us; speedup vs baseline: 1.0468x; 1.0323x over previous
//
#include <hip/hip_runtime.h>

#define T_ 4
#define B_ 32
#define C_ 384
#define N_ 256
#define HEADS_ 8
#define DH_ 48
#define EPS_ 1e-5f
#define NW_ (C_*C_)

typedef _Float16 f16;
typedef __attribute__((ext_vector_type(8))) _Float16 f16x8;
typedef __attribute__((ext_vector_type(16))) float f32x16;

#define PSCALE     4096.0f
#define PSCALE_INV (1.0f/4096.0f)

// ---------------------------------------------------------------------------
// Kernel 1: input LIF, 16B/lane float4 loads, packed 16B stores (no LDS).
// z<32: thread owns 8 consecutive channels x 4 consecutive n.
// z==32: weight split into 2 f16 planes (12 blocks).
// ---------------------------------------------------------------------------
__global__ __launch_bounds__(256)
void prep_kernel(const float* __restrict__ x, f16* __restrict__ s,
                 const float* __restrict__ qw, const float* __restrict__ kw,
                 const float* __restrict__ pw,
                 f16* __restrict__ q2, f16* __restrict__ k2, f16* __restrict__ p2)
{
    if (blockIdx.z == 32) {
        const int base = (blockIdx.y * 4 + blockIdx.x) * 256 + threadIdx.x; // 0..3071
        int idx = base;
#pragma unroll 4
        for (int it = 0; it < 48; ++it) {
            {
                float w = qw[idx]; f16 a = (f16)w; f16 bb = (f16)((w - (float)a) * PSCALE);
                q2[idx] = a; q2[NW_ + idx] = bb;
            }
            {
                float w = kw[idx]; f16 a = (f16)w; f16 bb = (f16)((w - (float)a) * PSCALE);
                k2[idx] = a; k2[NW_ + idx] = bb;
            }
            {
                float w = pw[idx]; f16 a = (f16)w; f16 bb = (f16)((w - (float)a) * PSCALE);
                p2[idx] = a; p2[NW_ + idx] = bb;
            }
            idx += 3072;
        }
        return;
    }

    const int tid = threadIdx.x;
    const int ng = tid & 15;                     // n-group
    const int cg = tid >> 4;                     // 0..15
    const int n4 = blockIdx.x * 64 + ng * 4;     // 4 consecutive n
    const int c0 = blockIdx.y * 128 + cg * 8;    // 8 consecutive c
    const int b  = blockIdx.z;

    float v[8][4];
#pragma unroll
    for (int i = 0; i < 8; ++i)
#pragma unroll
        for (int j = 0; j < 4; ++j) v[i][j] = 0.f;

#pragma unroll
    for (int t = 0; t < T_; ++t) {
        const float* xt = x + (((size_t)t * B_ + b) * C_) * N_;
        float4 xv[8];
#pragma unroll
        for (int i = 0; i < 8; ++i)
            xv[i] = *(const float4*)&xt[(size_t)(c0 + i) * N_ + n4];
#pragma unroll
        for (int j = 0; j < 4; ++j) {
            union { f16 h[8]; uint4 q; } u;
#pragma unroll
            for (int i = 0; i < 8; ++i) {
                float xa = (j == 0) ? xv[i].x : (j == 1) ? xv[i].y
                         : (j == 2) ? xv[i].z : xv[i].w;
                float vv = 0.5f * v[i][j] + xa;
                int sp = (vv >= 1.0f) ? 1 : 0;
                v[i][j] = sp ? 0.f : vv;
                u.h[i] = sp ? (f16)1.0f : (f16)0.0f;
            }
            f16* dst = s + (((size_t)t * B_ + b) * N_ + n4 + j) * (size_t)C_ + c0;
            *(uint4*)dst = u.q;
        }
    }
}

// ---------------------------------------------------------------------------
// Kernel 2: q/k GEMM + BN + fully in-register LIF.
// A-tile rows are ordered ar = n_local*4 + t, so in the 32x32 C layout
// (row = (r&3) + 8*(r>>2) + 4*lhi) the t-recurrence runs over adjacent
// accumulator registers (t == r&3): no P LDS round-trip, no extra barriers.
// grid.x = 512: blockIdx.x&1 = path (q/k), so the q/k pair sharing the same
// A-tile is dispatch-adjacent (A L2 reuse). Reg-staged padded LDS [*][72]
// (0 bank conflicts, measured r0/r3).
// ---------------------------------------------------------------------------
__global__ __launch_bounds__(256)
void qk_gemm_lif_kernel(const f16* __restrict__ Wq, const f16* __restrict__ Wk,
                        const f16* __restrict__ S,
                        const float* __restrict__ qg, const float* __restrict__ qb,
                        const float* __restrict__ qm, const float* __restrict__ qv,
                        const float* __restrict__ kg, const float* __restrict__ kb,
                        const float* __restrict__ km, const float* __restrict__ kv,
                        f16* __restrict__ q_spk, f16* __restrict__ k_spk)
{
    __shared__ __align__(16) char smem[36864];
    f16 (*As)[72]      = reinterpret_cast<f16(*)[72]>(smem);            // [128][72]
    f16 (*Bs)[64][72]  = reinterpret_cast<f16(*)[64][72]>(smem + 18432);// [2][64][72]

    const int tid  = threadIdx.x;
    const int lane = tid & 63;
    const int wave = tid >> 6;
    const int wm = wave & 1, wd = wave >> 1;
    const int l31 = lane & 31;
    const int lhi = lane >> 5;

    const int path = blockIdx.x & 1;      // 0=q 1=k (pairs share the A-tile)
    const int mb = blockIdx.x >> 1;       // 0..255
    const int b  = mb >> 3;
    const int n0 = (mb & 7) * 32;
    const int d0 = blockIdx.y * 64;

    const f16* W = path ? Wk : Wq;
    const float* g_  = path ? kg : qg;
    const float* be_ = path ? kb : qb;
    const float* m_  = path ? km : qm;
    const float* va_ = path ? kv : qv;
    f16* spk = path ? k_spk : q_spk;

    const int dcol = d0 + wd * 32 + l31;
    const float inv = g_[dcol] / sqrtf(va_[dcol] + EPS_);
    const float add = be_[dcol] - m_[dcol] * inv;

    // A staging map: row ar = n_local*4 + t  (t fastest)
    const int ar = tid >> 1;              // 0..127
    const int ah = (tid & 1) * 32;        // col half
    const f16* arow = S + (((size_t)(ar & 3) * B_ + b) * N_ + n0 + (ar >> 2)) * (size_t)C_;

    const int bp = tid >> 7;              // plane
    const int brr = (tid >> 1) & 63;      // d row
    const int bh = (tid & 1) * 32;
    const f16* brow = W + (size_t)bp * NW_ + (size_t)(d0 + brr) * C_;

    f32x16 acc[2][2];                     // [msub][plane]
#pragma unroll
    for (int ms = 0; ms < 2; ++ms)
#pragma unroll
        for (int p = 0; p < 2; ++p)
#pragma unroll
            for (int r = 0; r < 16; ++r) acc[ms][p][r] = 0.f;

    for (int kc = 0; kc < C_; kc += 64) {
        __syncthreads();
        {
            const f16* ga = arow + kc + ah;
            *(uint4*)&As[ar][ah]      = *(const uint4*)(ga);
            *(uint4*)&As[ar][ah + 8]  = *(const uint4*)(ga + 8);
            *(uint4*)&As[ar][ah + 16] = *(const uint4*)(ga + 16);
            *(uint4*)&As[ar][ah + 24] = *(const uint4*)(ga + 24);
            const f16* gb = brow + kc + bh;
            *(uint4*)&Bs[bp][brr][bh]      = *(const uint4*)(gb);
            *(uint4*)&Bs[bp][brr][bh + 8]  = *(const uint4*)(gb + 8);
            *(uint4*)&Bs[bp][brr][bh + 16] = *(const uint4*)(gb + 16);
            *(uint4*)&Bs[bp][brr][bh + 24] = *(const uint4*)(gb + 24);
        }
        __syncthreads();
#pragma unroll
        for (int kk = 0; kk < 4; ++kk) {
            const int ko = kk * 16 + lhi * 8;
            f16x8 a0 = *(const f16x8*)&As[wm * 64 + l31][ko];
            f16x8 a1 = *(const f16x8*)&As[wm * 64 + 32 + l31][ko];
            f16x8 b0 = *(const f16x8*)&Bs[0][wd * 32 + l31][ko];
            f16x8 b1 = *(const f16x8*)&Bs[1][wd * 32 + l31][ko];
            acc[0][0] = __builtin_amdgcn_mfma_f32_32x32x16_f16(a0, b0, acc[0][0], 0, 0, 0);
            acc[1][0] = __builtin_amdgcn_mfma_f32_32x32x16_f16(a1, b0, acc[1][0], 0, 0, 0);
            acc[0][1] = __builtin_amdgcn_mfma_f32_32x32x16_f16(a0, b1, acc[0][1], 0, 0, 0);
            acc[1][1] = __builtin_amdgcn_mfma_f32_32x32x16_f16(a1, b1, acc[1][1], 0, 0, 0);
        }
    }

    // in-register BN + LIF + spike store (no LDS, no barrier).
    // reg r = g*4 + t: row = t + 8g + 4lhi (+ms*32+wm*64) -> t = r&3,
    // n_local = wm*16 + ms*8 + 2g + lhi.
#pragma unroll
    for (int ms = 0; ms < 2; ++ms)
#pragma unroll
    for (int g = 0; g < 4; ++g) {
        const int n = n0 + wm * 16 + ms * 8 + 2 * g + lhi;
        float v = 0.f;
#pragma unroll
        for (int t = 0; t < 4; ++t) {
            const int r = g * 4 + t;
            float val = (acc[ms][0][r] + acc[ms][1][r] * PSCALE_INV) * inv + add;
            float vv = 0.5f * v + val;
            int sp = (vv >= 1.0f) ? 1 : 0;
            v = sp ? 0.f : vv;
            spk[(((size_t)t * B_ + b) * N_ + n) * C_ + dcol] =
                sp ? (f16)1.0f : (f16)0.0f;
        }
    }
}

// ---------------------------------------------------------------------------
// Kernel 3: fused head-sum + decayed memory + attention LIF (from q_spk).
// ---------------------------------------------------------------------------
__global__ __launch_bounds__(256)
void head_attn_kernel(const f16* __restrict__ q_spk,
                      const float* __restrict__ alpha_p,
                      unsigned char* __restrict__ attn)
{
    int i = blockIdx.x * 256 + threadIdx.x;   // B*H*N = 65536
    int n = i & (N_ - 1);
    int h = (i >> 8) & (HEADS_ - 1);
    int b = i >> 11;
    const float alpha = alpha_p[0];
    const int stride = B_ * HEADS_ * N_;
    float M = 0.f, v = 0.f, Sprev = 0.f;
#pragma unroll
    for (int t = 0; t < T_; ++t) {
        const uint4* p = (const uint4*)(q_spk + (((size_t)(t * B_ + b) * N_) + n) * C_ + h * DH_);
        int cnt = 0;
#pragma unroll
        for (int j = 0; j < 6; ++j) {
            uint4 w = p[j];
            cnt += __popc(w.x & 0x04000400u) + __popc(w.y & 0x04000400u)
                 + __popc(w.z & 0x04000400u) + __popc(w.w & 0x04000400u);
        }
        float Sqt = (float)cnt;
        if (t == 0) M = Sqt;
        else        M = alpha * M + (1.f - alpha) * Sprev;
        float qsum = M + Sqt;
        float vv = 0.5f * v + qsum;
        unsigned char sp = (vv >= 0.5f) ? 1 : 0;
        v = sp ? 0.f : vv;
        attn[(size_t)t * stride + i] = sp;
        Sprev = Sqt;
    }
}

// ---------------------------------------------------------------------------
// Kernel 4: proj GEMM. M = (tb, n) flat; block 128m x 64d, 4 waves, BK=64,
// 2 planes. A = (attn & k_spk) masked at staging. Epilogue bias+BN -> out.
// ---------------------------------------------------------------------------
__global__ __launch_bounds__(256)
void proj_gemm_kernel(const f16* __restrict__ Wp,
                      const f16* __restrict__ K,
                      const unsigned char* __restrict__ attn,
                      const float* __restrict__ bias,
                      const float* __restrict__ gamma, const float* __restrict__ beta,
                      const float* __restrict__ mean,  const float* __restrict__ var,
                      float* __restrict__ out)
{
    __shared__ __align__(16) char smem[36864];
    f16 (*As)[72]     = reinterpret_cast<f16(*)[72]>(smem);
    f16 (*Bs)[64][72] = reinterpret_cast<f16(*)[64][72]>(smem + 18432);

    const int tid  = threadIdx.x;
    const int lane = tid & 63;
    const int wave = tid >> 6;
    const int wm = wave & 1, wd = wave >> 1;
    const int l31 = lane & 31;
    const int lhi = lane >> 5;

    const int mb = blockIdx.x;            // 0..255
    const int tb = mb >> 1;
    const int n0 = (mb & 1) * 128;
    const int d0 = blockIdx.y * 64;

    const int dcol = d0 + wd * 32 + l31;
    const float iv = gamma[dcol] / sqrtf(var[dcol] + EPS_);
    const float ad = beta[dcol] - mean[dcol] * iv + bias[dcol] * iv;

    // A reg-stage map: 2 threads/row, 4 chunks each
    const int ar = tid >> 1;              // 0..127
    const int ah = (tid & 1) * 32;
    const int an = n0 + ar;
    const f16* arow = K + ((size_t)tb * N_ + an) * (size_t)C_;
    const unsigned char* At = attn + (size_t)tb * HEADS_ * N_;

    const int bp = tid >> 7;
    const int brr = (tid >> 1) & 63;
    const int bh = (tid & 1) * 32;
    const f16* brow = Wp + (size_t)bp * NW_ + (size_t)(d0 + brr) * C_;

    f32x16 acc[2][2];
#pragma unroll
    for (int ms = 0; ms < 2; ++ms)
#pragma unroll
        for (int p = 0; p < 2; ++p)
#pragma unroll
            for (int r = 0; r < 16; ++r) acc[ms][p][r] = 0.f;

    for (int kc = 0; kc < C_; kc += 64) {
        __syncthreads();
        {
#pragma unroll
            for (int j = 0; j < 4; ++j) {
                int c = kc + ah + 8 * j;
                int h = c / DH_;
                unsigned char am = At[(size_t)h * N_ + an];
                uint4 val = am ? *(const uint4*)(arow + c) : make_uint4(0u, 0u, 0u, 0u);
                *(uint4*)&As[ar][ah + 8 * j] = val;
            }
            const f16* gb = brow + kc + bh;
            *(uint4*)&Bs[bp][brr][bh]      = *(const uint4*)(gb);
            *(uint4*)&Bs[bp][brr][bh + 8]  = *(const uint4*)(gb + 8);
            *(uint4*)&Bs[bp][brr][bh + 16] = *(const uint4*)(gb + 16);
            *(uint4*)&Bs[bp][brr][bh + 24] = *(const uint4*)(gb + 24);
        }
        __syncthreads();
#pragma unroll
        for (int kk = 0; kk < 4; ++kk) {
            const int ko = kk * 16 + lhi * 8;
            f16x8 a0 = *(const f16x8*)&As[wm * 64 + l31][ko];
            f16x8 a1 = *(const f16x8*)&As[wm * 64 + 32 + l31][ko];
            f16x8 b0 = *(const f16x8*)&Bs[0][wd * 32 + l31][ko];
            f16x8 b1 = *(const f16x8*)&Bs[1][wd * 32 + l31][ko];
            acc[0][0] = __builtin_amdgcn_mfma_f32_32x32x16_f16(a0, b0, acc[0][0], 0, 0, 0);
            acc[1][0] = __builtin_amdgcn_mfma_f32_32x32x16_f16(a1, b0, acc[1][0], 0, 0, 0);
            acc[0][1] = __builtin_amdgcn_mfma_f32_32x32x16_f16(a0, b1, acc[0][1], 0, 0, 0);
            acc[1][1] = __builtin_amdgcn_mfma_f32_32x32x16_f16(a1, b1, acc[1][1], 0, 0, 0);
        }
    }

    // epilogue: out[tb][dcol][n]
    float* obase = out + ((size_t)tb * C_ + dcol) * N_;
#pragma unroll
    for (int ms = 0; ms < 2; ++ms)
#pragma unroll
    for (int r = 0; r < 16; ++r) {
        int n = n0 + wm * 64 + ms * 32 + (r & 3) + 8 * (r >> 2) + 4 * lhi;
        float val = acc[ms][0][r] + acc[ms][1][r] * PSCALE_INV;
        obase[n] = val * iv + ad;
    }
}

// ---------------------------------------------------------------------------
extern "C" void kernel_launch(void* const* d_in, const int* in_sizes, int n_in,
                              void* d_out, int out_size, void* d_ws, size_t ws_size,
                              hipStream_t stream)
{
    const float* x       = (const float*)d_in[0];
    const float* q_w     = (const float*)d_in[1];
    const float* q_gamma = (const float*)d_in[2];
    const float* q_beta  = (const float*)d_in[3];
    const float* q_mean  = (const float*)d_in[4];
    const float* q_var   = (const float*)d_in[5];
    const float* k_w     = (const float*)d_in[6];
    const float* k_gamma = (const float*)d_in[7];
    const float* k_beta  = (const float*)d_in[8];
    const float* k_mean  = (const float*)d_in[9];
    const float* k_var   = (const float*)d_in[10];
    const float* proj_w  = (const float*)d_in[11];
    const float* proj_b  = (const float*)d_in[12];
    const float* p_gamma = (const float*)d_in[13];
    const float* p_beta  = (const float*)d_in[14];
    const float* p_mean  = (const float*)d_in[15];
    const float* p_var   = (const float*)d_in[16];
    const float* m_alpha = (const float*)d_in[17];

    float* out = (float*)d_out;

    const size_t SPK_BYTES = (size_t)T_ * B_ * N_ * C_ * sizeof(f16);
    const size_t W2_BYTES  = (size_t)2 * NW_ * sizeof(f16);
    const size_t TBHN      = (size_t)T_ * B_ * HEADS_ * N_;

    unsigned char* ws = (unsigned char*)d_ws;
    size_t off = 0;
    auto carve = [&](size_t bytes) {
        off = (off + 255) & ~(size_t)255;
        void* p = ws + off;
        off += bytes;
        return p;
    };
    f16* s_f16  = (f16*)carve(SPK_BYTES);
    f16* q_spk  = (f16*)carve(SPK_BYTES);
    f16* k_spk  = (f16*)carve(SPK_BYTES);
    f16* Wq2    = (f16*)carve(W2_BYTES);
    f16* Wk2    = (f16*)carve(W2_BYTES);
    f16* Wp2    = (f16*)carve(W2_BYTES);
    unsigned char* attn = (unsigned char*)carve(TBHN);

    // 1. input LIF + packed direct stores (z<32); weight split (z==32)
    dim3 pgrid1(4, 3, 33);
    prep_kernel<<<pgrid1, 256, 0, stream>>>(x, s_f16, q_w, k_w, proj_w,
                                            Wq2, Wk2, Wp2);

    // 2. q+k GEMM + BN + in-register LIF (grid 512 x 6; q/k pairs adjacent)
    dim3 qkgrid(512, 6);
    qk_gemm_lif_kernel<<<qkgrid, 256, 0, stream>>>(Wq2, Wk2, s_f16,
                                                   q_gamma, q_beta, q_mean, q_var,
                                                   k_gamma, k_beta, k_mean, k_var,
                                                   q_spk, k_spk);

    // 3. fused head-sum + memory + attn LIF
    head_attn_kernel<<<(B_ * HEADS_ * N_) / 256, 256, 0, stream>>>(q_spk, m_alpha, attn);

    // 4. proj GEMM -> out (grid 256 x 6)
    dim3 pjgrid(256, 6);
    proj_gemm_kernel<<<pjgrid, 256, 0, stream>>>(Wp2, k_spk, attn, proj_b,
                                                 p_gamma, p_beta, p_mean, p_var, out);
}

// Round 5
// 228.080 us; speedup vs baseline: 1.0592x; 1.0118x over previous
//
#include <hip/hip_runtime.h>

#define T_ 4
#define B_ 32
#define C_ 384
#define N_ 256
#define HEADS_ 8
#define DH_ 48
#define EPS_ 1e-5f
#define NW_ (C_*C_)

typedef _Float16 f16;
typedef __attribute__((ext_vector_type(8))) _Float16 f16x8;
typedef __attribute__((ext_vector_type(16))) float f32x16;

#define PSCALE     4096.0f
#define PSCALE_INV (1.0f/4096.0f)
#define SPIKE_BYTE 0x3Cu   // high byte of f16 1.0

// unpack 4 spike bytes (0x3C/0x00) -> 2 u32 holding 4 f16 (0x3C00/0x0000)
__device__ __forceinline__ void unpack4(unsigned int w, unsigned int& lo, unsigned int& hi) {
#if defined(__has_builtin) && __has_builtin(__builtin_amdgcn_perm)
    lo = __builtin_amdgcn_perm(w, w, 0x010C000Cu);  // [0, b0, 0, b1]
    hi = __builtin_amdgcn_perm(w, w, 0x030C020Cu);  // [0, b2, 0, b3]
#else
    lo = ((w & 0xFFu) << 8) | ((w & 0xFF00u) << 16);
    hi = ((w & 0x00FF0000u) >> 8) | (w & 0xFF000000u);
#endif
}

// ---------------------------------------------------------------------------
// Kernel 1: input LIF, 16B/lane float4 loads, packed 16B stores (no LDS).
// z<32: thread owns 8 consecutive channels x 4 consecutive n.
// z==32: weight split into 2 f16 planes (12 blocks).
// ---------------------------------------------------------------------------
__global__ __launch_bounds__(256)
void prep_kernel(const float* __restrict__ x, f16* __restrict__ s,
                 const float* __restrict__ qw, const float* __restrict__ kw,
                 const float* __restrict__ pw,
                 f16* __restrict__ q2, f16* __restrict__ k2, f16* __restrict__ p2)
{
    if (blockIdx.z == 32) {
        const int base = (blockIdx.y * 4 + blockIdx.x) * 256 + threadIdx.x; // 0..3071
        int idx = base;
#pragma unroll 4
        for (int it = 0; it < 48; ++it) {
            {
                float w = qw[idx]; f16 a = (f16)w; f16 bb = (f16)((w - (float)a) * PSCALE);
                q2[idx] = a; q2[NW_ + idx] = bb;
            }
            {
                float w = kw[idx]; f16 a = (f16)w; f16 bb = (f16)((w - (float)a) * PSCALE);
                k2[idx] = a; k2[NW_ + idx] = bb;
            }
            {
                float w = pw[idx]; f16 a = (f16)w; f16 bb = (f16)((w - (float)a) * PSCALE);
                p2[idx] = a; p2[NW_ + idx] = bb;
            }
            idx += 3072;
        }
        return;
    }

    const int tid = threadIdx.x;
    const int ng = tid & 15;                     // n-group
    const int cg = tid >> 4;                     // 0..15
    const int n4 = blockIdx.x * 64 + ng * 4;     // 4 consecutive n
    const int c0 = blockIdx.y * 128 + cg * 8;    // 8 consecutive c
    const int b  = blockIdx.z;

    float v[8][4];
#pragma unroll
    for (int i = 0; i < 8; ++i)
#pragma unroll
        for (int j = 0; j < 4; ++j) v[i][j] = 0.f;

#pragma unroll
    for (int t = 0; t < T_; ++t) {
        const float* xt = x + (((size_t)t * B_ + b) * C_) * N_;
        float4 xv[8];
#pragma unroll
        for (int i = 0; i < 8; ++i)
            xv[i] = *(const float4*)&xt[(size_t)(c0 + i) * N_ + n4];
#pragma unroll
        for (int j = 0; j < 4; ++j) {
            union { f16 h[8]; uint4 q; } u;
#pragma unroll
            for (int i = 0; i < 8; ++i) {
                float xa = (j == 0) ? xv[i].x : (j == 1) ? xv[i].y
                         : (j == 2) ? xv[i].z : xv[i].w;
                float vv = 0.5f * v[i][j] + xa;
                int sp = (vv >= 1.0f) ? 1 : 0;
                v[i][j] = sp ? 0.f : vv;
                u.h[i] = sp ? (f16)1.0f : (f16)0.0f;
            }
            f16* dst = s + (((size_t)t * B_ + b) * N_ + n4 + j) * (size_t)C_ + c0;
            *(uint4*)dst = u.q;
        }
    }
}

// ---------------------------------------------------------------------------
// Kernel 2: q/k GEMM + BN + fully in-register LIF.
// Staging + LDS layout byte-identical to round 0 (grid 256x12, (t,n)-ordered
// global reads, [*][72] pad, 0 conflicts measured). The t-recurrence is made
// register-local by PERMUTING THE FRAGMENT-READ ROWS: lane reads LDS row
// rho(m) = 32*(m&3) + (m>>2) so MFMA m-index m holds content (t=m&3, n=m>>2).
// Read bank multiset = 4*(l31>>2) mod 32 -> same 8-group x 4-lane pattern as
// round 0. Epilogue: BN + LIF in registers (t == r&3), u8 spike stores (0x3C).
// ---------------------------------------------------------------------------
__global__ __launch_bounds__(256)
void qk_gemm_lif_kernel(const f16* __restrict__ Wq, const f16* __restrict__ Wk,
                        const f16* __restrict__ S,
                        const float* __restrict__ qg, const float* __restrict__ qb,
                        const float* __restrict__ qm, const float* __restrict__ qv,
                        const float* __restrict__ kg, const float* __restrict__ kb,
                        const float* __restrict__ km, const float* __restrict__ kv,
                        unsigned char* __restrict__ q_spk,
                        unsigned char* __restrict__ k_spk)
{
    __shared__ __align__(16) char smem[36864];
    f16 (*As)[72]      = reinterpret_cast<f16(*)[72]>(smem);            // [128][72]
    f16 (*Bs)[64][72]  = reinterpret_cast<f16(*)[64][72]>(smem + 18432);// [2][64][72]

    const int tid  = threadIdx.x;
    const int lane = tid & 63;
    const int wave = tid >> 6;
    const int wm = wave & 1, wd = wave >> 1;
    const int l31 = lane & 31;
    const int lhi = lane >> 5;

    const int mb = blockIdx.x;            // 0..255
    const int b  = mb >> 3;
    const int n0 = (mb & 7) * 32;
    const int dp0 = blockIdx.y * 64;      // 0..704
    const int path = (dp0 >= C_) ? 1 : 0; // 0=q 1=k
    const int d0 = dp0 - path * C_;

    const f16* W = path ? Wk : Wq;
    const float* g_  = path ? kg : qg;
    const float* be_ = path ? kb : qb;
    const float* m_  = path ? km : qm;
    const float* va_ = path ? kv : qv;
    unsigned char* spk = path ? k_spk : q_spk;

    const int dcol = d0 + wd * 32 + l31;
    const float inv = g_[dcol] / sqrtf(va_[dcol] + EPS_);
    const float add = be_[dcol] - m_[dcol] * inv;

    // staging map (round-0: wave covers 32 consecutive n in ONE t-plane)
    const int ar = tid >> 1;              // LDS row 0..127, content (t=ar>>5, n=ar&31)
    const int ah = (tid & 1) * 32;        // col half
    const int at = ar >> 5;               // t of this A row
    const int an = n0 + (ar & 31);        // n of this A row
    const f16* arow = S + (((size_t)at * B_ + b) * N_ + an) * (size_t)C_;

    const int bp = tid >> 7;              // plane
    const int brr = (tid >> 1) & 63;      // d row
    const int bh = (tid & 1) * 32;
    const f16* brow = W + (size_t)bp * NW_ + (size_t)(d0 + brr) * C_;

    // permuted fragment-read rows: rho(m) = 32*(m&3) + (m>>2)
    const f16* pa0 = &As[32 * (l31 & 3) + wm * 16 + (l31 >> 2)][0];   // msub 0
    const f16* pa1 = pa0 + 8 * 72;                                    // msub 1 (+8 rows)

    f32x16 acc[2][2];                     // [msub][plane]
#pragma unroll
    for (int ms = 0; ms < 2; ++ms)
#pragma unroll
        for (int p = 0; p < 2; ++p)
#pragma unroll
            for (int r = 0; r < 16; ++r) acc[ms][p][r] = 0.f;

    for (int kc = 0; kc < C_; kc += 64) {
        __syncthreads();
        {
            const f16* ga = arow + kc + ah;
            *(uint4*)&As[ar][ah]      = *(const uint4*)(ga);
            *(uint4*)&As[ar][ah + 8]  = *(const uint4*)(ga + 8);
            *(uint4*)&As[ar][ah + 16] = *(const uint4*)(ga + 16);
            *(uint4*)&As[ar][ah + 24] = *(const uint4*)(ga + 24);
            const f16* gb = brow + kc + bh;
            *(uint4*)&Bs[bp][brr][bh]      = *(const uint4*)(gb);
            *(uint4*)&Bs[bp][brr][bh + 8]  = *(const uint4*)(gb + 8);
            *(uint4*)&Bs[bp][brr][bh + 16] = *(const uint4*)(gb + 16);
            *(uint4*)&Bs[bp][brr][bh + 24] = *(const uint4*)(gb + 24);
        }
        __syncthreads();
#pragma unroll
        for (int kk = 0; kk < 4; ++kk) {
            const int ko = kk * 16 + lhi * 8;
            f16x8 a0 = *(const f16x8*)(pa0 + ko);
            f16x8 a1 = *(const f16x8*)(pa1 + ko);
            f16x8 b0 = *(const f16x8*)&Bs[0][wd * 32 + l31][ko];
            f16x8 b1 = *(const f16x8*)&Bs[1][wd * 32 + l31][ko];
            acc[0][0] = __builtin_amdgcn_mfma_f32_32x32x16_f16(a0, b0, acc[0][0], 0, 0, 0);
            acc[1][0] = __builtin_amdgcn_mfma_f32_32x32x16_f16(a1, b0, acc[1][0], 0, 0, 0);
            acc[0][1] = __builtin_amdgcn_mfma_f32_32x32x16_f16(a0, b1, acc[0][1], 0, 0, 0);
            acc[1][1] = __builtin_amdgcn_mfma_f32_32x32x16_f16(a1, b1, acc[1][1], 0, 0, 0);
        }
    }

    // in-register BN + LIF + u8 spike store (no LDS round-trip, no barriers).
    // C-row m = (r&3)+8*(r>>2)+4*lhi+32*ms+64*wm holds content
    // t = m&3 = r&3, n = n0 + (m>>2) = n0 + wm*16 + ms*8 + 2*(r>>2) + lhi.
#pragma unroll
    for (int ms = 0; ms < 2; ++ms)
#pragma unroll
    for (int g = 0; g < 4; ++g) {
        const int n = n0 + wm * 16 + ms * 8 + 2 * g + lhi;
        float v = 0.f;
#pragma unroll
        for (int t = 0; t < 4; ++t) {
            const int r = g * 4 + t;
            float val = (acc[ms][0][r] + acc[ms][1][r] * PSCALE_INV) * inv + add;
            float vv = 0.5f * v + val;
            int sp = (vv >= 1.0f) ? 1 : 0;
            v = sp ? 0.f : vv;
            spk[(((size_t)t * B_ + b) * N_ + n) * C_ + dcol] =
                sp ? (unsigned char)SPIKE_BYTE : (unsigned char)0;
        }
    }
}

// ---------------------------------------------------------------------------
// Kernel 3: fused head-sum + decayed memory + attention LIF (u8 spikes).
// Spike byte 0x3C -> count via bit 2 (mask 0x04040404).
// ---------------------------------------------------------------------------
__global__ __launch_bounds__(256)
void head_attn_kernel(const unsigned char* __restrict__ q_spk,
                      const float* __restrict__ alpha_p,
                      unsigned char* __restrict__ attn)
{
    int i = blockIdx.x * 256 + threadIdx.x;   // B*H*N = 65536
    int n = i & (N_ - 1);
    int h = (i >> 8) & (HEADS_ - 1);
    int b = i >> 11;
    const float alpha = alpha_p[0];
    const int stride = B_ * HEADS_ * N_;
    float M = 0.f, v = 0.f, Sprev = 0.f;
#pragma unroll
    for (int t = 0; t < T_; ++t) {
        const uint4* p = (const uint4*)(q_spk + (((size_t)(t * B_ + b) * N_) + n) * C_ + h * DH_);
        int cnt = 0;
#pragma unroll
        for (int j = 0; j < 3; ++j) {          // 48 bytes = 3 x uint4
            uint4 w = p[j];
            cnt += __popc(w.x & 0x04040404u) + __popc(w.y & 0x04040404u)
                 + __popc(w.z & 0x04040404u) + __popc(w.w & 0x04040404u);
        }
        float Sqt = (float)cnt;
        if (t == 0) M = Sqt;
        else        M = alpha * M + (1.f - alpha) * Sprev;
        float qsum = M + Sqt;
        float vv = 0.5f * v + qsum;
        unsigned char sp = (vv >= 0.5f) ? 1 : 0;
        v = sp ? 0.f : vv;
        attn[(size_t)t * stride + i] = sp;
        Sprev = Sqt;
    }
}

// ---------------------------------------------------------------------------
// Kernel 4: proj GEMM. A = (attn & k_spk_u8) expanded to f16 at staging
// (byte 0x3C -> f16 0x3C00 exact, 1 v_perm per 4 spikes). Reg-staged padded
// LDS. Epilogue bias+BN -> out.
// ---------------------------------------------------------------------------
__global__ __launch_bounds__(256)
void proj_gemm_kernel(const f16* __restrict__ Wp,
                      const unsigned char* __restrict__ K8,
                      const unsigned char* __restrict__ attn,
                      const float* __restrict__ bias,
                      const float* __restrict__ gamma, const float* __restrict__ beta,
                      const float* __restrict__ mean,  const float* __restrict__ var,
                      float* __restrict__ out)
{
    __shared__ __align__(16) char smem[36864];
    f16 (*As)[72]     = reinterpret_cast<f16(*)[72]>(smem);
    f16 (*Bs)[64][72] = reinterpret_cast<f16(*)[64][72]>(smem + 18432);

    const int tid  = threadIdx.x;
    const int lane = tid & 63;
    const int wave = tid >> 6;
    const int wm = wave & 1, wd = wave >> 1;
    const int l31 = lane & 31;
    const int lhi = lane >> 5;

    const int mb = blockIdx.x;            // 0..255
    const int tb = mb >> 1;
    const int n0 = (mb & 1) * 128;
    const int d0 = blockIdx.y * 64;

    const int dcol = d0 + wd * 32 + l31;
    const float iv = gamma[dcol] / sqrtf(var[dcol] + EPS_);
    const float ad = beta[dcol] - mean[dcol] * iv + bias[dcol] * iv;

    // A reg-stage map: 2 threads/row, 4 chunks of 8 channels each
    const int ar = tid >> 1;              // 0..127
    const int ah = (tid & 1) * 32;
    const int an = n0 + ar;
    const unsigned char* arow = K8 + ((size_t)tb * N_ + an) * (size_t)C_;
    const unsigned char* At = attn + (size_t)tb * HEADS_ * N_;

    const int bp = tid >> 7;
    const int brr = (tid >> 1) & 63;
    const int bh = (tid & 1) * 32;
    const f16* brow = Wp + (size_t)bp * NW_ + (size_t)(d0 + brr) * C_;

    f32x16 acc[2][2];
#pragma unroll
    for (int ms = 0; ms < 2; ++ms)
#pragma unroll
        for (int p = 0; p < 2; ++p)
#pragma unroll
            for (int r = 0; r < 16; ++r) acc[ms][p][r] = 0.f;

    for (int kc = 0; kc < C_; kc += 64) {
        __syncthreads();
        {
#pragma unroll
            for (int j = 0; j < 4; ++j) {
                int c = kc + ah + 8 * j;
                int h = c / DH_;
                unsigned char am = At[(size_t)h * N_ + an];
                uint2 w2 = am ? *(const uint2*)(arow + c) : make_uint2(0u, 0u);
                uint4 o;
                unpack4(w2.x, o.x, o.y);
                unpack4(w2.y, o.z, o.w);
                *(uint4*)&As[ar][ah + 8 * j] = o;
            }
            const f16* gb = brow + kc + bh;
            *(uint4*)&Bs[bp][brr][bh]      = *(const uint4*)(gb);
            *(uint4*)&Bs[bp][brr][bh + 8]  = *(const uint4*)(gb + 8);
            *(uint4*)&Bs[bp][brr][bh + 16] = *(const uint4*)(gb + 16);
            *(uint4*)&Bs[bp][brr][bh + 24] = *(const uint4*)(gb + 24);
        }
        __syncthreads();
#pragma unroll
        for (int kk = 0; kk < 4; ++kk) {
            const int ko = kk * 16 + lhi * 8;
            f16x8 a0 = *(const f16x8*)&As[wm * 64 + l31][ko];
            f16x8 a1 = *(const f16x8*)&As[wm * 64 + 32 + l31][ko];
            f16x8 b0 = *(const f16x8*)&Bs[0][wd * 32 + l31][ko];
            f16x8 b1 = *(const f16x8*)&Bs[1][wd * 32 + l31][ko];
            acc[0][0] = __builtin_amdgcn_mfma_f32_32x32x16_f16(a0, b0, acc[0][0], 0, 0, 0);
            acc[1][0] = __builtin_amdgcn_mfma_f32_32x32x16_f16(a1, b0, acc[1][0], 0, 0, 0);
            acc[0][1] = __builtin_amdgcn_mfma_f32_32x32x16_f16(a0, b1, acc[0][1], 0, 0, 0);
            acc[1][1] = __builtin_amdgcn_mfma_f32_32x32x16_f16(a1, b1, acc[1][1], 0, 0, 0);
        }
    }

    // epilogue: out[tb][dcol][n]
    float* obase = out + ((size_t)tb * C_ + dcol) * N_;
#pragma unroll
    for (int ms = 0; ms < 2; ++ms)
#pragma unroll
    for (int r = 0; r < 16; ++r) {
        int n = n0 + wm * 64 + ms * 32 + (r & 3) + 8 * (r >> 2) + 4 * lhi;
        float val = acc[ms][0][r] + acc[ms][1][r] * PSCALE_INV;
        obase[n] = val * iv + ad;
    }
}

// ---------------------------------------------------------------------------
extern "C" void kernel_launch(void* const* d_in, const int* in_sizes, int n_in,
                              void* d_out, int out_size, void* d_ws, size_t ws_size,
                              hipStream_t stream)
{
    const float* x       = (const float*)d_in[0];
    const float* q_w     = (const float*)d_in[1];
    const float* q_gamma = (const float*)d_in[2];
    const float* q_beta  = (const float*)d_in[3];
    const float* q_mean  = (const float*)d_in[4];
    const float* q_var   = (const float*)d_in[5];
    const float* k_w     = (const float*)d_in[6];
    const float* k_gamma = (const float*)d_in[7];
    const float* k_beta  = (const float*)d_in[8];
    const float* k_mean  = (const float*)d_in[9];
    const float* k_var   = (const float*)d_in[10];
    const float* proj_w  = (const float*)d_in[11];
    const float* proj_b  = (const float*)d_in[12];
    const float* p_gamma = (const float*)d_in[13];
    const float* p_beta  = (const float*)d_in[14];
    const float* p_mean  = (const float*)d_in[15];
    const float* p_var   = (const float*)d_in[16];
    const float* m_alpha = (const float*)d_in[17];

    float* out = (float*)d_out;

    const size_t S_BYTES   = (size_t)T_ * B_ * N_ * C_ * sizeof(f16);
    const size_t SPK_BYTES = (size_t)T_ * B_ * N_ * C_;          // u8
    const size_t W2_BYTES  = (size_t)2 * NW_ * sizeof(f16);
    const size_t TBHN      = (size_t)T_ * B_ * HEADS_ * N_;

    unsigned char* ws = (unsigned char*)d_ws;
    size_t off = 0;
    auto carve = [&](size_t bytes) {
        off = (off + 255) & ~(size_t)255;
        void* p = ws + off;
        off += bytes;
        return p;
    };
    f16* s_f16  = (f16*)carve(S_BYTES);
    unsigned char* q_spk = (unsigned char*)carve(SPK_BYTES);
    unsigned char* k_spk = (unsigned char*)carve(SPK_BYTES);
    f16* Wq2    = (f16*)carve(W2_BYTES);
    f16* Wk2    = (f16*)carve(W2_BYTES);
    f16* Wp2    = (f16*)carve(W2_BYTES);
    unsigned char* attn = (unsigned char*)carve(TBHN);

    // 1. input LIF + packed direct stores (z<32); weight split (z==32)
    dim3 pgrid1(4, 3, 33);
    prep_kernel<<<pgrid1, 256, 0, stream>>>(x, s_f16, q_w, k_w, proj_w,
                                            Wq2, Wk2, Wp2);

    // 2. q+k GEMM + BN + in-register LIF (grid 256 x 12, round-0 geometry)
    dim3 qkgrid(256, 12);
    qk_gemm_lif_kernel<<<qkgrid, 256, 0, stream>>>(Wq2, Wk2, s_f16,
                                                   q_gamma, q_beta, q_mean, q_var,
                                                   k_gamma, k_beta, k_mean, k_var,
                                                   q_spk, k_spk);

    // 3. fused head-sum + memory + attn LIF
    head_attn_kernel<<<(B_ * HEADS_ * N_) / 256, 256, 0, stream>>>(q_spk, m_alpha, attn);

    // 4. proj GEMM -> out (grid 256 x 6)
    dim3 pjgrid(256, 6);
    proj_gemm_kernel<<<pjgrid, 256, 0, stream>>>(Wp2, k_spk, attn, proj_b,
                                                 p_gamma, p_beta, p_mean, p_var, out);
}

// Round 7
// 224.996 us; speedup vs baseline: 1.0737x; 1.0137x over previous
//
#include <hip/hip_runtime.h>

#define T_ 4
#define B_ 32
#define C_ 384
#define N_ 256
#define HEADS_ 8
#define DH_ 48
#define EPS_ 1e-5f
#define NW_ (C_*C_)

typedef _Float16 f16;
typedef __attribute__((ext_vector_type(8))) _Float16 f16x8;
typedef __attribute__((ext_vector_type(16))) float f32x16;

#define PSCALE     4096.0f
#define PSCALE_INV (1.0f/4096.0f)
#define SPIKE_BYTE 0x3Cu   // high byte of f16 1.0

// unpack 4 spike bytes (0x3C/0x00) -> 2 u32 holding 4 f16 (0x3C00/0x0000)
__device__ __forceinline__ void unpack4(unsigned int w, unsigned int& lo, unsigned int& hi) {
#if defined(__has_builtin) && __has_builtin(__builtin_amdgcn_perm)
    lo = __builtin_amdgcn_perm(w, w, 0x010C000Cu);  // [0, b0, 0, b1]
    hi = __builtin_amdgcn_perm(w, w, 0x030C020Cu);  // [0, b2, 0, b3]
#else
    lo = ((w & 0xFFu) << 8) | ((w & 0xFF00u) << 16);
    hi = ((w & 0x00FF0000u) >> 8) | (w & 0xFF000000u);
#endif
}

// ---------------------------------------------------------------------------
// Kernel 1: input LIF, 16B/lane float4 loads, packed 16B stores (no LDS).
// z<32: thread owns 8 consecutive channels x 4 consecutive n.
// z==32: weight split into 2 f16 planes (12 blocks).
// ---------------------------------------------------------------------------
__global__ __launch_bounds__(256)
void prep_kernel(const float* __restrict__ x, f16* __restrict__ s,
                 const float* __restrict__ qw, const float* __restrict__ kw,
                 const float* __restrict__ pw,
                 f16* __restrict__ q2, f16* __restrict__ k2, f16* __restrict__ p2)
{
    if (blockIdx.z == 32) {
        const int base = (blockIdx.y * 4 + blockIdx.x) * 256 + threadIdx.x; // 0..3071
        int idx = base;
#pragma unroll 4
        for (int it = 0; it < 48; ++it) {
            {
                float w = qw[idx]; f16 a = (f16)w; f16 bb = (f16)((w - (float)a) * PSCALE);
                q2[idx] = a; q2[NW_ + idx] = bb;
            }
            {
                float w = kw[idx]; f16 a = (f16)w; f16 bb = (f16)((w - (float)a) * PSCALE);
                k2[idx] = a; k2[NW_ + idx] = bb;
            }
            {
                float w = pw[idx]; f16 a = (f16)w; f16 bb = (f16)((w - (float)a) * PSCALE);
                p2[idx] = a; p2[NW_ + idx] = bb;
            }
            idx += 3072;
        }
        return;
    }

    const int tid = threadIdx.x;
    const int ng = tid & 15;                     // n-group
    const int cg = tid >> 4;                     // 0..15
    const int n4 = blockIdx.x * 64 + ng * 4;     // 4 consecutive n
    const int c0 = blockIdx.y * 128 + cg * 8;    // 8 consecutive c
    const int b  = blockIdx.z;

    float v[8][4];
#pragma unroll
    for (int i = 0; i < 8; ++i)
#pragma unroll
        for (int j = 0; j < 4; ++j) v[i][j] = 0.f;

#pragma unroll
    for (int t = 0; t < T_; ++t) {
        const float* xt = x + (((size_t)t * B_ + b) * C_) * N_;
        float4 xv[8];
#pragma unroll
        for (int i = 0; i < 8; ++i)
            xv[i] = *(const float4*)&xt[(size_t)(c0 + i) * N_ + n4];
#pragma unroll
        for (int j = 0; j < 4; ++j) {
            union { f16 h[8]; uint4 q; } u;
#pragma unroll
            for (int i = 0; i < 8; ++i) {
                float xa = (j == 0) ? xv[i].x : (j == 1) ? xv[i].y
                         : (j == 2) ? xv[i].z : xv[i].w;
                float vv = 0.5f * v[i][j] + xa;
                int sp = (vv >= 1.0f) ? 1 : 0;
                v[i][j] = sp ? 0.f : vv;
                u.h[i] = sp ? (f16)1.0f : (f16)0.0f;
            }
            f16* dst = s + (((size_t)t * B_ + b) * N_ + n4 + j) * (size_t)C_ + c0;
            *(uint4*)dst = u.q;
        }
    }
}

// ---------------------------------------------------------------------------
// Kernel 2: q/k GEMM + BN + fully in-register LIF.
// Global staging order = round 0 (wave covers 32 consecutive n in ONE t-plane,
// FETCH-proven). Content (t,n) is stored at physical LDS row
//   sigma(4n+t) = 4n + ((t + (n>>1)) & 3)
// so fragment reads (lane l31 -> content c = wm*64+ms*32+l31, i.e. t = m&3)
// AND staging writes are both quarter-wave bank-balanced (2 lanes/residue,
// 8+-apart pairs -- the round-0 measured-zero structure). Epilogue: BN + LIF
// over adjacent acc registers (t == r&3), u8 spike stores. No P round-trip.
// ---------------------------------------------------------------------------
__global__ __launch_bounds__(256)
void qk_gemm_lif_kernel(const f16* __restrict__ Wq, const f16* __restrict__ Wk,
                        const f16* __restrict__ S,
                        const float* __restrict__ qg, const float* __restrict__ qb,
                        const float* __restrict__ qm, const float* __restrict__ qv,
                        const float* __restrict__ kg, const float* __restrict__ kb,
                        const float* __restrict__ km, const float* __restrict__ kv,
                        unsigned char* __restrict__ q_spk,
                        unsigned char* __restrict__ k_spk)
{
    __shared__ __align__(16) char smem[36864];
    f16 (*As)[72]      = reinterpret_cast<f16(*)[72]>(smem);            // [128][72]
    f16 (*Bs)[64][72]  = reinterpret_cast<f16(*)[64][72]>(smem + 18432);// [2][64][72]

    const int tid  = threadIdx.x;
    const int lane = tid & 63;
    const int wave = tid >> 6;
    const int wm = wave & 1, wd = wave >> 1;
    const int l31 = lane & 31;
    const int lhi = lane >> 5;

    const int mb = blockIdx.x;            // 0..255
    const int b  = mb >> 3;
    const int n0 = (mb & 7) * 32;
    const int dp0 = blockIdx.y * 64;      // 0..704
    const int path = (dp0 >= C_) ? 1 : 0; // 0=q 1=k
    const int d0 = dp0 - path * C_;

    const f16* W = path ? Wk : Wq;
    const float* g_  = path ? kg : qg;
    const float* be_ = path ? kb : qb;
    const float* m_  = path ? km : qm;
    const float* va_ = path ? kv : qv;
    unsigned char* spk = path ? k_spk : q_spk;

    const int dcol = d0 + wd * 32 + l31;
    const float inv = g_[dcol] / sqrtf(va_[dcol] + EPS_);
    const float add = be_[dcol] - m_[dcol] * inv;

    // staging map (round-0 global order: wave covers 32 consecutive n, one t)
    const int ar = tid >> 1;              // 0..127: content (t=ar>>5, n=ar&31)
    const int ah = (tid & 1) * 32;        // col half
    const int at = ar >> 5;               // t of this A row
    const int anl = ar & 31;              // n_local of this A row
    const f16* arow = S + (((size_t)at * B_ + b) * N_ + n0 + anl) * (size_t)C_;
    // physical LDS row: sigma(4n+t) = 4n + ((t + (n>>1)) & 3)
    const int aps = 4 * anl + ((at + (anl >> 1)) & 3);

    const int bp = tid >> 7;              // plane
    const int brr = (tid >> 1) & 63;      // d row
    const int bh = (tid & 1) * 32;
    const f16* brow = W + (size_t)bp * NW_ + (size_t)(d0 + brr) * C_;

    // fragment-read rows: sigma(wm*64+ms*32+l31)
    //   = wm*64 + ms*32 + 4*(l31>>2) + ((l31 + (l31>>3)) & 3)
    const int abase = 4 * (l31 >> 2) + ((l31 + (l31 >> 3)) & 3);
    const f16* pa0 = &As[wm * 64 + abase][0];   // msub 0
    const f16* pa1 = pa0 + 32 * 72;             // msub 1 (+32 physical rows)

    f32x16 acc[2][2];                     // [msub][plane]
#pragma unroll
    for (int ms = 0; ms < 2; ++ms)
#pragma unroll
        for (int p = 0; p < 2; ++p)
#pragma unroll
            for (int r = 0; r < 16; ++r) acc[ms][p][r] = 0.f;

    for (int kc = 0; kc < C_; kc += 64) {
        __syncthreads();
        {
            const f16* ga = arow + kc + ah;
            *(uint4*)&As[aps][ah]      = *(const uint4*)(ga);
            *(uint4*)&As[aps][ah + 8]  = *(const uint4*)(ga + 8);
            *(uint4*)&As[aps][ah + 16] = *(const uint4*)(ga + 16);
            *(uint4*)&As[aps][ah + 24] = *(const uint4*)(ga + 24);
            const f16* gb = brow + kc + bh;
            *(uint4*)&Bs[bp][brr][bh]      = *(const uint4*)(gb);
            *(uint4*)&Bs[bp][brr][bh + 8]  = *(const uint4*)(gb + 8);
            *(uint4*)&Bs[bp][brr][bh + 16] = *(const uint4*)(gb + 16);
            *(uint4*)&Bs[bp][brr][bh + 24] = *(const uint4*)(gb + 24);
        }
        __syncthreads();
#pragma unroll
        for (int kk = 0; kk < 4; ++kk) {
            const int ko = kk * 16 + lhi * 8;
            f16x8 a0 = *(const f16x8*)(pa0 + ko);
            f16x8 a1 = *(const f16x8*)(pa1 + ko);
            f16x8 b0 = *(const f16x8*)&Bs[0][wd * 32 + l31][ko];
            f16x8 b1 = *(const f16x8*)&Bs[1][wd * 32 + l31][ko];
            acc[0][0] = __builtin_amdgcn_mfma_f32_32x32x16_f16(a0, b0, acc[0][0], 0, 0, 0);
            acc[1][0] = __builtin_amdgcn_mfma_f32_32x32x16_f16(a1, b0, acc[1][0], 0, 0, 0);
            acc[0][1] = __builtin_amdgcn_mfma_f32_32x32x16_f16(a0, b1, acc[0][1], 0, 0, 0);
            acc[1][1] = __builtin_amdgcn_mfma_f32_32x32x16_f16(a1, b1, acc[1][1], 0, 0, 0);
        }
    }

    // in-register BN + LIF + u8 spike store (no LDS round-trip, no barriers).
    // acc reg r of subtile (wm,ms): content t = r&3,
    // n = n0 + wm*16 + ms*8 + 2*(r>>2) + lhi.
#pragma unroll
    for (int ms = 0; ms < 2; ++ms)
#pragma unroll
    for (int g = 0; g < 4; ++g) {
        const int n = n0 + wm * 16 + ms * 8 + 2 * g + lhi;
        float v = 0.f;
#pragma unroll
        for (int t = 0; t < 4; ++t) {
            const int r = g * 4 + t;
            float val = (acc[ms][0][r] + acc[ms][1][r] * PSCALE_INV) * inv + add;
            float vv = 0.5f * v + val;
            int sp = (vv >= 1.0f) ? 1 : 0;
            v = sp ? 0.f : vv;
            spk[(((size_t)t * B_ + b) * N_ + n) * C_ + dcol] =
                sp ? (unsigned char)SPIKE_BYTE : (unsigned char)0;
        }
    }
}

// ---------------------------------------------------------------------------
// Kernel 3: fused head-sum + decayed memory + attention LIF (u8 spikes).
// Spike byte 0x3C -> count via bit 2 (mask 0x04040404).
// ---------------------------------------------------------------------------
__global__ __launch_bounds__(256)
void head_attn_kernel(const unsigned char* __restrict__ q_spk,
                      const float* __restrict__ alpha_p,
                      unsigned char* __restrict__ attn)
{
    int i = blockIdx.x * 256 + threadIdx.x;   // B*H*N = 65536
    int n = i & (N_ - 1);
    int h = (i >> 8) & (HEADS_ - 1);
    int b = i >> 11;
    const float alpha = alpha_p[0];
    const int stride = B_ * HEADS_ * N_;
    float M = 0.f, v = 0.f, Sprev = 0.f;
#pragma unroll
    for (int t = 0; t < T_; ++t) {
        const uint4* p = (const uint4*)(q_spk + (((size_t)(t * B_ + b) * N_) + n) * C_ + h * DH_);
        int cnt = 0;
#pragma unroll
        for (int j = 0; j < 3; ++j) {          // 48 bytes = 3 x uint4
            uint4 w = p[j];
            cnt += __popc(w.x & 0x04040404u) + __popc(w.y & 0x04040404u)
                 + __popc(w.z & 0x04040404u) + __popc(w.w & 0x04040404u);
        }
        float Sqt = (float)cnt;
        if (t == 0) M = Sqt;
        else        M = alpha * M + (1.f - alpha) * Sprev;
        float qsum = M + Sqt;
        float vv = 0.5f * v + qsum;
        unsigned char sp = (vv >= 0.5f) ? 1 : 0;
        v = sp ? 0.f : vv;
        attn[(size_t)t * stride + i] = sp;
        Sprev = Sqt;
    }
}

// ---------------------------------------------------------------------------
// Kernel 4: proj GEMM. A = (attn & k_spk_u8) expanded to f16 at staging
// (byte 0x3C -> f16 0x3C00 exact, 1 v_perm per 4 spikes). Reg-staged padded
// LDS. Epilogue bias+BN -> out.
// ---------------------------------------------------------------------------
__global__ __launch_bounds__(256)
void proj_gemm_kernel(const f16* __restrict__ Wp,
                      const unsigned char* __restrict__ K8,
                      const unsigned char* __restrict__ attn,
                      const float* __restrict__ bias,
                      const float* __restrict__ gamma, const float* __restrict__ beta,
                      const float* __restrict__ mean,  const float* __restrict__ var,
                      float* __restrict__ out)
{
    __shared__ __align__(16) char smem[36864];
    f16 (*As)[72]     = reinterpret_cast<f16(*)[72]>(smem);
    f16 (*Bs)[64][72] = reinterpret_cast<f16(*)[64][72]>(smem + 18432);

    const int tid  = threadIdx.x;
    const int lane = tid & 63;
    const int wave = tid >> 6;
    const int wm = wave & 1, wd = wave >> 1;
    const int l31 = lane & 31;
    const int lhi = lane >> 5;

    const int mb = blockIdx.x;            // 0..255
    const int tb = mb >> 1;
    const int n0 = (mb & 1) * 128;
    const int d0 = blockIdx.y * 64;

    const int dcol = d0 + wd * 32 + l31;
    const float iv = gamma[dcol] / sqrtf(var[dcol] + EPS_);
    const float ad = beta[dcol] - mean[dcol] * iv + bias[dcol] * iv;

    // A reg-stage map: 2 threads/row, 4 chunks of 8 channels each
    const int ar = tid >> 1;              // 0..127
    const int ah = (tid & 1) * 32;
    const int an = n0 + ar;
    const unsigned char* arow = K8 + ((size_t)tb * N_ + an) * (size_t)C_;
    const unsigned char* At = attn + (size_t)tb * HEADS_ * N_;

    const int bp = tid >> 7;
    const int brr = (tid >> 1) & 63;
    const int bh = (tid & 1) * 32;
    const f16* brow = Wp + (size_t)bp * NW_ + (size_t)(d0 + brr) * C_;

    f32x16 acc[2][2];
#pragma unroll
    for (int ms = 0; ms < 2; ++ms)
#pragma unroll
        for (int p = 0; p < 2; ++p)
#pragma unroll
            for (int r = 0; r < 16; ++r) acc[ms][p][r] = 0.f;

    for (int kc = 0; kc < C_; kc += 64) {
        __syncthreads();
        {
#pragma unroll
            for (int j = 0; j < 4; ++j) {
                int c = kc + ah + 8 * j;
                int h = c / DH_;
                unsigned char am = At[(size_t)h * N_ + an];
                uint2 w2 = am ? *(const uint2*)(arow + c) : make_uint2(0u, 0u);
                uint4 o;
                unpack4(w2.x, o.x, o.y);
                unpack4(w2.y, o.z, o.w);
                *(uint4*)&As[ar][ah + 8 * j] = o;
            }
            const f16* gb = brow + kc + bh;
            *(uint4*)&Bs[bp][brr][bh]      = *(const uint4*)(gb);
            *(uint4*)&Bs[bp][brr][bh + 8]  = *(const uint4*)(gb + 8);
            *(uint4*)&Bs[bp][brr][bh + 16] = *(const uint4*)(gb + 16);
            *(uint4*)&Bs[bp][brr][bh + 24] = *(const uint4*)(gb + 24);
        }
        __syncthreads();
#pragma unroll
        for (int kk = 0; kk < 4; ++kk) {
            const int ko = kk * 16 + lhi * 8;
            f16x8 a0 = *(const f16x8*)&As[wm * 64 + l31][ko];
            f16x8 a1 = *(const f16x8*)&As[wm * 64 + 32 + l31][ko];
            f16x8 b0 = *(const f16x8*)&Bs[0][wd * 32 + l31][ko];
            f16x8 b1 = *(const f16x8*)&Bs[1][wd * 32 + l31][ko];
            acc[0][0] = __builtin_amdgcn_mfma_f32_32x32x16_f16(a0, b0, acc[0][0], 0, 0, 0);
            acc[1][0] = __builtin_amdgcn_mfma_f32_32x32x16_f16(a1, b0, acc[1][0], 0, 0, 0);
            acc[0][1] = __builtin_amdgcn_mfma_f32_32x32x16_f16(a0, b1, acc[0][1], 0, 0, 0);
            acc[1][1] = __builtin_amdgcn_mfma_f32_32x32x16_f16(a1, b1, acc[1][1], 0, 0, 0);
        }
    }

    // epilogue: out[tb][dcol][n]
    float* obase = out + ((size_t)tb * C_ + dcol) * N_;
#pragma unroll
    for (int ms = 0; ms < 2; ++ms)
#pragma unroll
    for (int r = 0; r < 16; ++r) {
        int n = n0 + wm * 64 + ms * 32 + (r & 3) + 8 * (r >> 2) + 4 * lhi;
        float val = acc[ms][0][r] + acc[ms][1][r] * PSCALE_INV;
        obase[n] = val * iv + ad;
    }
}

// ---------------------------------------------------------------------------
extern "C" void kernel_launch(void* const* d_in, const int* in_sizes, int n_in,
                              void* d_out, int out_size, void* d_ws, size_t ws_size,
                              hipStream_t stream)
{
    const float* x       = (const float*)d_in[0];
    const float* q_w     = (const float*)d_in[1];
    const float* q_gamma = (const float*)d_in[2];
    const float* q_beta  = (const float*)d_in[3];
    const float* q_mean  = (const float*)d_in[4];
    const float* q_var   = (const float*)d_in[5];
    const float* k_w     = (const float*)d_in[6];
    const float* k_gamma = (const float*)d_in[7];
    const float* k_beta  = (const float*)d_in[8];
    const float* k_mean  = (const float*)d_in[9];
    const float* k_var   = (const float*)d_in[10];
    const float* proj_w  = (const float*)d_in[11];
    const float* proj_b  = (const float*)d_in[12];
    const float* p_gamma = (const float*)d_in[13];
    const float* p_beta  = (const float*)d_in[14];
    const float* p_mean  = (const float*)d_in[15];
    const float* p_var   = (const float*)d_in[16];
    const float* m_alpha = (const float*)d_in[17];

    float* out = (float*)d_out;

    const size_t S_BYTES   = (size_t)T_ * B_ * N_ * C_ * sizeof(f16);
    const size_t SPK_BYTES = (size_t)T_ * B_ * N_ * C_;          // u8
    const size_t W2_BYTES  = (size_t)2 * NW_ * sizeof(f16);
    const size_t TBHN      = (size_t)T_ * B_ * HEADS_ * N_;

    unsigned char* ws = (unsigned char*)d_ws;
    size_t off = 0;
    auto carve = [&](size_t bytes) {
        off = (off + 255) & ~(size_t)255;
        void* p = ws + off;
        off += bytes;
        return p;
    };
    f16* s_f16  = (f16*)carve(S_BYTES);
    unsigned char* q_spk = (unsigned char*)carve(SPK_BYTES);
    unsigned char* k_spk = (unsigned char*)carve(SPK_BYTES);
    f16* Wq2    = (f16*)carve(W2_BYTES);
    f16* Wk2    = (f16*)carve(W2_BYTES);
    f16* Wp2    = (f16*)carve(W2_BYTES);
    unsigned char* attn = (unsigned char*)carve(TBHN);

    // 1. input LIF + packed direct stores (z<32); weight split (z==32)
    dim3 pgrid1(4, 3, 33);
    prep_kernel<<<pgrid1, 256, 0, stream>>>(x, s_f16, q_w, k_w, proj_w,
                                            Wq2, Wk2, Wp2);

    // 2. q+k GEMM + BN + in-register LIF (grid 256 x 12, round-0 geometry)
    dim3 qkgrid(256, 12);
    qk_gemm_lif_kernel<<<qkgrid, 256, 0, stream>>>(Wq2, Wk2, s_f16,
                                                   q_gamma, q_beta, q_mean, q_var,
                                                   k_gamma, k_beta, k_mean, k_var,
                                                   q_spk, k_spk);

    // 3. fused head-sum + memory + attn LIF
    head_attn_kernel<<<(B_ * HEADS_ * N_) / 256, 256, 0, stream>>>(q_spk, m_alpha, attn);

    // 4. proj GEMM -> out (grid 256 x 6)
    dim3 pjgrid(256, 6);
    proj_gemm_kernel<<<pjgrid, 256, 0, stream>>>(Wp2, k_spk, attn, proj_b,
                                                 p_gamma, p_beta, p_mean, p_var, out);
}

// Round 8
// 212.568 us; speedup vs baseline: 1.1365x; 1.0585x over previous
//
#include <hip/hip_runtime.h>

#define T_ 4
#define B_ 32
#define C_ 384
#define N_ 256
#define HEADS_ 8
#define DH_ 48
#define EPS_ 1e-5f
#define NW_ (C_*C_)

typedef _Float16 f16;
typedef __attribute__((ext_vector_type(8))) _Float16 f16x8;
typedef __attribute__((ext_vector_type(16))) float f32x16;

#define PSCALE     4096.0f
#define PSCALE_INV (1.0f/4096.0f)
#define SPIKE_BYTE 0x3Cu   // high byte of f16 1.0

// unpack 4 spike bytes (0x3C/0x00) -> 2 u32 holding 4 f16 (0x3C00/0x0000)
__device__ __forceinline__ void unpack4(unsigned int w, unsigned int& lo, unsigned int& hi) {
#if defined(__has_builtin) && __has_builtin(__builtin_amdgcn_perm)
    lo = __builtin_amdgcn_perm(w, w, 0x010C000Cu);  // [0, b0, 0, b1]
    hi = __builtin_amdgcn_perm(w, w, 0x030C020Cu);  // [0, b2, 0, b3]
#else
    lo = ((w & 0xFFu) << 8) | ((w & 0xFF00u) << 16);
    hi = ((w & 0x00FF0000u) >> 8) | (w & 0xFF000000u);
#endif
}

// expand 16 spike bytes (uint4) -> 32 f16 bytes (2x uint4)
__device__ __forceinline__ void unpack16(uint4 w, uint4& o0, uint4& o1) {
    unpack4(w.x, o0.x, o0.y); unpack4(w.y, o0.z, o0.w);
    unpack4(w.z, o1.x, o1.y); unpack4(w.w, o1.z, o1.w);
}

// ---------------------------------------------------------------------------
// Kernel 1: input LIF, 16B/lane float4 loads, u8 spike stores (8B/thread/n).
// z<32: thread owns 8 consecutive channels x 4 consecutive n.
// z==32: weight split into 2 f16 planes (12 blocks).
// ---------------------------------------------------------------------------
__global__ __launch_bounds__(256)
void prep_kernel(const float* __restrict__ x, unsigned char* __restrict__ s,
                 const float* __restrict__ qw, const float* __restrict__ kw,
                 const float* __restrict__ pw,
                 f16* __restrict__ q2, f16* __restrict__ k2, f16* __restrict__ p2)
{
    if (blockIdx.z == 32) {
        const int base = (blockIdx.y * 4 + blockIdx.x) * 256 + threadIdx.x; // 0..3071
        int idx = base;
#pragma unroll 4
        for (int it = 0; it < 48; ++it) {
            {
                float w = qw[idx]; f16 a = (f16)w; f16 bb = (f16)((w - (float)a) * PSCALE);
                q2[idx] = a; q2[NW_ + idx] = bb;
            }
            {
                float w = kw[idx]; f16 a = (f16)w; f16 bb = (f16)((w - (float)a) * PSCALE);
                k2[idx] = a; k2[NW_ + idx] = bb;
            }
            {
                float w = pw[idx]; f16 a = (f16)w; f16 bb = (f16)((w - (float)a) * PSCALE);
                p2[idx] = a; p2[NW_ + idx] = bb;
            }
            idx += 3072;
        }
        return;
    }

    const int tid = threadIdx.x;
    const int ng = tid & 15;                     // n-group
    const int cg = tid >> 4;                     // 0..15
    const int n4 = blockIdx.x * 64 + ng * 4;     // 4 consecutive n
    const int c0 = blockIdx.y * 128 + cg * 8;    // 8 consecutive c
    const int b  = blockIdx.z;

    float v[8][4];
#pragma unroll
    for (int i = 0; i < 8; ++i)
#pragma unroll
        for (int j = 0; j < 4; ++j) v[i][j] = 0.f;

#pragma unroll
    for (int t = 0; t < T_; ++t) {
        const float* xt = x + (((size_t)t * B_ + b) * C_) * N_;
        float4 xv[8];
#pragma unroll
        for (int i = 0; i < 8; ++i)
            xv[i] = *(const float4*)&xt[(size_t)(c0 + i) * N_ + n4];
#pragma unroll
        for (int j = 0; j < 4; ++j) {
            union { unsigned char bb[8]; uint2 u; } u;
#pragma unroll
            for (int i = 0; i < 8; ++i) {
                float xa = (j == 0) ? xv[i].x : (j == 1) ? xv[i].y
                         : (j == 2) ? xv[i].z : xv[i].w;
                float vv = 0.5f * v[i][j] + xa;
                int sp = (vv >= 1.0f) ? 1 : 0;
                v[i][j] = sp ? 0.f : vv;
                u.bb[i] = sp ? (unsigned char)SPIKE_BYTE : (unsigned char)0;
            }
            unsigned char* dst = s + (((size_t)t * B_ + b) * N_ + n4 + j) * (size_t)C_ + c0;
            *(uint2*)dst = u.u;
        }
    }
}

// ---------------------------------------------------------------------------
// Kernel 2: q/k GEMM + BN + fully in-register LIF.
// A source = u8 spikes (expanded to f16 at LDS-write via v_perm, bit-exact).
// sigma row permutation (round-7, conflicts 3x reduced) kept. NEW: register
// prefetch -- next K-step's global loads are issued AFTER the compute-phase
// barrier so they fly during the MFMA cluster and drain at the next
// iteration's first barrier (catalog 2-phase minimum; defeats the per-barrier
// vmcnt(0) serial exposure). Epilogue: BN + LIF over adjacent acc regs,
// u8 spike stores.
// ---------------------------------------------------------------------------
__global__ __launch_bounds__(256)
void qk_gemm_lif_kernel(const f16* __restrict__ Wq, const f16* __restrict__ Wk,
                        const unsigned char* __restrict__ S,
                        const float* __restrict__ qg, const float* __restrict__ qb,
                        const float* __restrict__ qm, const float* __restrict__ qv,
                        const float* __restrict__ kg, const float* __restrict__ kb,
                        const float* __restrict__ km, const float* __restrict__ kv,
                        unsigned char* __restrict__ q_spk,
                        unsigned char* __restrict__ k_spk)
{
    __shared__ __align__(16) char smem[36864];
    f16 (*As)[72]      = reinterpret_cast<f16(*)[72]>(smem);            // [128][72]
    f16 (*Bs)[64][72]  = reinterpret_cast<f16(*)[64][72]>(smem + 18432);// [2][64][72]

    const int tid  = threadIdx.x;
    const int lane = tid & 63;
    const int wave = tid >> 6;
    const int wm = wave & 1, wd = wave >> 1;
    const int l31 = lane & 31;
    const int lhi = lane >> 5;

    const int mb = blockIdx.x;            // 0..255
    const int b  = mb >> 3;
    const int n0 = (mb & 7) * 32;
    const int dp0 = blockIdx.y * 64;      // 0..704
    const int path = (dp0 >= C_) ? 1 : 0; // 0=q 1=k
    const int d0 = dp0 - path * C_;

    const f16* W = path ? Wk : Wq;
    const float* g_  = path ? kg : qg;
    const float* be_ = path ? kb : qb;
    const float* m_  = path ? km : qm;
    const float* va_ = path ? kv : qv;
    unsigned char* spk = path ? k_spk : q_spk;

    const int dcol = d0 + wd * 32 + l31;
    const float inv = g_[dcol] / sqrtf(va_[dcol] + EPS_);
    const float add = be_[dcol] - m_[dcol] * inv;

    // staging map (round-0 global order: wave covers 32 consecutive n, one t)
    const int ar = tid >> 1;              // 0..127: content (t=ar>>5, n=ar&31)
    const int ah = (tid & 1) * 32;        // channel-half offset (bytes in u8 / f16 elems)
    const int at = ar >> 5;
    const int anl = ar & 31;
    const unsigned char* arow = S + (((size_t)at * B_ + b) * N_ + n0 + anl) * (size_t)C_;
    // physical LDS row: sigma(4n+t) = 4n + ((t + (n>>1)) & 3)
    const int aps = 4 * anl + ((at + (anl >> 1)) & 3);

    const int bp = tid >> 7;              // plane
    const int brr = (tid >> 1) & 63;      // d row
    const int bh = (tid & 1) * 32;
    const f16* brow = W + (size_t)bp * NW_ + (size_t)(d0 + brr) * C_;

    // fragment-read rows: sigma(wm*64+ms*32+l31)
    const int abase = 4 * (l31 >> 2) + ((l31 + (l31 >> 3)) & 3);
    const f16* pa0 = &As[wm * 64 + abase][0];   // msub 0
    const f16* pa1 = pa0 + 32 * 72;             // msub 1 (+32 physical rows)

    f32x16 acc[2][2];                     // [msub][plane]
#pragma unroll
    for (int ms = 0; ms < 2; ++ms)
#pragma unroll
        for (int p = 0; p < 2; ++p)
#pragma unroll
            for (int r = 0; r < 16; ++r) acc[ms][p][r] = 0.f;

    // prologue prefetch (tile 0)
    uint4 ra0 = *(const uint4*)(arow + ah);
    uint4 ra1 = *(const uint4*)(arow + ah + 16);
    uint4 rb0 = *(const uint4*)(brow + bh);
    uint4 rb1 = *(const uint4*)(brow + bh + 8);
    uint4 rb2 = *(const uint4*)(brow + bh + 16);
    uint4 rb3 = *(const uint4*)(brow + bh + 24);

#pragma unroll
    for (int ic = 0; ic < 6; ++ic) {
        __syncthreads();                  // prev-tile reads done; drains prefetch
        {
            uint4 o0, o1;
            unpack16(ra0, o0, o1);
            *(uint4*)&As[aps][ah]      = o0;
            *(uint4*)&As[aps][ah + 8]  = o1;
            unpack16(ra1, o0, o1);
            *(uint4*)&As[aps][ah + 16] = o0;
            *(uint4*)&As[aps][ah + 24] = o1;
            *(uint4*)&Bs[bp][brr][bh]      = rb0;
            *(uint4*)&Bs[bp][brr][bh + 8]  = rb1;
            *(uint4*)&Bs[bp][brr][bh + 16] = rb2;
            *(uint4*)&Bs[bp][brr][bh + 24] = rb3;
        }
        __syncthreads();                  // writes visible
        if (ic < 5) {                     // issue next-tile loads: in flight during MFMA
            const int kn = ic * 64 + 64;
            ra0 = *(const uint4*)(arow + kn + ah);
            ra1 = *(const uint4*)(arow + kn + ah + 16);
            rb0 = *(const uint4*)(brow + kn + bh);
            rb1 = *(const uint4*)(brow + kn + bh + 8);
            rb2 = *(const uint4*)(brow + kn + bh + 16);
            rb3 = *(const uint4*)(brow + kn + bh + 24);
        }
#pragma unroll
        for (int kk = 0; kk < 4; ++kk) {
            const int ko = kk * 16 + lhi * 8;
            f16x8 a0 = *(const f16x8*)(pa0 + ko);
            f16x8 a1 = *(const f16x8*)(pa1 + ko);
            f16x8 b0 = *(const f16x8*)&Bs[0][wd * 32 + l31][ko];
            f16x8 b1 = *(const f16x8*)&Bs[1][wd * 32 + l31][ko];
            acc[0][0] = __builtin_amdgcn_mfma_f32_32x32x16_f16(a0, b0, acc[0][0], 0, 0, 0);
            acc[1][0] = __builtin_amdgcn_mfma_f32_32x32x16_f16(a1, b0, acc[1][0], 0, 0, 0);
            acc[0][1] = __builtin_amdgcn_mfma_f32_32x32x16_f16(a0, b1, acc[0][1], 0, 0, 0);
            acc[1][1] = __builtin_amdgcn_mfma_f32_32x32x16_f16(a1, b1, acc[1][1], 0, 0, 0);
        }
    }

    // in-register BN + LIF + u8 spike store (t == r&3; no LDS, no barrier).
#pragma unroll
    for (int ms = 0; ms < 2; ++ms)
#pragma unroll
    for (int g = 0; g < 4; ++g) {
        const int n = n0 + wm * 16 + ms * 8 + 2 * g + lhi;
        float v = 0.f;
#pragma unroll
        for (int t = 0; t < 4; ++t) {
            const int r = g * 4 + t;
            float val = (acc[ms][0][r] + acc[ms][1][r] * PSCALE_INV) * inv + add;
            float vv = 0.5f * v + val;
            int sp = (vv >= 1.0f) ? 1 : 0;
            v = sp ? 0.f : vv;
            spk[(((size_t)t * B_ + b) * N_ + n) * C_ + dcol] =
                sp ? (unsigned char)SPIKE_BYTE : (unsigned char)0;
        }
    }
}

// ---------------------------------------------------------------------------
// Kernel 3: fused head-sum + decayed memory + attention LIF (u8 spikes).
// Spike byte 0x3C -> count via bit 2 (mask 0x04040404).
// ---------------------------------------------------------------------------
__global__ __launch_bounds__(256)
void head_attn_kernel(const unsigned char* __restrict__ q_spk,
                      const float* __restrict__ alpha_p,
                      unsigned char* __restrict__ attn)
{
    int i = blockIdx.x * 256 + threadIdx.x;   // B*H*N = 65536
    int n = i & (N_ - 1);
    int h = (i >> 8) & (HEADS_ - 1);
    int b = i >> 11;
    const float alpha = alpha_p[0];
    const int stride = B_ * HEADS_ * N_;
    float M = 0.f, v = 0.f, Sprev = 0.f;
#pragma unroll
    for (int t = 0; t < T_; ++t) {
        const uint4* p = (const uint4*)(q_spk + (((size_t)(t * B_ + b) * N_) + n) * C_ + h * DH_);
        int cnt = 0;
#pragma unroll
        for (int j = 0; j < 3; ++j) {          // 48 bytes = 3 x uint4
            uint4 w = p[j];
            cnt += __popc(w.x & 0x04040404u) + __popc(w.y & 0x04040404u)
                 + __popc(w.z & 0x04040404u) + __popc(w.w & 0x04040404u);
        }
        float Sqt = (float)cnt;
        if (t == 0) M = Sqt;
        else        M = alpha * M + (1.f - alpha) * Sprev;
        float qsum = M + Sqt;
        float vv = 0.5f * v + qsum;
        unsigned char sp = (vv >= 0.5f) ? 1 : 0;
        v = sp ? 0.f : vv;
        attn[(size_t)t * stride + i] = sp;
        Sprev = Sqt;
    }
}

// ---------------------------------------------------------------------------
// Kernel 4: proj GEMM. A = (attn & k_spk_u8) expanded to f16 at staging.
// Register prefetch of A (u8 + mask) and B, same placement as qk.
// Epilogue bias+BN -> out.
// ---------------------------------------------------------------------------
__global__ __launch_bounds__(256)
void proj_gemm_kernel(const f16* __restrict__ Wp,
                      const unsigned char* __restrict__ K8,
                      const unsigned char* __restrict__ attn,
                      const float* __restrict__ bias,
                      const float* __restrict__ gamma, const float* __restrict__ beta,
                      const float* __restrict__ mean,  const float* __restrict__ var,
                      float* __restrict__ out)
{
    __shared__ __align__(16) char smem[36864];
    f16 (*As)[72]     = reinterpret_cast<f16(*)[72]>(smem);
    f16 (*Bs)[64][72] = reinterpret_cast<f16(*)[64][72]>(smem + 18432);

    const int tid  = threadIdx.x;
    const int lane = tid & 63;
    const int wave = tid >> 6;
    const int wm = wave & 1, wd = wave >> 1;
    const int l31 = lane & 31;
    const int lhi = lane >> 5;

    const int mb = blockIdx.x;            // 0..255
    const int tb = mb >> 1;
    const int n0 = (mb & 1) * 128;
    const int d0 = blockIdx.y * 64;

    const int dcol = d0 + wd * 32 + l31;
    const float iv = gamma[dcol] / sqrtf(var[dcol] + EPS_);
    const float ad = beta[dcol] - mean[dcol] * iv + bias[dcol] * iv;

    // A reg-stage map: 2 threads/row, 4 chunks of 8 channels each
    const int ar = tid >> 1;              // 0..127
    const int ah = (tid & 1) * 32;
    const int an = n0 + ar;
    const unsigned char* arow = K8 + ((size_t)tb * N_ + an) * (size_t)C_;
    const unsigned char* At = attn + (size_t)tb * HEADS_ * N_;

    const int bp = tid >> 7;
    const int brr = (tid >> 1) & 63;
    const int bh = (tid & 1) * 32;
    const f16* brow = Wp + (size_t)bp * NW_ + (size_t)(d0 + brr) * C_;

    f32x16 acc[2][2];
#pragma unroll
    for (int ms = 0; ms < 2; ++ms)
#pragma unroll
        for (int p = 0; p < 2; ++p)
#pragma unroll
            for (int r = 0; r < 16; ++r) acc[ms][p][r] = 0.f;

    // prologue prefetch (tile 0)
    uint2 wa0, wa1, wa2, wa3;
    unsigned char am0, am1, am2, am3;
    uint4 rb0, rb1, rb2, rb3;
    {
        const int c0 = ah;
        am0 = At[(size_t)((c0     ) / DH_) * N_ + an]; wa0 = *(const uint2*)(arow + c0);
        am1 = At[(size_t)((c0 +  8) / DH_) * N_ + an]; wa1 = *(const uint2*)(arow + c0 + 8);
        am2 = At[(size_t)((c0 + 16) / DH_) * N_ + an]; wa2 = *(const uint2*)(arow + c0 + 16);
        am3 = At[(size_t)((c0 + 24) / DH_) * N_ + an]; wa3 = *(const uint2*)(arow + c0 + 24);
        rb0 = *(const uint4*)(brow + bh);
        rb1 = *(const uint4*)(brow + bh + 8);
        rb2 = *(const uint4*)(brow + bh + 16);
        rb3 = *(const uint4*)(brow + bh + 24);
    }

#pragma unroll
    for (int ic = 0; ic < 6; ++ic) {
        __syncthreads();
        {
            uint2 w;
            uint4 o;
            w = am0 ? wa0 : make_uint2(0u, 0u);
            unpack4(w.x, o.x, o.y); unpack4(w.y, o.z, o.w);
            *(uint4*)&As[ar][ah] = o;
            w = am1 ? wa1 : make_uint2(0u, 0u);
            unpack4(w.x, o.x, o.y); unpack4(w.y, o.z, o.w);
            *(uint4*)&As[ar][ah + 8] = o;
            w = am2 ? wa2 : make_uint2(0u, 0u);
            unpack4(w.x, o.x, o.y); unpack4(w.y, o.z, o.w);
            *(uint4*)&As[ar][ah + 16] = o;
            w = am3 ? wa3 : make_uint2(0u, 0u);
            unpack4(w.x, o.x, o.y); unpack4(w.y, o.z, o.w);
            *(uint4*)&As[ar][ah + 24] = o;
            *(uint4*)&Bs[bp][brr][bh]      = rb0;
            *(uint4*)&Bs[bp][brr][bh + 8]  = rb1;
            *(uint4*)&Bs[bp][brr][bh + 16] = rb2;
            *(uint4*)&Bs[bp][brr][bh + 24] = rb3;
        }
        __syncthreads();
        if (ic < 5) {
            const int kn = ic * 64 + 64;
            const int c0 = kn + ah;
            am0 = At[(size_t)((c0     ) / DH_) * N_ + an]; wa0 = *(const uint2*)(arow + c0);
            am1 = At[(size_t)((c0 +  8) / DH_) * N_ + an]; wa1 = *(const uint2*)(arow + c0 + 8);
            am2 = At[(size_t)((c0 + 16) / DH_) * N_ + an]; wa2 = *(const uint2*)(arow + c0 + 16);
            am3 = At[(size_t)((c0 + 24) / DH_) * N_ + an]; wa3 = *(const uint2*)(arow + c0 + 24);
            rb0 = *(const uint4*)(brow + kn + bh);
            rb1 = *(const uint4*)(brow + kn + bh + 8);
            rb2 = *(const uint4*)(brow + kn + bh + 16);
            rb3 = *(const uint4*)(brow + kn + bh + 24);
        }
#pragma unroll
        for (int kk = 0; kk < 4; ++kk) {
            const int ko = kk * 16 + lhi * 8;
            f16x8 a0 = *(const f16x8*)&As[wm * 64 + l31][ko];
            f16x8 a1 = *(const f16x8*)&As[wm * 64 + 32 + l31][ko];
            f16x8 b0 = *(const f16x8*)&Bs[0][wd * 32 + l31][ko];
            f16x8 b1 = *(const f16x8*)&Bs[1][wd * 32 + l31][ko];
            acc[0][0] = __builtin_amdgcn_mfma_f32_32x32x16_f16(a0, b0, acc[0][0], 0, 0, 0);
            acc[1][0] = __builtin_amdgcn_mfma_f32_32x32x16_f16(a1, b0, acc[1][0], 0, 0, 0);
            acc[0][1] = __builtin_amdgcn_mfma_f32_32x32x16_f16(a0, b1, acc[0][1], 0, 0, 0);
            acc[1][1] = __builtin_amdgcn_mfma_f32_32x32x16_f16(a1, b1, acc[1][1], 0, 0, 0);
        }
    }

    // epilogue: out[tb][dcol][n]
    float* obase = out + ((size_t)tb * C_ + dcol) * N_;
#pragma unroll
    for (int ms = 0; ms < 2; ++ms)
#pragma unroll
    for (int r = 0; r < 16; ++r) {
        int n = n0 + wm * 64 + ms * 32 + (r & 3) + 8 * (r >> 2) + 4 * lhi;
        float val = acc[ms][0][r] + acc[ms][1][r] * PSCALE_INV;
        obase[n] = val * iv + ad;
    }
}

// ---------------------------------------------------------------------------
extern "C" void kernel_launch(void* const* d_in, const int* in_sizes, int n_in,
                              void* d_out, int out_size, void* d_ws, size_t ws_size,
                              hipStream_t stream)
{
    const float* x       = (const float*)d_in[0];
    const float* q_w     = (const float*)d_in[1];
    const float* q_gamma = (const float*)d_in[2];
    const float* q_beta  = (const float*)d_in[3];
    const float* q_mean  = (const float*)d_in[4];
    const float* q_var   = (const float*)d_in[5];
    const float* k_w     = (const float*)d_in[6];
    const float* k_gamma = (const float*)d_in[7];
    const float* k_beta  = (const float*)d_in[8];
    const float* k_mean  = (const float*)d_in[9];
    const float* k_var   = (const float*)d_in[10];
    const float* proj_w  = (const float*)d_in[11];
    const float* proj_b  = (const float*)d_in[12];
    const float* p_gamma = (const float*)d_in[13];
    const float* p_beta  = (const float*)d_in[14];
    const float* p_mean  = (const float*)d_in[15];
    const float* p_var   = (const float*)d_in[16];
    const float* m_alpha = (const float*)d_in[17];

    float* out = (float*)d_out;

    const size_t SPK_BYTES = (size_t)T_ * B_ * N_ * C_;          // u8
    const size_t W2_BYTES  = (size_t)2 * NW_ * sizeof(f16);
    const size_t TBHN      = (size_t)T_ * B_ * HEADS_ * N_;

    unsigned char* ws = (unsigned char*)d_ws;
    size_t off = 0;
    auto carve = [&](size_t bytes) {
        off = (off + 255) & ~(size_t)255;
        void* p = ws + off;
        off += bytes;
        return p;
    };
    unsigned char* s_u8  = (unsigned char*)carve(SPK_BYTES);
    unsigned char* q_spk = (unsigned char*)carve(SPK_BYTES);
    unsigned char* k_spk = (unsigned char*)carve(SPK_BYTES);
    f16* Wq2    = (f16*)carve(W2_BYTES);
    f16* Wk2    = (f16*)carve(W2_BYTES);
    f16* Wp2    = (f16*)carve(W2_BYTES);
    unsigned char* attn = (unsigned char*)carve(TBHN);

    // 1. input LIF (u8 spikes) + weight split (z==32)
    dim3 pgrid1(4, 3, 33);
    prep_kernel<<<pgrid1, 256, 0, stream>>>(x, s_u8, q_w, k_w, proj_w,
                                            Wq2, Wk2, Wp2);

    // 2. q+k GEMM + BN + in-register LIF (grid 256 x 12)
    dim3 qkgrid(256, 12);
    qk_gemm_lif_kernel<<<qkgrid, 256, 0, stream>>>(Wq2, Wk2, s_u8,
                                                   q_gamma, q_beta, q_mean, q_var,
                                                   k_gamma, k_beta, k_mean, k_var,
                                                   q_spk, k_spk);

    // 3. fused head-sum + memory + attn LIF
    head_attn_kernel<<<(B_ * HEADS_ * N_) / 256, 256, 0, stream>>>(q_spk, m_alpha, attn);

    // 4. proj GEMM -> out (grid 256 x 6)
    dim3 pjgrid(256, 6);
    proj_gemm_kernel<<<pjgrid, 256, 0, stream>>>(Wp2, k_spk, attn, proj_b,
                                                 p_gamma, p_beta, p_mean, p_var, out);
}

// Round 9
// 211.538 us; speedup vs baseline: 1.1420x; 1.0049x over previous
//
#include <hip/hip_runtime.h>

#define T_ 4
#define B_ 32
#define C_ 384
#define N_ 256
#define HEADS_ 8
#define DH_ 48
#define EPS_ 1e-5f
#define NW_ (C_*C_)

typedef _Float16 f16;
typedef __attribute__((ext_vector_type(8))) _Float16 f16x8;
typedef __attribute__((ext_vector_type(16))) float f32x16;

#define PSCALE     4096.0f
#define PSCALE_INV (1.0f/4096.0f)
#define SPIKE_BYTE 0x3Cu   // high byte of f16 1.0

// unpack 4 spike bytes (0x3C/0x00) -> 2 u32 holding 4 f16 (0x3C00/0x0000)
__device__ __forceinline__ void unpack4(unsigned int w, unsigned int& lo, unsigned int& hi) {
#if defined(__has_builtin) && __has_builtin(__builtin_amdgcn_perm)
    lo = __builtin_amdgcn_perm(w, w, 0x010C000Cu);  // [0, b0, 0, b1]
    hi = __builtin_amdgcn_perm(w, w, 0x030C020Cu);  // [0, b2, 0, b3]
#else
    lo = ((w & 0xFFu) << 8) | ((w & 0xFF00u) << 16);
    hi = ((w & 0x00FF0000u) >> 8) | (w & 0xFF000000u);
#endif
}

// expand 16 spike bytes (uint4) -> 32 f16 bytes (2x uint4)
__device__ __forceinline__ void unpack16(uint4 w, uint4& o0, uint4& o1) {
    unpack4(w.x, o0.x, o0.y); unpack4(w.y, o0.z, o0.w);
    unpack4(w.z, o1.x, o1.y); unpack4(w.w, o1.z, o1.w);
}

// ---------------------------------------------------------------------------
// Kernel 1: input LIF, 16B/lane float4 loads, u8 spike stores.
// z==32: weight split into 2 f16 planes (12 blocks).
// ---------------------------------------------------------------------------
__global__ __launch_bounds__(256)
void prep_kernel(const float* __restrict__ x, unsigned char* __restrict__ s,
                 const float* __restrict__ qw, const float* __restrict__ kw,
                 const float* __restrict__ pw,
                 f16* __restrict__ q2, f16* __restrict__ k2, f16* __restrict__ p2)
{
    if (blockIdx.z == 32) {
        const int base = (blockIdx.y * 4 + blockIdx.x) * 256 + threadIdx.x; // 0..3071
        int idx = base;
#pragma unroll 4
        for (int it = 0; it < 48; ++it) {
            {
                float w = qw[idx]; f16 a = (f16)w; f16 bb = (f16)((w - (float)a) * PSCALE);
                q2[idx] = a; q2[NW_ + idx] = bb;
            }
            {
                float w = kw[idx]; f16 a = (f16)w; f16 bb = (f16)((w - (float)a) * PSCALE);
                k2[idx] = a; k2[NW_ + idx] = bb;
            }
            {
                float w = pw[idx]; f16 a = (f16)w; f16 bb = (f16)((w - (float)a) * PSCALE);
                p2[idx] = a; p2[NW_ + idx] = bb;
            }
            idx += 3072;
        }
        return;
    }

    const int tid = threadIdx.x;
    const int ng = tid & 15;                     // n-group
    const int cg = tid >> 4;                     // 0..15
    const int n4 = blockIdx.x * 64 + ng * 4;     // 4 consecutive n
    const int c0 = blockIdx.y * 128 + cg * 8;    // 8 consecutive c
    const int b  = blockIdx.z;

    float v[8][4];
#pragma unroll
    for (int i = 0; i < 8; ++i)
#pragma unroll
        for (int j = 0; j < 4; ++j) v[i][j] = 0.f;

#pragma unroll
    for (int t = 0; t < T_; ++t) {
        const float* xt = x + (((size_t)t * B_ + b) * C_) * N_;
        float4 xv[8];
#pragma unroll
        for (int i = 0; i < 8; ++i)
            xv[i] = *(const float4*)&xt[(size_t)(c0 + i) * N_ + n4];
#pragma unroll
        for (int j = 0; j < 4; ++j) {
            union { unsigned char bb[8]; uint2 u; } u;
#pragma unroll
            for (int i = 0; i < 8; ++i) {
                float xa = (j == 0) ? xv[i].x : (j == 1) ? xv[i].y
                         : (j == 2) ? xv[i].z : xv[i].w;
                float vv = 0.5f * v[i][j] + xa;
                int sp = (vv >= 1.0f) ? 1 : 0;
                v[i][j] = sp ? 0.f : vv;
                u.bb[i] = sp ? (unsigned char)SPIKE_BYTE : (unsigned char)0;
            }
            unsigned char* dst = s + (((size_t)t * B_ + b) * N_ + n4 + j) * (size_t)C_ + c0;
            *(uint2*)dst = u.u;
        }
    }
}

// ---------------------------------------------------------------------------
// Kernel 2: q/k GEMM + BN + fully in-register LIF.
// DOUBLE-BUFFERED LDS, BK=32, ONE barrier per K-step: per step
//   barrier -> issue next-tile global loads -> MFMA on buf[cur]
//   -> unpack+write next tile into buf[1-cur]
// so the staging writes and u8->f16 unpack co-issue with the MFMA cluster
// (separate pipes) instead of sitting in a barrier-fenced serial region.
// Rows stride 40 f16 (80 B, 16-aligned; bank stride 20 words = 4*(5r%8),
// same x4-per-bank-group class as the round-0-validated 36-word stride).
// sigma row permutation + in-register LIF epilogue unchanged (validated).
// LDS = 40960 B -> exactly 4 blocks/CU.
// ---------------------------------------------------------------------------
__global__ __launch_bounds__(256)
void qk_gemm_lif_kernel(const f16* __restrict__ Wq, const f16* __restrict__ Wk,
                        const unsigned char* __restrict__ S,
                        const float* __restrict__ qg, const float* __restrict__ qb,
                        const float* __restrict__ qm, const float* __restrict__ qv,
                        const float* __restrict__ kg, const float* __restrict__ kb,
                        const float* __restrict__ km, const float* __restrict__ kv,
                        unsigned char* __restrict__ q_spk,
                        unsigned char* __restrict__ k_spk)
{
    __shared__ __align__(16) char smem[40960];
    f16 (*Ab[2])[40];
    f16 (*Bb[2])[64][40];
    Ab[0] = reinterpret_cast<f16(*)[40]>(smem);                  // [128][40]
    Ab[1] = reinterpret_cast<f16(*)[40]>(smem + 10240);
    Bb[0] = reinterpret_cast<f16(*)[64][40]>(smem + 20480);      // [2][64][40]
    Bb[1] = reinterpret_cast<f16(*)[64][40]>(smem + 30720);

    const int tid  = threadIdx.x;
    const int lane = tid & 63;
    const int wave = tid >> 6;
    const int wm = wave & 1, wd = wave >> 1;
    const int l31 = lane & 31;
    const int lhi = lane >> 5;

    const int mb = blockIdx.x;            // 0..255
    const int b  = mb >> 3;
    const int n0 = (mb & 7) * 32;
    const int dp0 = blockIdx.y * 64;      // 0..704
    const int path = (dp0 >= C_) ? 1 : 0; // 0=q 1=k
    const int d0 = dp0 - path * C_;

    const f16* W = path ? Wk : Wq;
    const float* g_  = path ? kg : qg;
    const float* be_ = path ? kb : qb;
    const float* m_  = path ? km : qm;
    const float* va_ = path ? kv : qv;
    unsigned char* spk = path ? k_spk : q_spk;

    const int dcol = d0 + wd * 32 + l31;
    const float inv = g_[dcol] / sqrtf(va_[dcol] + EPS_);
    const float add = be_[dcol] - m_[dcol] * inv;

    // A staging map: 2 threads/row, 16 cols each (16 u8 bytes -> 16 f16)
    const int ar  = tid >> 1;             // 0..127: content (t=ar>>5, n=ar&31)
    const int ah  = (tid & 1) * 16;       // col (f16 elems == u8 bytes)
    const int at  = ar >> 5;
    const int anl = ar & 31;
    const unsigned char* arow = S + (((size_t)at * B_ + b) * N_ + n0 + anl) * (size_t)C_;
    // physical LDS row: sigma(4n+t) = 4n + ((t + (n>>1)) & 3)
    const int aps = 4 * anl + ((at + (anl >> 1)) & 3);

    // B staging map: 2 threads/row (128 rows = 2 planes x 64), 16 cols each
    const int rb  = tid >> 1;             // 0..127
    const int bp  = rb >> 6;
    const int brr = rb & 63;
    const int bh  = (tid & 1) * 16;       // f16 col
    const f16* brow = W + (size_t)bp * NW_ + (size_t)(d0 + brr) * C_;

    // fragment-read rows: sigma(wm*64+ms*32+l31)
    const int abase = 4 * (l31 >> 2) + ((l31 + (l31 >> 3)) & 3);
    const int ard0 = wm * 64 + abase;     // msub 0 row; msub 1 = +32
    const int brd  = wd * 32 + l31;

    f32x16 acc[2][2];                     // [msub][plane]
#pragma unroll
    for (int ms = 0; ms < 2; ++ms)
#pragma unroll
        for (int p = 0; p < 2; ++p)
#pragma unroll
            for (int r = 0; r < 16; ++r) acc[ms][p][r] = 0.f;

    // prologue: load + write tile 0 into buf 0
    uint4 la  = *(const uint4*)(arow + ah);
    uint4 lb0 = *(const uint4*)(brow + bh);
    uint4 lb1 = *(const uint4*)(brow + bh + 8);
    {
        uint4 o0, o1;
        unpack16(la, o0, o1);
        *(uint4*)&Ab[0][aps][ah]     = o0;
        *(uint4*)&Ab[0][aps][ah + 8] = o1;
        *(uint4*)&Bb[0][bp][brr][bh]     = lb0;
        *(uint4*)&Bb[0][bp][brr][bh + 8] = lb1;
    }

#pragma unroll
    for (int ic = 0; ic < 12; ++ic) {
        const int cur = ic & 1, nxt = cur ^ 1;
        __syncthreads();
        if (ic < 11) {                    // next-tile loads: fly during MFMA
            const int kn = (ic + 1) * 32;
            la  = *(const uint4*)(arow + kn + ah);
            lb0 = *(const uint4*)(brow + kn + bh);
            lb1 = *(const uint4*)(brow + kn + bh + 8);
        }
#pragma unroll
        for (int kk = 0; kk < 2; ++kk) {
            const int ko = kk * 16 + lhi * 8;
            f16x8 a0 = *(const f16x8*)&Ab[cur][ard0][ko];
            f16x8 a1 = *(const f16x8*)&Ab[cur][ard0 + 32][ko];
            f16x8 b0 = *(const f16x8*)&Bb[cur][0][brd][ko];
            f16x8 b1 = *(const f16x8*)&Bb[cur][1][brd][ko];
            acc[0][0] = __builtin_amdgcn_mfma_f32_32x32x16_f16(a0, b0, acc[0][0], 0, 0, 0);
            acc[1][0] = __builtin_amdgcn_mfma_f32_32x32x16_f16(a1, b0, acc[1][0], 0, 0, 0);
            acc[0][1] = __builtin_amdgcn_mfma_f32_32x32x16_f16(a0, b1, acc[0][1], 0, 0, 0);
            acc[1][1] = __builtin_amdgcn_mfma_f32_32x32x16_f16(a1, b1, acc[1][1], 0, 0, 0);
        }
        if (ic < 11) {                    // write next tile (other buffer):
            uint4 o0, o1;                 // overlaps MFMA, fenced by next barrier
            unpack16(la, o0, o1);
            *(uint4*)&Ab[nxt][aps][ah]     = o0;
            *(uint4*)&Ab[nxt][aps][ah + 8] = o1;
            *(uint4*)&Bb[nxt][bp][brr][bh]     = lb0;
            *(uint4*)&Bb[nxt][bp][brr][bh + 8] = lb1;
        }
    }

    // in-register BN + LIF + u8 spike store (t == r&3; no LDS, no barrier).
#pragma unroll
    for (int ms = 0; ms < 2; ++ms)
#pragma unroll
    for (int g = 0; g < 4; ++g) {
        const int n = n0 + wm * 16 + ms * 8 + 2 * g + lhi;
        float v = 0.f;
#pragma unroll
        for (int t = 0; t < 4; ++t) {
            const int r = g * 4 + t;
            float val = (acc[ms][0][r] + acc[ms][1][r] * PSCALE_INV) * inv + add;
            float vv = 0.5f * v + val;
            int sp = (vv >= 1.0f) ? 1 : 0;
            v = sp ? 0.f : vv;
            spk[(((size_t)t * B_ + b) * N_ + n) * C_ + dcol] =
                sp ? (unsigned char)SPIKE_BYTE : (unsigned char)0;
        }
    }
}

// ---------------------------------------------------------------------------
// Kernel 3: fused head-sum + decayed memory + attention LIF (u8 spikes).
// ---------------------------------------------------------------------------
__global__ __launch_bounds__(256)
void head_attn_kernel(const unsigned char* __restrict__ q_spk,
                      const float* __restrict__ alpha_p,
                      unsigned char* __restrict__ attn)
{
    int i = blockIdx.x * 256 + threadIdx.x;   // B*H*N = 65536
    int n = i & (N_ - 1);
    int h = (i >> 8) & (HEADS_ - 1);
    int b = i >> 11;
    const float alpha = alpha_p[0];
    const int stride = B_ * HEADS_ * N_;
    float M = 0.f, v = 0.f, Sprev = 0.f;
#pragma unroll
    for (int t = 0; t < T_; ++t) {
        const uint4* p = (const uint4*)(q_spk + (((size_t)(t * B_ + b) * N_) + n) * C_ + h * DH_);
        int cnt = 0;
#pragma unroll
        for (int j = 0; j < 3; ++j) {          // 48 bytes = 3 x uint4
            uint4 w = p[j];
            cnt += __popc(w.x & 0x04040404u) + __popc(w.y & 0x04040404u)
                 + __popc(w.z & 0x04040404u) + __popc(w.w & 0x04040404u);
        }
        float Sqt = (float)cnt;
        if (t == 0) M = Sqt;
        else        M = alpha * M + (1.f - alpha) * Sprev;
        float qsum = M + Sqt;
        float vv = 0.5f * v + qsum;
        unsigned char sp = (vv >= 0.5f) ? 1 : 0;
        v = sp ? 0.f : vv;
        attn[(size_t)t * stride + i] = sp;
        Sprev = Sqt;
    }
}

// ---------------------------------------------------------------------------
// Kernel 4: proj GEMM. A = (attn & k_spk_u8) expanded to f16 at staging.
// Register prefetch of A (u8 + mask) and B. Epilogue bias+BN -> out.
// (unchanged from round 8 for clean attribution)
// ---------------------------------------------------------------------------
__global__ __launch_bounds__(256)
void proj_gemm_kernel(const f16* __restrict__ Wp,
                      const unsigned char* __restrict__ K8,
                      const unsigned char* __restrict__ attn,
                      const float* __restrict__ bias,
                      const float* __restrict__ gamma, const float* __restrict__ beta,
                      const float* __restrict__ mean,  const float* __restrict__ var,
                      float* __restrict__ out)
{
    __shared__ __align__(16) char smem[36864];
    f16 (*As)[72]     = reinterpret_cast<f16(*)[72]>(smem);
    f16 (*Bs)[64][72] = reinterpret_cast<f16(*)[64][72]>(smem + 18432);

    const int tid  = threadIdx.x;
    const int lane = tid & 63;
    const int wave = tid >> 6;
    const int wm = wave & 1, wd = wave >> 1;
    const int l31 = lane & 31;
    const int lhi = lane >> 5;

    const int mb = blockIdx.x;            // 0..255
    const int tb = mb >> 1;
    const int n0 = (mb & 1) * 128;
    const int d0 = blockIdx.y * 64;

    const int dcol = d0 + wd * 32 + l31;
    const float iv = gamma[dcol] / sqrtf(var[dcol] + EPS_);
    const float ad = beta[dcol] - mean[dcol] * iv + bias[dcol] * iv;

    // A reg-stage map: 2 threads/row, 4 chunks of 8 channels each
    const int ar = tid >> 1;              // 0..127
    const int ah = (tid & 1) * 32;
    const int an = n0 + ar;
    const unsigned char* arow = K8 + ((size_t)tb * N_ + an) * (size_t)C_;
    const unsigned char* At = attn + (size_t)tb * HEADS_ * N_;

    const int bp = tid >> 7;
    const int brr = (tid >> 1) & 63;
    const int bh = (tid & 1) * 32;
    const f16* brow = Wp + (size_t)bp * NW_ + (size_t)(d0 + brr) * C_;

    f32x16 acc[2][2];
#pragma unroll
    for (int ms = 0; ms < 2; ++ms)
#pragma unroll
        for (int p = 0; p < 2; ++p)
#pragma unroll
            for (int r = 0; r < 16; ++r) acc[ms][p][r] = 0.f;

    // prologue prefetch (tile 0)
    uint2 wa0, wa1, wa2, wa3;
    unsigned char am0, am1, am2, am3;
    uint4 rb0, rb1, rb2, rb3;
    {
        const int c0 = ah;
        am0 = At[(size_t)((c0     ) / DH_) * N_ + an]; wa0 = *(const uint2*)(arow + c0);
        am1 = At[(size_t)((c0 +  8) / DH_) * N_ + an]; wa1 = *(const uint2*)(arow + c0 + 8);
        am2 = At[(size_t)((c0 + 16) / DH_) * N_ + an]; wa2 = *(const uint2*)(arow + c0 + 16);
        am3 = At[(size_t)((c0 + 24) / DH_) * N_ + an]; wa3 = *(const uint2*)(arow + c0 + 24);
        rb0 = *(const uint4*)(brow + bh);
        rb1 = *(const uint4*)(brow + bh + 8);
        rb2 = *(const uint4*)(brow + bh + 16);
        rb3 = *(const uint4*)(brow + bh + 24);
    }

#pragma unroll
    for (int ic = 0; ic < 6; ++ic) {
        __syncthreads();
        {
            uint2 w;
            uint4 o;
            w = am0 ? wa0 : make_uint2(0u, 0u);
            unpack4(w.x, o.x, o.y); unpack4(w.y, o.z, o.w);
            *(uint4*)&As[ar][ah] = o;
            w = am1 ? wa1 : make_uint2(0u, 0u);
            unpack4(w.x, o.x, o.y); unpack4(w.y, o.z, o.w);
            *(uint4*)&As[ar][ah + 8] = o;
            w = am2 ? wa2 : make_uint2(0u, 0u);
            unpack4(w.x, o.x, o.y); unpack4(w.y, o.z, o.w);
            *(uint4*)&As[ar][ah + 16] = o;
            w = am3 ? wa3 : make_uint2(0u, 0u);
            unpack4(w.x, o.x, o.y); unpack4(w.y, o.z, o.w);
            *(uint4*)&As[ar][ah + 24] = o;
            *(uint4*)&Bs[bp][brr][bh]      = rb0;
            *(uint4*)&Bs[bp][brr][bh + 8]  = rb1;
            *(uint4*)&Bs[bp][brr][bh + 16] = rb2;
            *(uint4*)&Bs[bp][brr][bh + 24] = rb3;
        }
        __syncthreads();
        if (ic < 5) {
            const int kn = ic * 64 + 64;
            const int c0 = kn + ah;
            am0 = At[(size_t)((c0     ) / DH_) * N_ + an]; wa0 = *(const uint2*)(arow + c0);
            am1 = At[(size_t)((c0 +  8) / DH_) * N_ + an]; wa1 = *(const uint2*)(arow + c0 + 8);
            am2 = At[(size_t)((c0 + 16) / DH_) * N_ + an]; wa2 = *(const uint2*)(arow + c0 + 16);
            am3 = At[(size_t)((c0 + 24) / DH_) * N_ + an]; wa3 = *(const uint2*)(arow + c0 + 24);
            rb0 = *(const uint4*)(brow + kn + bh);
            rb1 = *(const uint4*)(brow + kn + bh + 8);
            rb2 = *(const uint4*)(brow + kn + bh + 16);
            rb3 = *(const uint4*)(brow + kn + bh + 24);
        }
#pragma unroll
        for (int kk = 0; kk < 4; ++kk) {
            const int ko = kk * 16 + lhi * 8;
            f16x8 a0 = *(const f16x8*)&As[wm * 64 + l31][ko];
            f16x8 a1 = *(const f16x8*)&As[wm * 64 + 32 + l31][ko];
            f16x8 b0 = *(const f16x8*)&Bs[0][wd * 32 + l31][ko];
            f16x8 b1 = *(const f16x8*)&Bs[1][wd * 32 + l31][ko];
            acc[0][0] = __builtin_amdgcn_mfma_f32_32x32x16_f16(a0, b0, acc[0][0], 0, 0, 0);
            acc[1][0] = __builtin_amdgcn_mfma_f32_32x32x16_f16(a1, b0, acc[1][0], 0, 0, 0);
            acc[0][1] = __builtin_amdgcn_mfma_f32_32x32x16_f16(a0, b1, acc[0][1], 0, 0, 0);
            acc[1][1] = __builtin_amdgcn_mfma_f32_32x32x16_f16(a1, b1, acc[1][1], 0, 0, 0);
        }
    }

    // epilogue: out[tb][dcol][n]
    float* obase = out + ((size_t)tb * C_ + dcol) * N_;
#pragma unroll
    for (int ms = 0; ms < 2; ++ms)
#pragma unroll
    for (int r = 0; r < 16; ++r) {
        int n = n0 + wm * 64 + ms * 32 + (r & 3) + 8 * (r >> 2) + 4 * lhi;
        float val = acc[ms][0][r] + acc[ms][1][r] * PSCALE_INV;
        obase[n] = val * iv + ad;
    }
}

// ---------------------------------------------------------------------------
extern "C" void kernel_launch(void* const* d_in, const int* in_sizes, int n_in,
                              void* d_out, int out_size, void* d_ws, size_t ws_size,
                              hipStream_t stream)
{
    const float* x       = (const float*)d_in[0];
    const float* q_w     = (const float*)d_in[1];
    const float* q_gamma = (const float*)d_in[2];
    const float* q_beta  = (const float*)d_in[3];
    const float* q_mean  = (const float*)d_in[4];
    const float* q_var   = (const float*)d_in[5];
    const float* k_w     = (const float*)d_in[6];
    const float* k_gamma = (const float*)d_in[7];
    const float* k_beta  = (const float*)d_in[8];
    const float* k_mean  = (const float*)d_in[9];
    const float* k_var   = (const float*)d_in[10];
    const float* proj_w  = (const float*)d_in[11];
    const float* proj_b  = (const float*)d_in[12];
    const float* p_gamma = (const float*)d_in[13];
    const float* p_beta  = (const float*)d_in[14];
    const float* p_mean  = (const float*)d_in[15];
    const float* p_var   = (const float*)d_in[16];
    const float* m_alpha = (const float*)d_in[17];

    float* out = (float*)d_out;

    const size_t SPK_BYTES = (size_t)T_ * B_ * N_ * C_;          // u8
    const size_t W2_BYTES  = (size_t)2 * NW_ * sizeof(f16);
    const size_t TBHN      = (size_t)T_ * B_ * HEADS_ * N_;

    unsigned char* ws = (unsigned char*)d_ws;
    size_t off = 0;
    auto carve = [&](size_t bytes) {
        off = (off + 255) & ~(size_t)255;
        void* p = ws + off;
        off += bytes;
        return p;
    };
    unsigned char* s_u8  = (unsigned char*)carve(SPK_BYTES);
    unsigned char* q_spk = (unsigned char*)carve(SPK_BYTES);
    unsigned char* k_spk = (unsigned char*)carve(SPK_BYTES);
    f16* Wq2    = (f16*)carve(W2_BYTES);
    f16* Wk2    = (f16*)carve(W2_BYTES);
    f16* Wp2    = (f16*)carve(W2_BYTES);
    unsigned char* attn = (unsigned char*)carve(TBHN);

    // 1. input LIF (u8 spikes) + weight split (z==32)
    dim3 pgrid1(4, 3, 33);
    prep_kernel<<<pgrid1, 256, 0, stream>>>(x, s_u8, q_w, k_w, proj_w,
                                            Wq2, Wk2, Wp2);

    // 2. q+k GEMM + BN + in-register LIF (grid 256 x 12, dbuf BK=32)
    dim3 qkgrid(256, 12);
    qk_gemm_lif_kernel<<<qkgrid, 256, 0, stream>>>(Wq2, Wk2, s_u8,
                                                   q_gamma, q_beta, q_mean, q_var,
                                                   k_gamma, k_beta, k_mean, k_var,
                                                   q_spk, k_spk);

    // 3. fused head-sum + memory + attn LIF
    head_attn_kernel<<<(B_ * HEADS_ * N_) / 256, 256, 0, stream>>>(q_spk, m_alpha, attn);

    // 4. proj GEMM -> out (grid 256 x 6)
    dim3 pjgrid(256, 6);
    proj_gemm_kernel<<<pjgrid, 256, 0, stream>>>(Wp2, k_spk, attn, proj_b,
                                                 p_gamma, p_beta, p_mean, p_var, out);
}

// Round 11
// 206.755 us; speedup vs baseline: 1.1684x; 1.0231x over previous
//
#include <hip/hip_runtime.h>

#define T_ 4
#define B_ 32
#define C_ 384
#define N_ 256
#define HEADS_ 8
#define DH_ 48
#define EPS_ 1e-5f
#define NW_ (C_*C_)

typedef _Float16 f16;
typedef __attribute__((ext_vector_type(8))) _Float16 f16x8;
typedef __attribute__((ext_vector_type(16))) float f32x16;

#define PSCALE     4096.0f
#define PSCALE_INV (1.0f/4096.0f)
#define SPIKE_BYTE 0x3Cu   // high byte of f16 1.0

// unpack 4 spike bytes (0x3C/0x00) -> 2 u32 holding 4 f16 (0x3C00/0x0000)
__device__ __forceinline__ void unpack4(unsigned int w, unsigned int& lo, unsigned int& hi) {
#if defined(__has_builtin) && __has_builtin(__builtin_amdgcn_perm)
    lo = __builtin_amdgcn_perm(w, w, 0x010C000Cu);  // [0, b0, 0, b1]
    hi = __builtin_amdgcn_perm(w, w, 0x030C020Cu);  // [0, b2, 0, b3]
#else
    lo = ((w & 0xFFu) << 8) | ((w & 0xFF00u) << 16);
    hi = ((w & 0x00FF0000u) >> 8) | (w & 0xFF000000u);
#endif
}

// expand 16 spike bytes (uint4) -> 32 f16 bytes (2x uint4)
__device__ __forceinline__ void unpack16(uint4 w, uint4& o0, uint4& o1) {
    unpack4(w.x, o0.x, o0.y); unpack4(w.y, o0.z, o0.w);
    unpack4(w.z, o1.x, o1.y); unpack4(w.w, o1.z, o1.w);
}

// split one f32 weight -> (a, b) f16 planes
__device__ __forceinline__ void wsplit(float w, f16& a, f16& b) {
    a = (f16)w; b = (f16)((w - (float)a) * PSCALE);
}

// ---------------------------------------------------------------------------
// Kernel 1: input LIF (z<32, round-8 version) + weight split over 144 blocks
// (z in [32,44)): 36864 threads = NW_/4 float4 elements, ONE float4 per
// array per thread -- no loop, exact bounds.
// ---------------------------------------------------------------------------
__global__ __launch_bounds__(256)
void prep_kernel(const float* __restrict__ x, unsigned char* __restrict__ s,
                 const float* __restrict__ qw, const float* __restrict__ kw,
                 const float* __restrict__ pw,
                 f16* __restrict__ q2, f16* __restrict__ k2, f16* __restrict__ p2)
{
    if (blockIdx.z >= 32) {
        const int blid = ((blockIdx.z - 32) * 3 + blockIdx.y) * 4 + blockIdx.x; // 0..143
        const int i4 = blid * 256 + threadIdx.x;   // 0..36863 == NW_/4 - 1
        {
            float4 w = ((const float4*)qw)[i4];
            union { f16 h[4]; uint2 u; } a, b;
            wsplit(w.x, a.h[0], b.h[0]); wsplit(w.y, a.h[1], b.h[1]);
            wsplit(w.z, a.h[2], b.h[2]); wsplit(w.w, a.h[3], b.h[3]);
            *(uint2*)&q2[(size_t)i4 * 4] = a.u;
            *(uint2*)&q2[NW_ + (size_t)i4 * 4] = b.u;
        }
        {
            float4 w = ((const float4*)kw)[i4];
            union { f16 h[4]; uint2 u; } a, b;
            wsplit(w.x, a.h[0], b.h[0]); wsplit(w.y, a.h[1], b.h[1]);
            wsplit(w.z, a.h[2], b.h[2]); wsplit(w.w, a.h[3], b.h[3]);
            *(uint2*)&k2[(size_t)i4 * 4] = a.u;
            *(uint2*)&k2[NW_ + (size_t)i4 * 4] = b.u;
        }
        {
            float4 w = ((const float4*)pw)[i4];
            union { f16 h[4]; uint2 u; } a, b;
            wsplit(w.x, a.h[0], b.h[0]); wsplit(w.y, a.h[1], b.h[1]);
            wsplit(w.z, a.h[2], b.h[2]); wsplit(w.w, a.h[3], b.h[3]);
            *(uint2*)&p2[(size_t)i4 * 4] = a.u;
            *(uint2*)&p2[NW_ + (size_t)i4 * 4] = b.u;
        }
        return;
    }

    const int tid = threadIdx.x;
    const int ng = tid & 15;                     // n-group
    const int cg = tid >> 4;                     // 0..15
    const int n4 = blockIdx.x * 64 + ng * 4;     // 4 consecutive n
    const int c0 = blockIdx.y * 128 + cg * 8;    // 8 consecutive c
    const int b  = blockIdx.z;

    float v[8][4];
#pragma unroll
    for (int i = 0; i < 8; ++i)
#pragma unroll
        for (int j = 0; j < 4; ++j) v[i][j] = 0.f;

#pragma unroll
    for (int t = 0; t < T_; ++t) {
        const float* xt = x + (((size_t)t * B_ + b) * C_) * N_;
        float4 xv[8];
#pragma unroll
        for (int i = 0; i < 8; ++i)
            xv[i] = *(const float4*)&xt[(size_t)(c0 + i) * N_ + n4];
#pragma unroll
        for (int j = 0; j < 4; ++j) {
            union { unsigned char bb[8]; uint2 u; } u;
#pragma unroll
            for (int i = 0; i < 8; ++i) {
                float xa = (j == 0) ? xv[i].x : (j == 1) ? xv[i].y
                         : (j == 2) ? xv[i].z : xv[i].w;
                float vv = 0.5f * v[i][j] + xa;
                int sp = (vv >= 1.0f) ? 1 : 0;
                v[i][j] = sp ? 0.f : vv;
                u.bb[i] = sp ? (unsigned char)SPIKE_BYTE : (unsigned char)0;
            }
            unsigned char* dst = s + (((size_t)t * B_ + b) * N_ + n4 + j) * (size_t)C_ + c0;
            *(uint2*)dst = u.u;
        }
    }
}

// ---------------------------------------------------------------------------
// Kernel 2: q/k GEMM + BN + fully in-register LIF (round-8 version, 50 us).
// BK=64, 2-barrier K-step with register prefetch issued after the 2nd
// barrier; sigma row permutation; u8 spikes in/out.
// ---------------------------------------------------------------------------
__global__ __launch_bounds__(256)
void qk_gemm_lif_kernel(const f16* __restrict__ Wq, const f16* __restrict__ Wk,
                        const unsigned char* __restrict__ S,
                        const float* __restrict__ qg, const float* __restrict__ qb,
                        const float* __restrict__ qm, const float* __restrict__ qv,
                        const float* __restrict__ kg, const float* __restrict__ kb,
                        const float* __restrict__ km, const float* __restrict__ kv,
                        unsigned char* __restrict__ q_spk,
                        unsigned char* __restrict__ k_spk)
{
    __shared__ __align__(16) char smem[36864];
    f16 (*As)[72]      = reinterpret_cast<f16(*)[72]>(smem);            // [128][72]
    f16 (*Bs)[64][72]  = reinterpret_cast<f16(*)[64][72]>(smem + 18432);// [2][64][72]

    const int tid  = threadIdx.x;
    const int lane = tid & 63;
    const int wave = tid >> 6;
    const int wm = wave & 1, wd = wave >> 1;
    const int l31 = lane & 31;
    const int lhi = lane >> 5;

    const int mb = blockIdx.x;            // 0..255
    const int b  = mb >> 3;
    const int n0 = (mb & 7) * 32;
    const int dp0 = blockIdx.y * 64;      // 0..704
    const int path = (dp0 >= C_) ? 1 : 0; // 0=q 1=k
    const int d0 = dp0 - path * C_;

    const f16* W = path ? Wk : Wq;
    const float* g_  = path ? kg : qg;
    const float* be_ = path ? kb : qb;
    const float* m_  = path ? km : qm;
    const float* va_ = path ? kv : qv;
    unsigned char* spk = path ? k_spk : q_spk;

    const int dcol = d0 + wd * 32 + l31;
    const float inv = g_[dcol] / sqrtf(va_[dcol] + EPS_);
    const float add = be_[dcol] - m_[dcol] * inv;

    // staging map (round-0 global order: wave covers 32 consecutive n, one t)
    const int ar = tid >> 1;              // 0..127: content (t=ar>>5, n=ar&31)
    const int ah = (tid & 1) * 32;        // channel-half offset
    const int at = ar >> 5;
    const int anl = ar & 31;
    const unsigned char* arow = S + (((size_t)at * B_ + b) * N_ + n0 + anl) * (size_t)C_;
    // physical LDS row: sigma(4n+t) = 4n + ((t + (n>>1)) & 3)
    const int aps = 4 * anl + ((at + (anl >> 1)) & 3);

    const int bp = tid >> 7;              // plane
    const int brr = (tid >> 1) & 63;      // d row
    const int bh = (tid & 1) * 32;
    const f16* brow = W + (size_t)bp * NW_ + (size_t)(d0 + brr) * C_;

    // fragment-read rows: sigma(wm*64+ms*32+l31)
    const int abase = 4 * (l31 >> 2) + ((l31 + (l31 >> 3)) & 3);
    const f16* pa0 = &As[wm * 64 + abase][0];   // msub 0
    const f16* pa1 = pa0 + 32 * 72;             // msub 1 (+32 physical rows)

    f32x16 acc[2][2];                     // [msub][plane]
#pragma unroll
    for (int ms = 0; ms < 2; ++ms)
#pragma unroll
        for (int p = 0; p < 2; ++p)
#pragma unroll
            for (int r = 0; r < 16; ++r) acc[ms][p][r] = 0.f;

    // prologue prefetch (tile 0)
    uint4 ra0 = *(const uint4*)(arow + ah);
    uint4 ra1 = *(const uint4*)(arow + ah + 16);
    uint4 rb0 = *(const uint4*)(brow + bh);
    uint4 rb1 = *(const uint4*)(brow + bh + 8);
    uint4 rb2 = *(const uint4*)(brow + bh + 16);
    uint4 rb3 = *(const uint4*)(brow + bh + 24);

#pragma unroll
    for (int ic = 0; ic < 6; ++ic) {
        __syncthreads();                  // prev-tile reads done; drains prefetch
        {
            uint4 o0, o1;
            unpack16(ra0, o0, o1);
            *(uint4*)&As[aps][ah]      = o0;
            *(uint4*)&As[aps][ah + 8]  = o1;
            unpack16(ra1, o0, o1);
            *(uint4*)&As[aps][ah + 16] = o0;
            *(uint4*)&As[aps][ah + 24] = o1;
            *(uint4*)&Bs[bp][brr][bh]      = rb0;
            *(uint4*)&Bs[bp][brr][bh + 8]  = rb1;
            *(uint4*)&Bs[bp][brr][bh + 16] = rb2;
            *(uint4*)&Bs[bp][brr][bh + 24] = rb3;
        }
        __syncthreads();                  // writes visible
        if (ic < 5) {                     // issue next-tile loads: in flight during MFMA
            const int kn = ic * 64 + 64;
            ra0 = *(const uint4*)(arow + kn + ah);
            ra1 = *(const uint4*)(arow + kn + ah + 16);
            rb0 = *(const uint4*)(brow + kn + bh);
            rb1 = *(const uint4*)(brow + kn + bh + 8);
            rb2 = *(const uint4*)(brow + kn + bh + 16);
            rb3 = *(const uint4*)(brow + kn + bh + 24);
        }
#pragma unroll
        for (int kk = 0; kk < 4; ++kk) {
            const int ko = kk * 16 + lhi * 8;
            f16x8 a0 = *(const f16x8*)(pa0 + ko);
            f16x8 a1 = *(const f16x8*)(pa1 + ko);
            f16x8 b0 = *(const f16x8*)&Bs[0][wd * 32 + l31][ko];
            f16x8 b1 = *(const f16x8*)&Bs[1][wd * 32 + l31][ko];
            acc[0][0] = __builtin_amdgcn_mfma_f32_32x32x16_f16(a0, b0, acc[0][0], 0, 0, 0);
            acc[1][0] = __builtin_amdgcn_mfma_f32_32x32x16_f16(a1, b0, acc[1][0], 0, 0, 0);
            acc[0][1] = __builtin_amdgcn_mfma_f32_32x32x16_f16(a0, b1, acc[0][1], 0, 0, 0);
            acc[1][1] = __builtin_amdgcn_mfma_f32_32x32x16_f16(a1, b1, acc[1][1], 0, 0, 0);
        }
    }

    // in-register BN + LIF + u8 spike store (t == r&3; no LDS, no barrier).
#pragma unroll
    for (int ms = 0; ms < 2; ++ms)
#pragma unroll
    for (int g = 0; g < 4; ++g) {
        const int n = n0 + wm * 16 + ms * 8 + 2 * g + lhi;
        float v = 0.f;
#pragma unroll
        for (int t = 0; t < 4; ++t) {
            const int r = g * 4 + t;
            float val = (acc[ms][0][r] + acc[ms][1][r] * PSCALE_INV) * inv + add;
            float vv = 0.5f * v + val;
            int sp = (vv >= 1.0f) ? 1 : 0;
            v = sp ? 0.f : vv;
            spk[(((size_t)t * B_ + b) * N_ + n) * C_ + dcol] =
                sp ? (unsigned char)SPIKE_BYTE : (unsigned char)0;
        }
    }
}

// ---------------------------------------------------------------------------
// Kernel 3: fused head-sum + decayed memory + attention LIF (u8 spikes).
// ---------------------------------------------------------------------------
__global__ __launch_bounds__(256)
void head_attn_kernel(const unsigned char* __restrict__ q_spk,
                      const float* __restrict__ alpha_p,
                      unsigned char* __restrict__ attn)
{
    int i = blockIdx.x * 256 + threadIdx.x;   // B*H*N = 65536
    int n = i & (N_ - 1);
    int h = (i >> 8) & (HEADS_ - 1);
    int b = i >> 11;
    const float alpha = alpha_p[0];
    const int stride = B_ * HEADS_ * N_;
    float M = 0.f, v = 0.f, Sprev = 0.f;
#pragma unroll
    for (int t = 0; t < T_; ++t) {
        const uint4* p = (const uint4*)(q_spk + (((size_t)(t * B_ + b) * N_) + n) * C_ + h * DH_);
        int cnt = 0;
#pragma unroll
        for (int j = 0; j < 3; ++j) {          // 48 bytes = 3 x uint4
            uint4 w = p[j];
            cnt += __popc(w.x & 0x04040404u) + __popc(w.y & 0x04040404u)
                 + __popc(w.z & 0x04040404u) + __popc(w.w & 0x04040404u);
        }
        float Sqt = (float)cnt;
        if (t == 0) M = Sqt;
        else        M = alpha * M + (1.f - alpha) * Sprev;
        float qsum = M + Sqt;
        float vv = 0.5f * v + qsum;
        unsigned char sp = (vv >= 0.5f) ? 1 : 0;
        v = sp ? 0.f : vv;
        attn[(size_t)t * stride + i] = sp;
        Sprev = Sqt;
    }
}

// ---------------------------------------------------------------------------
// Kernel 4: proj GEMM (round-8 version). A = (attn & k_spk_u8) expanded to
// f16 at staging; register prefetch of A and B. Epilogue bias+BN -> out.
// ---------------------------------------------------------------------------
__global__ __launch_bounds__(256)
void proj_gemm_kernel(const f16* __restrict__ Wp,
                      const unsigned char* __restrict__ K8,
                      const unsigned char* __restrict__ attn,
                      const float* __restrict__ bias,
                      const float* __restrict__ gamma, const float* __restrict__ beta,
                      const float* __restrict__ mean,  const float* __restrict__ var,
                      float* __restrict__ out)
{
    __shared__ __align__(16) char smem[36864];
    f16 (*As)[72]     = reinterpret_cast<f16(*)[72]>(smem);
    f16 (*Bs)[64][72] = reinterpret_cast<f16(*)[64][72]>(smem + 18432);

    const int tid  = threadIdx.x;
    const int lane = tid & 63;
    const int wave = tid >> 6;
    const int wm = wave & 1, wd = wave >> 1;
    const int l31 = lane & 31;
    const int lhi = lane >> 5;

    const int mb = blockIdx.x;            // 0..255
    const int tb = mb >> 1;
    const int n0 = (mb & 1) * 128;
    const int d0 = blockIdx.y * 64;

    const int dcol = d0 + wd * 32 + l31;
    const float iv = gamma[dcol] / sqrtf(var[dcol] + EPS_);
    const float ad = beta[dcol] - mean[dcol] * iv + bias[dcol] * iv;

    // A reg-stage map: 2 threads/row, 4 chunks of 8 channels each
    const int ar = tid >> 1;              // 0..127
    const int ah = (tid & 1) * 32;
    const int an = n0 + ar;
    const unsigned char* arow = K8 + ((size_t)tb * N_ + an) * (size_t)C_;
    const unsigned char* At = attn + (size_t)tb * HEADS_ * N_;

    const int bp = tid >> 7;
    const int brr = (tid >> 1) & 63;
    const int bh = (tid & 1) * 32;
    const f16* brow = Wp + (size_t)bp * NW_ + (size_t)(d0 + brr) * C_;

    f32x16 acc[2][2];
#pragma unroll
    for (int ms = 0; ms < 2; ++ms)
#pragma unroll
        for (int p = 0; p < 2; ++p)
#pragma unroll
            for (int r = 0; r < 16; ++r) acc[ms][p][r] = 0.f;

    // prologue prefetch (tile 0)
    uint2 wa0, wa1, wa2, wa3;
    unsigned char am0, am1, am2, am3;
    uint4 rb0, rb1, rb2, rb3;
    {
        const int c0 = ah;
        am0 = At[(size_t)((c0     ) / DH_) * N_ + an]; wa0 = *(const uint2*)(arow + c0);
        am1 = At[(size_t)((c0 +  8) / DH_) * N_ + an]; wa1 = *(const uint2*)(arow + c0 + 8);
        am2 = At[(size_t)((c0 + 16) / DH_) * N_ + an]; wa2 = *(const uint2*)(arow + c0 + 16);
        am3 = At[(size_t)((c0 + 24) / DH_) * N_ + an]; wa3 = *(const uint2*)(arow + c0 + 24);
        rb0 = *(const uint4*)(brow + bh);
        rb1 = *(const uint4*)(brow + bh + 8);
        rb2 = *(const uint4*)(brow + bh + 16);
        rb3 = *(const uint4*)(brow + bh + 24);
    }

#pragma unroll
    for (int ic = 0; ic < 6; ++ic) {
        __syncthreads();
        {
            uint2 w;
            uint4 o;
            w = am0 ? wa0 : make_uint2(0u, 0u);
            unpack4(w.x, o.x, o.y); unpack4(w.y, o.z, o.w);
            *(uint4*)&As[ar][ah] = o;
            w = am1 ? wa1 : make_uint2(0u, 0u);
            unpack4(w.x, o.x, o.y); unpack4(w.y, o.z, o.w);
            *(uint4*)&As[ar][ah + 8] = o;
            w = am2 ? wa2 : make_uint2(0u, 0u);
            unpack4(w.x, o.x, o.y); unpack4(w.y, o.z, o.w);
            *(uint4*)&As[ar][ah + 16] = o;
            w = am3 ? wa3 : make_uint2(0u, 0u);
            unpack4(w.x, o.x, o.y); unpack4(w.y, o.z, o.w);
            *(uint4*)&As[ar][ah + 24] = o;
            *(uint4*)&Bs[bp][brr][bh]      = rb0;
            *(uint4*)&Bs[bp][brr][bh + 8]  = rb1;
            *(uint4*)&Bs[bp][brr][bh + 16] = rb2;
            *(uint4*)&Bs[bp][brr][bh + 24] = rb3;
        }
        __syncthreads();
        if (ic < 5) {
            const int kn = ic * 64 + 64;
            const int c0 = kn + ah;
            am0 = At[(size_t)((c0     ) / DH_) * N_ + an]; wa0 = *(const uint2*)(arow + c0);
            am1 = At[(size_t)((c0 +  8) / DH_) * N_ + an]; wa1 = *(const uint2*)(arow + c0 + 8);
            am2 = At[(size_t)((c0 + 16) / DH_) * N_ + an]; wa2 = *(const uint2*)(arow + c0 + 16);
            am3 = At[(size_t)((c0 + 24) / DH_) * N_ + an]; wa3 = *(const uint2*)(arow + c0 + 24);
            rb0 = *(const uint4*)(brow + kn + bh);
            rb1 = *(const uint4*)(brow + kn + bh + 8);
            rb2 = *(const uint4*)(brow + kn + bh + 16);
            rb3 = *(const uint4*)(brow + kn + bh + 24);
        }
#pragma unroll
        for (int kk = 0; kk < 4; ++kk) {
            const int ko = kk * 16 + lhi * 8;
            f16x8 a0 = *(const f16x8*)&As[wm * 64 + l31][ko];
            f16x8 a1 = *(const f16x8*)&As[wm * 64 + 32 + l31][ko];
            f16x8 b0 = *(const f16x8*)&Bs[0][wd * 32 + l31][ko];
            f16x8 b1 = *(const f16x8*)&Bs[1][wd * 32 + l31][ko];
            acc[0][0] = __builtin_amdgcn_mfma_f32_32x32x16_f16(a0, b0, acc[0][0], 0, 0, 0);
            acc[1][0] = __builtin_amdgcn_mfma_f32_32x32x16_f16(a1, b0, acc[1][0], 0, 0, 0);
            acc[0][1] = __builtin_amdgcn_mfma_f32_32x32x16_f16(a0, b1, acc[0][1], 0, 0, 0);
            acc[1][1] = __builtin_amdgcn_mfma_f32_32x32x16_f16(a1, b1, acc[1][1], 0, 0, 0);
        }
    }

    // epilogue: out[tb][dcol][n]
    float* obase = out + ((size_t)tb * C_ + dcol) * N_;
#pragma unroll
    for (int ms = 0; ms < 2; ++ms)
#pragma unroll
    for (int r = 0; r < 16; ++r) {
        int n = n0 + wm * 64 + ms * 32 + (r & 3) + 8 * (r >> 2) + 4 * lhi;
        float val = acc[ms][0][r] + acc[ms][1][r] * PSCALE_INV;
        obase[n] = val * iv + ad;
    }
}

// ---------------------------------------------------------------------------
extern "C" void kernel_launch(void* const* d_in, const int* in_sizes, int n_in,
                              void* d_out, int out_size, void* d_ws, size_t ws_size,
                              hipStream_t stream)
{
    const float* x       = (const float*)d_in[0];
    const float* q_w     = (const float*)d_in[1];
    const float* q_gamma = (const float*)d_in[2];
    const float* q_beta  = (const float*)d_in[3];
    const float* q_mean  = (const float*)d_in[4];
    const float* q_var   = (const float*)d_in[5];
    const float* k_w     = (const float*)d_in[6];
    const float* k_gamma = (const float*)d_in[7];
    const float* k_beta  = (const float*)d_in[8];
    const float* k_mean  = (const float*)d_in[9];
    const float* k_var   = (const float*)d_in[10];
    const float* proj_w  = (const float*)d_in[11];
    const float* proj_b  = (const float*)d_in[12];
    const float* p_gamma = (const float*)d_in[13];
    const float* p_beta  = (const float*)d_in[14];
    const float* p_mean  = (const float*)d_in[15];
    const float* p_var   = (const float*)d_in[16];
    const float* m_alpha = (const float*)d_in[17];

    float* out = (float*)d_out;

    const size_t SPK_BYTES = (size_t)T_ * B_ * N_ * C_;          // u8
    const size_t W2_BYTES  = (size_t)2 * NW_ * sizeof(f16);
    const size_t TBHN      = (size_t)T_ * B_ * HEADS_ * N_;

    unsigned char* ws = (unsigned char*)d_ws;
    size_t off = 0;
    auto carve = [&](size_t bytes) {
        off = (off + 255) & ~(size_t)255;
        void* p = ws + off;
        off += bytes;
        return p;
    };
    unsigned char* s_u8  = (unsigned char*)carve(SPK_BYTES);
    unsigned char* q_spk = (unsigned char*)carve(SPK_BYTES);
    unsigned char* k_spk = (unsigned char*)carve(SPK_BYTES);
    f16* Wq2    = (f16*)carve(W2_BYTES);
    f16* Wk2    = (f16*)carve(W2_BYTES);
    f16* Wp2    = (f16*)carve(W2_BYTES);
    unsigned char* attn = (unsigned char*)carve(TBHN);

    // 1. input LIF (u8 spikes, z<32) + weight split over 144 blocks (z in [32,44))
    dim3 pgrid1(4, 3, 44);
    prep_kernel<<<pgrid1, 256, 0, stream>>>(x, s_u8, q_w, k_w, proj_w,
                                            Wq2, Wk2, Wp2);

    // 2. q+k GEMM + BN + in-register LIF (grid 256 x 12, round-8 version)
    dim3 qkgrid(256, 12);
    qk_gemm_lif_kernel<<<qkgrid, 256, 0, stream>>>(Wq2, Wk2, s_u8,
                                                   q_gamma, q_beta, q_mean, q_var,
                                                   k_gamma, k_beta, k_mean, k_var,
                                                   q_spk, k_spk);

    // 3. fused head-sum + memory + attn LIF
    head_attn_kernel<<<(B_ * HEADS_ * N_) / 256, 256, 0, stream>>>(q_spk, m_alpha, attn);

    // 4. proj GEMM -> out (grid 256 x 6)
    dim3 pjgrid(256, 6);
    proj_gemm_kernel<<<pjgrid, 256, 0, stream>>>(Wp2, k_spk, attn, proj_b,
                                                 p_gamma, p_beta, p_mean, p_var, out);
}

// Round 12
// 200.656 us; speedup vs baseline: 1.2039x; 1.0304x over previous
//
#include <hip/hip_runtime.h>

#define T_ 4
#define B_ 32
#define C_ 384
#define N_ 256
#define HEADS_ 8
#define DH_ 48
#define EPS_ 1e-5f
#define NW_ (C_*C_)

typedef _Float16 f16;
typedef __attribute__((ext_vector_type(8))) _Float16 f16x8;
typedef __attribute__((ext_vector_type(16))) float f32x16;

#define PSCALE     4096.0f
#define PSCALE_INV (1.0f/4096.0f)
#define SPIKE_BYTE 0x3Cu   // high byte of f16 1.0

// unpack 4 spike bytes (0x3C/0x00) -> 2 u32 holding 4 f16 (0x3C00/0x0000)
__device__ __forceinline__ void unpack4(unsigned int w, unsigned int& lo, unsigned int& hi) {
#if defined(__has_builtin) && __has_builtin(__builtin_amdgcn_perm)
    lo = __builtin_amdgcn_perm(w, w, 0x010C000Cu);  // [0, b0, 0, b1]
    hi = __builtin_amdgcn_perm(w, w, 0x030C020Cu);  // [0, b2, 0, b3]
#else
    lo = ((w & 0xFFu) << 8) | ((w & 0xFF00u) << 16);
    hi = ((w & 0x00FF0000u) >> 8) | (w & 0xFF000000u);
#endif
}

// expand 16 spike bytes (uint4) -> 32 f16 bytes (2x uint4)
__device__ __forceinline__ void unpack16(uint4 w, uint4& o0, uint4& o1) {
    unpack4(w.x, o0.x, o0.y); unpack4(w.y, o0.z, o0.w);
    unpack4(w.z, o1.x, o1.y); unpack4(w.w, o1.z, o1.w);
}

// split one f32 weight -> (a, b) f16 planes
__device__ __forceinline__ void wsplit(float w, f16& a, f16& b) {
    a = (f16)w; b = (f16)((w - (float)a) * PSCALE);
}

// ---------------------------------------------------------------------------
// Kernel 1: input LIF (z<32) + weight split over 144 blocks (z in [32,44)).
// (round-11 version, validated)
// ---------------------------------------------------------------------------
__global__ __launch_bounds__(256)
void prep_kernel(const float* __restrict__ x, unsigned char* __restrict__ s,
                 const float* __restrict__ qw, const float* __restrict__ kw,
                 const float* __restrict__ pw,
                 f16* __restrict__ q2, f16* __restrict__ k2, f16* __restrict__ p2)
{
    if (blockIdx.z >= 32) {
        const int blid = ((blockIdx.z - 32) * 3 + blockIdx.y) * 4 + blockIdx.x; // 0..143
        const int i4 = blid * 256 + threadIdx.x;   // 0..36863 == NW_/4 - 1
        {
            float4 w = ((const float4*)qw)[i4];
            union { f16 h[4]; uint2 u; } a, b;
            wsplit(w.x, a.h[0], b.h[0]); wsplit(w.y, a.h[1], b.h[1]);
            wsplit(w.z, a.h[2], b.h[2]); wsplit(w.w, a.h[3], b.h[3]);
            *(uint2*)&q2[(size_t)i4 * 4] = a.u;
            *(uint2*)&q2[NW_ + (size_t)i4 * 4] = b.u;
        }
        {
            float4 w = ((const float4*)kw)[i4];
            union { f16 h[4]; uint2 u; } a, b;
            wsplit(w.x, a.h[0], b.h[0]); wsplit(w.y, a.h[1], b.h[1]);
            wsplit(w.z, a.h[2], b.h[2]); wsplit(w.w, a.h[3], b.h[3]);
            *(uint2*)&k2[(size_t)i4 * 4] = a.u;
            *(uint2*)&k2[NW_ + (size_t)i4 * 4] = b.u;
        }
        {
            float4 w = ((const float4*)pw)[i4];
            union { f16 h[4]; uint2 u; } a, b;
            wsplit(w.x, a.h[0], b.h[0]); wsplit(w.y, a.h[1], b.h[1]);
            wsplit(w.z, a.h[2], b.h[2]); wsplit(w.w, a.h[3], b.h[3]);
            *(uint2*)&p2[(size_t)i4 * 4] = a.u;
            *(uint2*)&p2[NW_ + (size_t)i4 * 4] = b.u;
        }
        return;
    }

    const int tid = threadIdx.x;
    const int ng = tid & 15;                     // n-group
    const int cg = tid >> 4;                     // 0..15
    const int n4 = blockIdx.x * 64 + ng * 4;     // 4 consecutive n
    const int c0 = blockIdx.y * 128 + cg * 8;    // 8 consecutive c
    const int b  = blockIdx.z;

    float v[8][4];
#pragma unroll
    for (int i = 0; i < 8; ++i)
#pragma unroll
        for (int j = 0; j < 4; ++j) v[i][j] = 0.f;

#pragma unroll
    for (int t = 0; t < T_; ++t) {
        const float* xt = x + (((size_t)t * B_ + b) * C_) * N_;
        float4 xv[8];
#pragma unroll
        for (int i = 0; i < 8; ++i)
            xv[i] = *(const float4*)&xt[(size_t)(c0 + i) * N_ + n4];
#pragma unroll
        for (int j = 0; j < 4; ++j) {
            union { unsigned char bb[8]; uint2 u; } u;
#pragma unroll
            for (int i = 0; i < 8; ++i) {
                float xa = (j == 0) ? xv[i].x : (j == 1) ? xv[i].y
                         : (j == 2) ? xv[i].z : xv[i].w;
                float vv = 0.5f * v[i][j] + xa;
                int sp = (vv >= 1.0f) ? 1 : 0;
                v[i][j] = sp ? 0.f : vv;
                u.bb[i] = sp ? (unsigned char)SPIKE_BYTE : (unsigned char)0;
            }
            unsigned char* dst = s + (((size_t)t * B_ + b) * N_ + n4 + j) * (size_t)C_ + c0;
            *(uint2*)dst = u.u;
        }
    }
}

// ---------------------------------------------------------------------------
// Kernel 2: q/k GEMM + BN + fully in-register LIF (round-8 K-loop, 50 us).
// CHANGE: q_spk layout is now (t, b, h, n, 48) -- h folded into the store
// base (per-thread constant) so head_attn reads are contiguous. k_spk keeps
// (t, b, n, C) for proj's GEMM A-rows.
// ---------------------------------------------------------------------------
__global__ __launch_bounds__(256)
void qk_gemm_lif_kernel(const f16* __restrict__ Wq, const f16* __restrict__ Wk,
                        const unsigned char* __restrict__ S,
                        const float* __restrict__ qg, const float* __restrict__ qb,
                        const float* __restrict__ qm, const float* __restrict__ qv,
                        const float* __restrict__ kg, const float* __restrict__ kb,
                        const float* __restrict__ km, const float* __restrict__ kv,
                        unsigned char* __restrict__ q_spk,
                        unsigned char* __restrict__ k_spk)
{
    __shared__ __align__(16) char smem[36864];
    f16 (*As)[72]      = reinterpret_cast<f16(*)[72]>(smem);            // [128][72]
    f16 (*Bs)[64][72]  = reinterpret_cast<f16(*)[64][72]>(smem + 18432);// [2][64][72]

    const int tid  = threadIdx.x;
    const int lane = tid & 63;
    const int wave = tid >> 6;
    const int wm = wave & 1, wd = wave >> 1;
    const int l31 = lane & 31;
    const int lhi = lane >> 5;

    const int mb = blockIdx.x;            // 0..255
    const int b  = mb >> 3;
    const int n0 = (mb & 7) * 32;
    const int dp0 = blockIdx.y * 64;      // 0..704
    const int path = (dp0 >= C_) ? 1 : 0; // 0=q 1=k
    const int d0 = dp0 - path * C_;

    const f16* W = path ? Wk : Wq;
    const float* g_  = path ? kg : qg;
    const float* be_ = path ? kb : qb;
    const float* m_  = path ? km : qm;
    const float* va_ = path ? kv : qv;

    const int dcol = d0 + wd * 32 + l31;
    const float inv = g_[dcol] / sqrtf(va_[dcol] + EPS_);
    const float add = be_[dcol] - m_[dcol] * inv;

    // staging map (round-0 global order: wave covers 32 consecutive n, one t)
    const int ar = tid >> 1;              // 0..127: content (t=ar>>5, n=ar&31)
    const int ah = (tid & 1) * 32;        // channel-half offset
    const int at = ar >> 5;
    const int anl = ar & 31;
    const unsigned char* arow = S + (((size_t)at * B_ + b) * N_ + n0 + anl) * (size_t)C_;
    // physical LDS row: sigma(4n+t) = 4n + ((t + (n>>1)) & 3)
    const int aps = 4 * anl + ((at + (anl >> 1)) & 3);

    const int bp = tid >> 7;              // plane
    const int brr = (tid >> 1) & 63;      // d row
    const int bh = (tid & 1) * 32;
    const f16* brow = W + (size_t)bp * NW_ + (size_t)(d0 + brr) * C_;

    // fragment-read rows: sigma(wm*64+ms*32+l31)
    const int abase = 4 * (l31 >> 2) + ((l31 + (l31 >> 3)) & 3);
    const f16* pa0 = &As[wm * 64 + abase][0];   // msub 0
    const f16* pa1 = pa0 + 32 * 72;             // msub 1 (+32 physical rows)

    f32x16 acc[2][2];                     // [msub][plane]
#pragma unroll
    for (int ms = 0; ms < 2; ++ms)
#pragma unroll
        for (int p = 0; p < 2; ++p)
#pragma unroll
            for (int r = 0; r < 16; ++r) acc[ms][p][r] = 0.f;

    // prologue prefetch (tile 0)
    uint4 ra0 = *(const uint4*)(arow + ah);
    uint4 ra1 = *(const uint4*)(arow + ah + 16);
    uint4 rb0 = *(const uint4*)(brow + bh);
    uint4 rb1 = *(const uint4*)(brow + bh + 8);
    uint4 rb2 = *(const uint4*)(brow + bh + 16);
    uint4 rb3 = *(const uint4*)(brow + bh + 24);

#pragma unroll
    for (int ic = 0; ic < 6; ++ic) {
        __syncthreads();                  // prev-tile reads done; drains prefetch
        {
            uint4 o0, o1;
            unpack16(ra0, o0, o1);
            *(uint4*)&As[aps][ah]      = o0;
            *(uint4*)&As[aps][ah + 8]  = o1;
            unpack16(ra1, o0, o1);
            *(uint4*)&As[aps][ah + 16] = o0;
            *(uint4*)&As[aps][ah + 24] = o1;
            *(uint4*)&Bs[bp][brr][bh]      = rb0;
            *(uint4*)&Bs[bp][brr][bh + 8]  = rb1;
            *(uint4*)&Bs[bp][brr][bh + 16] = rb2;
            *(uint4*)&Bs[bp][brr][bh + 24] = rb3;
        }
        __syncthreads();                  // writes visible
        if (ic < 5) {                     // issue next-tile loads: in flight during MFMA
            const int kn = ic * 64 + 64;
            ra0 = *(const uint4*)(arow + kn + ah);
            ra1 = *(const uint4*)(arow + kn + ah + 16);
            rb0 = *(const uint4*)(brow + kn + bh);
            rb1 = *(const uint4*)(brow + kn + bh + 8);
            rb2 = *(const uint4*)(brow + kn + bh + 16);
            rb3 = *(const uint4*)(brow + kn + bh + 24);
        }
#pragma unroll
        for (int kk = 0; kk < 4; ++kk) {
            const int ko = kk * 16 + lhi * 8;
            f16x8 a0 = *(const f16x8*)(pa0 + ko);
            f16x8 a1 = *(const f16x8*)(pa1 + ko);
            f16x8 b0 = *(const f16x8*)&Bs[0][wd * 32 + l31][ko];
            f16x8 b1 = *(const f16x8*)&Bs[1][wd * 32 + l31][ko];
            acc[0][0] = __builtin_amdgcn_mfma_f32_32x32x16_f16(a0, b0, acc[0][0], 0, 0, 0);
            acc[1][0] = __builtin_amdgcn_mfma_f32_32x32x16_f16(a1, b0, acc[1][0], 0, 0, 0);
            acc[0][1] = __builtin_amdgcn_mfma_f32_32x32x16_f16(a0, b1, acc[0][1], 0, 0, 0);
            acc[1][1] = __builtin_amdgcn_mfma_f32_32x32x16_f16(a1, b1, acc[1][1], 0, 0, 0);
        }
    }

    // in-register BN + LIF + u8 spike store (t == r&3; no LDS, no barrier).
    if (path == 0) {
        const int hq = dcol / DH_;
        const int dh = dcol - hq * DH_;
#pragma unroll
        for (int ms = 0; ms < 2; ++ms)
#pragma unroll
        for (int g = 0; g < 4; ++g) {
            const int n = n0 + wm * 16 + ms * 8 + 2 * g + lhi;
            float v = 0.f;
#pragma unroll
            for (int t = 0; t < 4; ++t) {
                const int r = g * 4 + t;
                float val = (acc[ms][0][r] + acc[ms][1][r] * PSCALE_INV) * inv + add;
                float vv = 0.5f * v + val;
                int sp = (vv >= 1.0f) ? 1 : 0;
                v = sp ? 0.f : vv;
                q_spk[((((size_t)t * B_ + b) * HEADS_ + hq) * N_ + n) * DH_ + dh] =
                    sp ? (unsigned char)SPIKE_BYTE : (unsigned char)0;
            }
        }
    } else {
#pragma unroll
        for (int ms = 0; ms < 2; ++ms)
#pragma unroll
        for (int g = 0; g < 4; ++g) {
            const int n = n0 + wm * 16 + ms * 8 + 2 * g + lhi;
            float v = 0.f;
#pragma unroll
            for (int t = 0; t < 4; ++t) {
                const int r = g * 4 + t;
                float val = (acc[ms][0][r] + acc[ms][1][r] * PSCALE_INV) * inv + add;
                float vv = 0.5f * v + val;
                int sp = (vv >= 1.0f) ? 1 : 0;
                v = sp ? 0.f : vv;
                k_spk[(((size_t)t * B_ + b) * N_ + n) * C_ + dcol] =
                    sp ? (unsigned char)SPIKE_BYTE : (unsigned char)0;
            }
        }
    }
}

// ---------------------------------------------------------------------------
// Kernel 3: fused head-sum + decayed memory + attention LIF.
// q_spk layout (t,b,h,n,48): each thread reads 48 contiguous bytes;
// consecutive threads (n) adjacent -> full line utilization.
// ---------------------------------------------------------------------------
__global__ __launch_bounds__(256)
void head_attn_kernel(const unsigned char* __restrict__ q_spk,
                      const float* __restrict__ alpha_p,
                      unsigned char* __restrict__ attn)
{
    int i = blockIdx.x * 256 + threadIdx.x;   // B*H*N = 65536
    const float alpha = alpha_p[0];
    const int stride = B_ * HEADS_ * N_;      // == per-t elements of (b,h,n)
    float M = 0.f, v = 0.f, Sprev = 0.f;
#pragma unroll
    for (int t = 0; t < T_; ++t) {
        const uint4* p = (const uint4*)(q_spk + ((size_t)t * stride + i) * DH_);
        int cnt = 0;
#pragma unroll
        for (int j = 0; j < 3; ++j) {          // 48 bytes = 3 x uint4
            uint4 w = p[j];
            cnt += __popc(w.x & 0x04040404u) + __popc(w.y & 0x04040404u)
                 + __popc(w.z & 0x04040404u) + __popc(w.w & 0x04040404u);
        }
        float Sqt = (float)cnt;
        if (t == 0) M = Sqt;
        else        M = alpha * M + (1.f - alpha) * Sprev;
        float qsum = M + Sqt;
        float vv = 0.5f * v + qsum;
        unsigned char sp = (vv >= 0.5f) ? 1 : 0;
        v = sp ? 0.f : vv;
        attn[(size_t)t * stride + i] = sp;
        Sprev = Sqt;
    }
}

// ---------------------------------------------------------------------------
// Kernel 4: proj GEMM (round-8 K-loop). NEW epilogue: acc -> padded [64][129]
// f32 LDS tile (all-distinct-bank scalar writes) -> float4 stores with 32
// consecutive lanes covering 512 contiguous bytes (fully coalesced out).
// ---------------------------------------------------------------------------
__global__ __launch_bounds__(256)
void proj_gemm_kernel(const f16* __restrict__ Wp,
                      const unsigned char* __restrict__ K8,
                      const unsigned char* __restrict__ attn,
                      const float* __restrict__ bias,
                      const float* __restrict__ gamma, const float* __restrict__ beta,
                      const float* __restrict__ mean,  const float* __restrict__ var,
                      float* __restrict__ out)
{
    __shared__ __align__(16) char smem[36864];
    f16 (*As)[72]     = reinterpret_cast<f16(*)[72]>(smem);
    f16 (*Bs)[64][72] = reinterpret_cast<f16(*)[64][72]>(smem + 18432);
    float (*Pt)[129]  = reinterpret_cast<float(*)[129]>(smem);   // reuse: [64][129]

    const int tid  = threadIdx.x;
    const int lane = tid & 63;
    const int wave = tid >> 6;
    const int wm = wave & 1, wd = wave >> 1;
    const int l31 = lane & 31;
    const int lhi = lane >> 5;

    const int mb = blockIdx.x;            // 0..255
    const int tb = mb >> 1;
    const int n0 = (mb & 1) * 128;
    const int d0 = blockIdx.y * 64;

    const int dcol = d0 + wd * 32 + l31;
    const float iv = gamma[dcol] / sqrtf(var[dcol] + EPS_);
    const float ad = beta[dcol] - mean[dcol] * iv + bias[dcol] * iv;

    // A reg-stage map: 2 threads/row, 4 chunks of 8 channels each
    const int ar = tid >> 1;              // 0..127
    const int ah = (tid & 1) * 32;
    const int an = n0 + ar;
    const unsigned char* arow = K8 + ((size_t)tb * N_ + an) * (size_t)C_;
    const unsigned char* At = attn + (size_t)tb * HEADS_ * N_;

    const int bp = tid >> 7;
    const int brr = (tid >> 1) & 63;
    const int bh = (tid & 1) * 32;
    const f16* brow = Wp + (size_t)bp * NW_ + (size_t)(d0 + brr) * C_;

    f32x16 acc[2][2];
#pragma unroll
    for (int ms = 0; ms < 2; ++ms)
#pragma unroll
        for (int p = 0; p < 2; ++p)
#pragma unroll
            for (int r = 0; r < 16; ++r) acc[ms][p][r] = 0.f;

    // prologue prefetch (tile 0)
    uint2 wa0, wa1, wa2, wa3;
    unsigned char am0, am1, am2, am3;
    uint4 rb0, rb1, rb2, rb3;
    {
        const int c0 = ah;
        am0 = At[(size_t)((c0     ) / DH_) * N_ + an]; wa0 = *(const uint2*)(arow + c0);
        am1 = At[(size_t)((c0 +  8) / DH_) * N_ + an]; wa1 = *(const uint2*)(arow + c0 + 8);
        am2 = At[(size_t)((c0 + 16) / DH_) * N_ + an]; wa2 = *(const uint2*)(arow + c0 + 16);
        am3 = At[(size_t)((c0 + 24) / DH_) * N_ + an]; wa3 = *(const uint2*)(arow + c0 + 24);
        rb0 = *(const uint4*)(brow + bh);
        rb1 = *(const uint4*)(brow + bh + 8);
        rb2 = *(const uint4*)(brow + bh + 16);
        rb3 = *(const uint4*)(brow + bh + 24);
    }

#pragma unroll
    for (int ic = 0; ic < 6; ++ic) {
        __syncthreads();
        {
            uint2 w;
            uint4 o;
            w = am0 ? wa0 : make_uint2(0u, 0u);
            unpack4(w.x, o.x, o.y); unpack4(w.y, o.z, o.w);
            *(uint4*)&As[ar][ah] = o;
            w = am1 ? wa1 : make_uint2(0u, 0u);
            unpack4(w.x, o.x, o.y); unpack4(w.y, o.z, o.w);
            *(uint4*)&As[ar][ah + 8] = o;
            w = am2 ? wa2 : make_uint2(0u, 0u);
            unpack4(w.x, o.x, o.y); unpack4(w.y, o.z, o.w);
            *(uint4*)&As[ar][ah + 16] = o;
            w = am3 ? wa3 : make_uint2(0u, 0u);
            unpack4(w.x, o.x, o.y); unpack4(w.y, o.z, o.w);
            *(uint4*)&As[ar][ah + 24] = o;
            *(uint4*)&Bs[bp][brr][bh]      = rb0;
            *(uint4*)&Bs[bp][brr][bh + 8]  = rb1;
            *(uint4*)&Bs[bp][brr][bh + 16] = rb2;
            *(uint4*)&Bs[bp][brr][bh + 24] = rb3;
        }
        __syncthreads();
        if (ic < 5) {
            const int kn = ic * 64 + 64;
            const int c0 = kn + ah;
            am0 = At[(size_t)((c0     ) / DH_) * N_ + an]; wa0 = *(const uint2*)(arow + c0);
            am1 = At[(size_t)((c0 +  8) / DH_) * N_ + an]; wa1 = *(const uint2*)(arow + c0 + 8);
            am2 = At[(size_t)((c0 + 16) / DH_) * N_ + an]; wa2 = *(const uint2*)(arow + c0 + 16);
            am3 = At[(size_t)((c0 + 24) / DH_) * N_ + an]; wa3 = *(const uint2*)(arow + c0 + 24);
            rb0 = *(const uint4*)(brow + kn + bh);
            rb1 = *(const uint4*)(brow + kn + bh + 8);
            rb2 = *(const uint4*)(brow + kn + bh + 16);
            rb3 = *(const uint4*)(brow + kn + bh + 24);
        }
#pragma unroll
        for (int kk = 0; kk < 4; ++kk) {
            const int ko = kk * 16 + lhi * 8;
            f16x8 a0 = *(const f16x8*)&As[wm * 64 + l31][ko];
            f16x8 a1 = *(const f16x8*)&As[wm * 64 + 32 + l31][ko];
            f16x8 b0 = *(const f16x8*)&Bs[0][wd * 32 + l31][ko];
            f16x8 b1 = *(const f16x8*)&Bs[1][wd * 32 + l31][ko];
            acc[0][0] = __builtin_amdgcn_mfma_f32_32x32x16_f16(a0, b0, acc[0][0], 0, 0, 0);
            acc[1][0] = __builtin_amdgcn_mfma_f32_32x32x16_f16(a1, b0, acc[1][0], 0, 0, 0);
            acc[0][1] = __builtin_amdgcn_mfma_f32_32x32x16_f16(a0, b1, acc[0][1], 0, 0, 0);
            acc[1][1] = __builtin_amdgcn_mfma_f32_32x32x16_f16(a1, b1, acc[1][1], 0, 0, 0);
        }
    }

    // epilogue: BN in regs -> LDS transpose tile -> coalesced float4 stores
    __syncthreads();                      // K-loop LDS reads done; safe to reuse
    {
        const int dl = wd * 32 + l31;     // local d row 0..63
#pragma unroll
        for (int ms = 0; ms < 2; ++ms)
#pragma unroll
        for (int r = 0; r < 16; ++r) {
            const int nl = wm * 64 + ms * 32 + (r & 3) + 8 * (r >> 2) + 4 * lhi;
            Pt[dl][nl] = (acc[ms][0][r] + acc[ms][1][r] * PSCALE_INV) * iv + ad;
        }
    }
    __syncthreads();
    {
        const int col4 = (tid & 31) * 4;  // float offset 0..124
        const int rw   = tid >> 5;        // 0..7
#pragma unroll
        for (int it = 0; it < 8; ++it) {
            const int row = rw + it * 8;  // 0..63
            float4 vv = *(const float4*)&Pt[row][col4];
            *(float4*)&out[((size_t)tb * C_ + d0 + row) * N_ + n0 + col4] = vv;
        }
    }
}

// ---------------------------------------------------------------------------
extern "C" void kernel_launch(void* const* d_in, const int* in_sizes, int n_in,
                              void* d_out, int out_size, void* d_ws, size_t ws_size,
                              hipStream_t stream)
{
    const float* x       = (const float*)d_in[0];
    const float* q_w     = (const float*)d_in[1];
    const float* q_gamma = (const float*)d_in[2];
    const float* q_beta  = (const float*)d_in[3];
    const float* q_mean  = (const float*)d_in[4];
    const float* q_var   = (const float*)d_in[5];
    const float* k_w     = (const float*)d_in[6];
    const float* k_gamma = (const float*)d_in[7];
    const float* k_beta  = (const float*)d_in[8];
    const float* k_mean  = (const float*)d_in[9];
    const float* k_var   = (const float*)d_in[10];
    const float* proj_w  = (const float*)d_in[11];
    const float* proj_b  = (const float*)d_in[12];
    const float* p_gamma = (const float*)d_in[13];
    const float* p_beta  = (const float*)d_in[14];
    const float* p_mean  = (const float*)d_in[15];
    const float* p_var   = (const float*)d_in[16];
    const float* m_alpha = (const float*)d_in[17];

    float* out = (float*)d_out;

    const size_t SPK_BYTES = (size_t)T_ * B_ * N_ * C_;          // u8 (both layouts)
    const size_t W2_BYTES  = (size_t)2 * NW_ * sizeof(f16);
    const size_t TBHN      = (size_t)T_ * B_ * HEADS_ * N_;

    unsigned char* ws = (unsigned char*)d_ws;
    size_t off = 0;
    auto carve = [&](size_t bytes) {
        off = (off + 255) & ~(size_t)255;
        void* p = ws + off;
        off += bytes;
        return p;
    };
    unsigned char* s_u8  = (unsigned char*)carve(SPK_BYTES);
    unsigned char* q_spk = (unsigned char*)carve(SPK_BYTES);   // (t,b,h,n,48)
    unsigned char* k_spk = (unsigned char*)carve(SPK_BYTES);   // (t,b,n,C)
    f16* Wq2    = (f16*)carve(W2_BYTES);
    f16* Wk2    = (f16*)carve(W2_BYTES);
    f16* Wp2    = (f16*)carve(W2_BYTES);
    unsigned char* attn = (unsigned char*)carve(TBHN);

    // 1. input LIF (u8 spikes, z<32) + weight split over 144 blocks (z in [32,44))
    dim3 pgrid1(4, 3, 44);
    prep_kernel<<<pgrid1, 256, 0, stream>>>(x, s_u8, q_w, k_w, proj_w,
                                            Wq2, Wk2, Wp2);

    // 2. q+k GEMM + BN + in-register LIF (grid 256 x 12)
    dim3 qkgrid(256, 12);
    qk_gemm_lif_kernel<<<qkgrid, 256, 0, stream>>>(Wq2, Wk2, s_u8,
                                                   q_gamma, q_beta, q_mean, q_var,
                                                   k_gamma, k_beta, k_mean, k_var,
                                                   q_spk, k_spk);

    // 3. fused head-sum + memory + attn LIF
    head_attn_kernel<<<(B_ * HEADS_ * N_) / 256, 256, 0, stream>>>(q_spk, m_alpha, attn);

    // 4. proj GEMM -> out (grid 256 x 6)
    dim3 pjgrid(256, 6);
    proj_gemm_kernel<<<pjgrid, 256, 0, stream>>>(Wp2, k_spk, attn, proj_b,
                                                 p_gamma, p_beta, p_mean, p_var, out);
}